// Round 2
// baseline (1366.567 us; speedup 1.0000x reference)
//
#include <hip/hip_runtime.h>
#include <hip/hip_bf16.h>

#define T_OBS 16
#define NAg   4096
#define Vn    8
#define NV    32768           // NAg*Vn
#define SEQ   36864           // NAg + NV
#define PRED  25
#define ESTR  68              // padded LDS stride for 64-wide seq tiles
#define HSTR  132             // padded LDS stride for 128-wide dec hidden
#define GSTR  388             // padded LDS stride for 384-wide gi
#define XSTR  116             // padded LDS stride for 112-wide xc tile

__device__ __forceinline__ float leakyf(float v){ return v >= 0.f ? v : 0.1f*v; }
__device__ __forceinline__ float sigf(float x){ return 1.f/(1.f+__expf(-x)); }
__device__ __forceinline__ float tanhf_(float x){
  x = fminf(fmaxf(x, -10.f), 10.f);
  float e = __expf(2.f*x);
  return (e-1.f)/(e+1.f);
}
__device__ __forceinline__ float bf2f(unsigned short u){
  union{unsigned int i; float f;} v; v.i = ((unsigned int)u)<<16; return v.f;
}
__device__ __forceinline__ unsigned short f2bf(float f){
  __hip_bfloat16 b = __float2bfloat16(f);
  return *reinterpret_cast<unsigned short*>(&b);
}
__device__ __forceinline__ float bflo(unsigned int u){ union{unsigned int i; float f;} v; v.i = u<<16; return v.f; }
__device__ __forceinline__ float bfhi(unsigned int u){ union{unsigned int i; float f;} v; v.i = u & 0xffff0000u; return v.f; }
__device__ __forceinline__ float dot4f(float4 a, float4 b, float acc){
  return fmaf(a.x,b.x, fmaf(a.y,b.y, fmaf(a.z,b.z, fmaf(a.w,b.w, acc))));
}

// ---------------------------------------------------------------------------
// Decode bool masks (dtype-representation-defensive) -> per-agent selected
// cell indices (8 ascending flat (gw*13+gh) indices). Every selected cell
// spans 64 identical consecutive elements (ENC broadcast).
// ---------------------------------------------------------------------------
__global__ void k_decode_masks(const void* __restrict__ masks, int* __restrict__ cells){
  int n = blockIdx.x*blockDim.x + threadIdx.x;
  if (n >= NAg) return;
  const unsigned char* m8  = (const unsigned char*)masks;
  const int*           m32 = (const int*)masks;
  int tmp[8]; for (int v=0; v<8; ++v) tmp[v] = 0;
  int cnt = 0;
  for (int cc=0; cc<39; ++cc){                 // u8 interpretation (bool bytes)
    size_t base = ((size_t)n*39 + cc)*64;
    if (m8[base] && m8[base+1] && m8[base+33]){ if (cnt<8) tmp[cnt]=cc; cnt++; }
  }
  if (cnt != 8){                               // fallback: 4-byte elements (int32/float32)
    cnt = 0;
    for (int cc=0; cc<39; ++cc){
      size_t base = ((size_t)n*39 + cc)*64;
      if (m32[base] != 0){ if (cnt<8) tmp[cnt]=cc; cnt++; }
    }
  }
  for (int v=0; v<8; ++v) cells[n*8+v] = tmp[v];
}

// ---------------------------------------------------------------------------
// One-shot weight re-layouts into workspace:
//  W1r: soc_W (64o,64c,3ky,3kx) f32 -> bf16 [kk=ky*3+kx][o][c pad 68]
//  WhhP: dec_Whh (384,128) f32 -> uint2[k4][384] (4 packed bf16 per entry)
// ---------------------------------------------------------------------------
__global__ void k_prep(const float* __restrict__ socW, unsigned short* __restrict__ W1r,
                       const float* __restrict__ dWhh, uint2* __restrict__ WhhP){
  int idx = blockIdx.x*blockDim.x + threadIdx.x;   // 36864 threads
  if (idx < 36864){
    int c  = idx & 63;
    int o  = (idx>>6) & 63;
    int kk = idx >> 12;                            // ky*3+kx, 0..8
    int ky = kk/3, kx = kk%3;
    W1r[(kk*64 + o)*ESTR + c] = f2bf(socW[(o*64 + c)*9 + ky*3 + kx]);
  }
  if (idx < 12288){
    int j  = idx % 384;
    int k4 = idx / 384;
    const float* p = dWhh + (size_t)j*128 + k4*4;
    uint2 u;
    u.x = (unsigned int)f2bf(p[0]) | ((unsigned int)f2bf(p[1])<<16);
    u.y = (unsigned int)f2bf(p[2]) | ((unsigned int)f2bf(p[3])<<16);
    WhhP[k4*384 + j] = u;
  }
}

// ---------------------------------------------------------------------------
// x_e = leaky(x @ dyn_W.T + dyn_b) -> E[t][0..4095][c] (bf16)
// ---------------------------------------------------------------------------
__global__ void k_embed_x(const float* __restrict__ x, const float* __restrict__ dynW,
                          const float* __restrict__ dynb, __hip_bfloat16* __restrict__ E){
  int idx = blockIdx.x*blockDim.x + threadIdx.x;   // 16*4096*64 exactly
  int c = idx & 63;
  int s = (idx >> 6) & 4095;
  int t = idx >> 18;
  float x0 = x[((size_t)t*NAg + s)*2 + 0];
  float x1 = x[((size_t)t*NAg + s)*2 + 1];
  float v = leakyf(fmaf(x0, dynW[c*2+0], fmaf(x1, dynW[c*2+1], dynb[c])));
  E[((size_t)t*SEQ + s)*64 + c] = __float2bfloat16(v);
}

// ---------------------------------------------------------------------------
// Per agent n: ng_e = leaky(dyn(ngbrs)), h = ng_e@sW.T+sb,
// agg[t,w,c] = sum_{v,k} h[t,v,k*64+c]*G[k,v,w]  -> E[t][4096+n*8+w][c]
// All 16 t handled in one block; sW kept transposed-packed in LDS.
// ---------------------------------------------------------------------------
__global__ __launch_bounds__(256,1) void k_embed_agg(
    const float* __restrict__ ngbrs, const float* __restrict__ graphs,
    const float* __restrict__ dynW, const float* __restrict__ dynb,
    const float* __restrict__ sW, const float* __restrict__ sb,
    __hip_bfloat16* __restrict__ E)
{
  __shared__ float4 SW4[16*128];      // [c4][j]  (j = 0..127)
  __shared__ float  nge[16*8*64];     // [t][v][c]
  __shared__ float  hm [16*8*128];    // [t][v][j]
  __shared__ float  gL[128];          // [k][v][w]
  __shared__ float  sbL[128], dwL[128], dbL[64];
  const int tid = threadIdx.x;
  const int n = blockIdx.x;

  for (int idx=tid; idx<2048; idx+=256){
    int j = idx & 127, c4 = idx >> 7;
    SW4[c4*128 + j] = *(const float4*)(sW + (size_t)j*64 + c4*4);
  }
  if (tid < 128) gL[tid]  = graphs[(size_t)n*128 + tid];
  if (tid < 128) sbL[tid] = sb[tid];
  if (tid < 128) dwL[tid] = dynW[tid];
  if (tid < 64)  dbL[tid] = dynb[tid];
  __syncthreads();

  for (int idx=tid; idx<8192; idx+=256){       // nge
    int c = idx & 63, v = (idx>>6)&7, t = idx>>9;
    const float* p = ngbrs + ((size_t)t*NV + (size_t)n*8 + v)*2;
    nge[idx] = leakyf(fmaf(p[0], dwL[c*2], fmaf(p[1], dwL[c*2+1], dbL[c])));
  }
  __syncthreads();

  #pragma unroll
  for (int p2=0; p2<2; ++p2){                  // hm: 512 tasks (t, jb)
    int task = tid + 256*p2;
    int t = task >> 5, jb = task & 31;
    float acc[8][4];
    #pragma unroll
    for (int jj=0; jj<4; ++jj){ float b = sbL[jb + jj*32];
      #pragma unroll
      for (int v=0; v<8; ++v) acc[v][jj] = b; }
    for (int c4=0; c4<16; ++c4){
      float4 wv[4];
      #pragma unroll
      for (int jj=0; jj<4; ++jj) wv[jj] = SW4[c4*128 + jj*32 + jb];
      #pragma unroll
      for (int v=0; v<8; ++v){
        float4 xv = *(const float4*)(nge + (t*8+v)*64 + c4*4);
        #pragma unroll
        for (int jj=0; jj<4; ++jj) acc[v][jj] = dot4f(wv[jj], xv, acc[v][jj]);
      }
    }
    #pragma unroll
    for (int v=0; v<8; ++v)
      #pragma unroll
      for (int jj=0; jj<4; ++jj)
        hm[(t*8+v)*128 + jj*32 + jb] = acc[v][jj];
  }
  __syncthreads();

  #pragma unroll
  for (int p2=0; p2<8; ++p2){                  // agg + store: 2048 tasks (t,w,c4)
    int task = tid + 256*p2;
    int c4 = task & 15, w = (task>>4)&7, t = task>>7;
    float4 acc = make_float4(0.f,0.f,0.f,0.f);
    #pragma unroll
    for (int k=0; k<2; ++k)
      #pragma unroll
      for (int v=0; v<8; ++v){
        float g = gL[(k*8+v)*8 + w];
        float4 h4 = *(const float4*)(hm + (t*8+v)*128 + k*64 + c4*4);
        acc.x = fmaf(g,h4.x,acc.x); acc.y = fmaf(g,h4.y,acc.y);
        acc.z = fmaf(g,h4.z,acc.z); acc.w = fmaf(g,h4.w,acc.w);
      }
    __hip_bfloat16* dst = E + ((size_t)t*SEQ + NAg + (size_t)n*8 + w)*64 + c4*4;
    ushort4 uo;
    uo.x = f2bf(acc.x); uo.y = f2bf(acc.y); uo.z = f2bf(acc.z); uo.w = f2bf(acc.w);
    *reinterpret_cast<ushort4*>(dst) = uo;
  }
}

// ---------------------------------------------------------------------------
// Encoder GRU over 36864 sequences x 16 steps (shared weights), h kept in LDS.
// Block: 64 seqs, 256 threads; thread = 4 i (ip,ip+16,ip+32,ip+48) x 4 s.
// ---------------------------------------------------------------------------
__global__ __launch_bounds__(256,1) void k_gru_enc(
    const __hip_bfloat16* __restrict__ E,
    const float* __restrict__ Wih, const float* __restrict__ Whh,
    const float* __restrict__ bih, const float* __restrict__ bhh,
    float* __restrict__ h_all)
{
  __shared__ float4 WIT[16*192];      // [k4][j]  transposed-packed Wih
  __shared__ float4 WHT[16*192];      // [k4][j]
  __shared__ float  xsb[64*ESTR];
  __shared__ float  hsb[64*ESTR];
  __shared__ float  bihL[192], bhhL[192];
  const int tid = threadIdx.x;
  const size_t s0 = (size_t)blockIdx.x * 64;

  for (int idx=tid; idx<3072; idx+=256){
    int j = idx % 192, k4 = idx / 192;
    WIT[idx] = *(const float4*)(Wih + (size_t)j*64 + k4*4);
    WHT[idx] = *(const float4*)(Whh + (size_t)j*64 + k4*4);
  }
  if (tid < 192){ bihL[tid] = bih[tid]; bhhL[tid] = bhh[tid]; }
  for (int idx=tid; idx<64*ESTR; idx+=256) hsb[idx] = 0.f;
  __syncthreads();

  const int ip = tid & 15;
  const int sg = tid >> 4;            // 0..15
  const int sB = sg*4;
  const unsigned short* Eu = reinterpret_cast<const unsigned short*>(E);

  for (int t=0; t<T_OBS; ++t){
    for (int ch=tid; ch<1024; ch+=256){            // stage x tile (bf16 -> f32)
      int s = ch >> 4, c4 = ch & 15;
      ushort4 u = *(const ushort4*)(Eu + ((size_t)t*SEQ + s0 + s)*64 + c4*4);
      float* d = xsb + s*ESTR + c4*4;
      d[0]=bf2f(u.x); d[1]=bf2f(u.y); d[2]=bf2f(u.z); d[3]=bf2f(u.w);
    }
    __syncthreads();

    float aR[4][4], aZ[4][4], aN[4][4], aHN[4][4];
    #pragma unroll
    for (int q=0; q<4; ++q){ int i = ip + q*16;
      #pragma unroll
      for (int u=0; u<4; ++u){
        aR[q][u] = bihL[i]     + bhhL[i];
        aZ[q][u] = bihL[64+i]  + bhhL[64+i];
        aN[q][u] = bihL[128+i];
        aHN[q][u]= bhhL[128+i];
      }
    }
    for (int k4=0; k4<16; ++k4){                   // gi += x @ Wih.T
      float4 xv[4];
      #pragma unroll
      for (int u=0; u<4; ++u) xv[u] = *(const float4*)(xsb + (sB+u)*ESTR + k4*4);
      const float4* Wk = WIT + k4*192;
      #pragma unroll
      for (int q=0; q<4; ++q){ int i = ip + q*16;
        float4 wr = Wk[i], wz = Wk[64+i], wn = Wk[128+i];
        #pragma unroll
        for (int u=0; u<4; ++u){
          aR[q][u] = dot4f(wr, xv[u], aR[q][u]);
          aZ[q][u] = dot4f(wz, xv[u], aZ[q][u]);
          aN[q][u] = dot4f(wn, xv[u], aN[q][u]);
        }
      }
    }
    for (int k4=0; k4<16; ++k4){                   // gh += h @ Whh.T
      float4 hv[4];
      #pragma unroll
      for (int u=0; u<4; ++u) hv[u] = *(const float4*)(hsb + (sB+u)*ESTR + k4*4);
      const float4* Wk = WHT + k4*192;
      #pragma unroll
      for (int q=0; q<4; ++q){ int i = ip + q*16;
        float4 wr = Wk[i], wz = Wk[64+i], wn = Wk[128+i];
        #pragma unroll
        for (int u=0; u<4; ++u){
          aR[q][u]  = dot4f(wr, hv[u], aR[q][u]);
          aZ[q][u]  = dot4f(wz, hv[u], aZ[q][u]);
          aHN[q][u] = dot4f(wn, hv[u], aHN[q][u]);
        }
      }
    }
    float hnew[4][4];
    #pragma unroll
    for (int q=0; q<4; ++q){ int i = ip + q*16;
      #pragma unroll
      for (int u=0; u<4; ++u){
        float r  = sigf(aR[q][u]);
        float z  = sigf(aZ[q][u]);
        float nn = tanhf_(fmaf(r, aHN[q][u], aN[q][u]));
        float ho = hsb[(sB+u)*ESTR + i];
        hnew[q][u] = fmaf(z, ho - nn, nn);         // (1-z)*n + z*h
      }
    }
    __syncthreads();
    #pragma unroll
    for (int q=0; q<4; ++q){ int i = ip + q*16;
      #pragma unroll
      for (int u=0; u<4; ++u) hsb[(sB+u)*ESTR + i] = hnew[q][u];
    }
    __syncthreads();
  }
  #pragma unroll
  for (int q=0; q<4; ++q){ int i = ip + q*16;
    #pragma unroll
    for (int u=0; u<4; ++u)
      h_all[(s0 + sB + u)*64 + i] = hsb[(sB+u)*ESTR + i];
  }
}

// ---------------------------------------------------------------------------
// x_s = leaky(h_x @ hid_W.T + hid_b) -> xc[:, 0:32]
// ---------------------------------------------------------------------------
__global__ void k_xs(const float* __restrict__ h_all, const float* __restrict__ hidW,
                     const float* __restrict__ hidb, float* __restrict__ xc){
  int idx = blockIdx.x*blockDim.x + threadIdx.x;   // 4096*32
  int j = idx & 31, n = idx >> 5;
  const float* h = h_all + (size_t)n*64;
  const float* w = hidW + (size_t)j*64;
  float acc = hidb[j];
  for (int k4=0; k4<16; ++k4)
    acc = dot4f(*(const float4*)(h + k4*4), *(const float4*)(w + k4*4), acc);
  xc[(size_t)n*112 + j] = leakyf(acc);
}

// ---------------------------------------------------------------------------
// Social branch: sparse scatter (8 nonzero cells) + conv(3x3) + conv(3x1)
// + maxpool -> xc[:, 32:112].  4 agents per block, one wave per agent.
// ---------------------------------------------------------------------------
__global__ __launch_bounds__(256,1) void k_soc(
    const float* __restrict__ h_all, const int* __restrict__ cells,
    const unsigned short* __restrict__ W1r, const float* __restrict__ socb,
    const float* __restrict__ c31W, const float* __restrict__ c31b,
    float* __restrict__ xc)
{
  __shared__ unsigned short W1L[9*64*ESTR];   // [kk][o][c pad68] bf16
  __shared__ float W2L[64*48];                // [o][ky][p]
  __shared__ float hv[4][8][64];
  __shared__ float out1[4][64][12];
  __shared__ float out2[4][16][9];
  __shared__ int   cellsL[4][8];
  __shared__ float b2L[16];
  const int tid = threadIdx.x;
  const int n0 = blockIdx.x * 4;

  {
    const uint4* src = reinterpret_cast<const uint4*>(W1r);
    uint4* dst = reinterpret_cast<uint4*>(W1L);
    for (int idx=tid; idx<(9*64*ESTR)/8; idx+=256) dst[idx] = src[idx];
  }
  {
    const float* hsrc = h_all + ((size_t)NAg + (size_t)n0*8)*64;
    float* hdst = &hv[0][0][0];
    for (int idx=tid; idx<2048; idx+=256) hdst[idx] = hsrc[idx];
  }
  for (int idx=tid; idx<3072; idx+=256){
    int p = idx/192, rem = idx%192, o = rem/3, ky = rem%3;
    W2L[(o*3+ky)*16 + p] = c31W[idx];
  }
  if (tid < 16) b2L[tid] = c31b[tid];
  if (tid < 32){ int ag = tid>>3, v = tid&7; cellsL[ag][v] = cells[(n0+ag)*8 + v]; }
  for (int idx=tid; idx<2816; idx+=256){
    int y = idx%11, o = (idx/11)&63, ag = idx/704;
    out1[ag][o][y] = socb[o];
  }
  __syncthreads();

  const int ag = tid >> 6;      // wave id = agent
  const int o  = tid & 63;
  for (int v=0; v<8; ++v){
    int cc = cellsL[ag][v];
    int gw = cc/13, gh = cc%13;
    const float* hvv = hv[ag][v];
    #pragma unroll
    for (int ky=0; ky<3; ++ky){
      int y = gh - ky;
      if (0 <= y && y < 11){
        const unsigned short* wp = W1L + ((ky*3+gw)*64 + o)*ESTR;
        float acc = 0.f;
        #pragma unroll
        for (int c4=0; c4<16; ++c4){
          ushort4 wv = *(const ushort4*)(wp + c4*4);
          float4  h4 = *(const float4*)(hvv + c4*4);
          acc = fmaf(h4.x, bf2f(wv.x), fmaf(h4.y, bf2f(wv.y),
                fmaf(h4.z, bf2f(wv.z), fmaf(h4.w, bf2f(wv.w), acc))));
        }
        out1[ag][o][y] += acc;
      }
    }
  }
  __syncthreads();
  for (int idx=tid; idx<2816; idx+=256){
    int y = idx%11, oo = (idx/11)&63, a2 = idx/704;
    out1[a2][oo][y] = leakyf(out1[a2][oo][y]);
  }
  __syncthreads();

  #pragma unroll
  for (int pass=0; pass<3; ++pass){              // conv2 (3x1) + leaky
    int l = tid & 63;
    int p = l & 15, y2 = (l >> 4) + pass*4;
    if (y2 < 9){
      float acc = b2L[p];
      for (int oo=0; oo<64; ++oo){
        const float* o1 = &out1[ag][oo][y2];
        const float* w2 = &W2L[oo*48 + p];
        acc = fmaf(o1[0], w2[0], fmaf(o1[1], w2[16], fmaf(o1[2], w2[32], acc)));
      }
      out2[ag][p][y2] = leakyf(acc);
    }
  }
  __syncthreads();

  for (int idx=tid; idx<320; idx+=256){          // maxpool (pad -inf, win 2 str 2)
    int e = idx % 80, a2 = idx / 80;
    int p = e/5, w = e%5;
    float val = (w==0) ? out2[a2][p][0]
                       : fmaxf(out2[a2][p][2*w-1], out2[a2][p][2*w]);
    xc[(size_t)(n0+a2)*112 + 32 + e] = val;
  }
}

// ---------------------------------------------------------------------------
// Decoder GRU (input constant over 25 steps => gi computed once) + out head.
// Block: 16 seqs, 256 threads; thread = 2 i (ih, ih+64) x 4 s.
// ---------------------------------------------------------------------------
__global__ __launch_bounds__(256,1) void k_dec(
    const float* __restrict__ xc, const uint2* __restrict__ WhhP,
    const float* __restrict__ dWih, const float* __restrict__ dbih,
    const float* __restrict__ dbhh, const float* __restrict__ outW,
    const float* __restrict__ outb, float* __restrict__ out)
{
  __shared__ uint2 WH[32*384];          // [k4][j], 4 bf16 each
  __shared__ float gi[16*GSTR];
  __shared__ float hsb[16*HSTR];
  __shared__ float xct[16*XSTR];
  __shared__ float oW[5*HSTR];
  __shared__ float ob[5];
  __shared__ float bhhL[384];
  const int tid = threadIdx.x;
  const int n0 = blockIdx.x * 16;

  for (int idx=tid; idx<12288; idx+=256) WH[idx] = WhhP[idx];
  for (int idx=tid; idx<16*112; idx+=256){
    int s = idx/112, k = idx%112;
    xct[s*XSTR + k] = xc[(size_t)(n0+s)*112 + k];
  }
  for (int idx=tid; idx<640; idx+=256) oW[(idx>>7)*HSTR + (idx&127)] = outW[idx];
  if (tid < 5) ob[tid] = outb[tid];
  for (int idx=tid; idx<384; idx+=256) bhhL[idx] = dbhh[idx];
  for (int idx=tid; idx<16*HSTR; idx+=256) hsb[idx] = 0.f;
  __syncthreads();

  {                                      // gi = xc @ dec_Wih.T + dec_bih (once)
    int s = tid & 15, jq = tid >> 4;
    for (int jj=0; jj<24; ++jj){
      int j = jq*24 + jj;
      float acc = dbih[j];
      const float* w  = dWih + (size_t)j*112;
      const float* xr = xct + s*XSTR;
      for (int k4=0; k4<28; ++k4)
        acc = dot4f(*(const float4*)(w + k4*4), *(const float4*)(xr + k4*4), acc);
      gi[s*GSTR + j] = acc;
    }
  }
  __syncthreads();

  const int ih = tid & 63;
  const int sg = tid >> 6;               // 0..3
  const int sB = sg*4;

  for (int t=0; t<PRED; ++t){
    float aR[2][4], aZ[2][4], aHN[2][4];
    #pragma unroll
    for (int q=0; q<2; ++q){ int i = ih + q*64;
      #pragma unroll
      for (int u=0; u<4; ++u){ aR[q][u]=bhhL[i]; aZ[q][u]=bhhL[128+i]; aHN[q][u]=bhhL[256+i]; }
    }
    for (int k4=0; k4<32; ++k4){
      float4 hv[4];
      #pragma unroll
      for (int u=0; u<4; ++u) hv[u] = *(const float4*)(hsb + (sB+u)*HSTR + k4*4);
      const uint2* Wk = WH + k4*384;
      #pragma unroll
      for (int q=0; q<2; ++q){ int i = ih + q*64;
        uint2 wr = Wk[i], wz = Wk[128+i], wn = Wk[256+i];
        float r0=bflo(wr.x), r1=bfhi(wr.x), r2=bflo(wr.y), r3=bfhi(wr.y);
        float z0=bflo(wz.x), z1=bfhi(wz.x), z2=bflo(wz.y), z3=bfhi(wz.y);
        float n0_=bflo(wn.x), n1=bfhi(wn.x), n2=bflo(wn.y), n3=bfhi(wn.y);
        #pragma unroll
        for (int u=0; u<4; ++u){
          aR[q][u]  = fmaf(r0,hv[u].x, fmaf(r1,hv[u].y, fmaf(r2,hv[u].z, fmaf(r3,hv[u].w, aR[q][u]))));
          aZ[q][u]  = fmaf(z0,hv[u].x, fmaf(z1,hv[u].y, fmaf(z2,hv[u].z, fmaf(z3,hv[u].w, aZ[q][u]))));
          aHN[q][u] = fmaf(n0_,hv[u].x,fmaf(n1,hv[u].y, fmaf(n2,hv[u].z, fmaf(n3,hv[u].w, aHN[q][u]))));
        }
      }
    }
    float hnew[2][4];
    #pragma unroll
    for (int q=0; q<2; ++q){ int i = ih + q*64;
      #pragma unroll
      for (int u=0; u<4; ++u){
        int s = sB + u;
        float r  = sigf(gi[s*GSTR + i]       + aR[q][u]);
        float z  = sigf(gi[s*GSTR + 128 + i] + aZ[q][u]);
        float nn = tanhf_(fmaf(r, aHN[q][u], gi[s*GSTR + 256 + i]));
        float ho = hsb[s*HSTR + i];
        hnew[q][u] = fmaf(z, ho - nn, nn);
      }
    }
    __syncthreads();
    #pragma unroll
    for (int q=0; q<2; ++q){ int i = ih + q*64;
      #pragma unroll
      for (int u=0; u<4; ++u) hsb[(sB+u)*HSTR + i] = hnew[q][u];
    }
    __syncthreads();
    if (tid < 80){                        // output head: o = hs@out_W.T+out_b
      int s = tid/5, oo = tid%5;
      float acc = ob[oo];
      const float* hr = hsb + s*HSTR;
      const float* wr = oW + oo*HSTR;
      for (int k4=0; k4<32; ++k4)
        acc = dot4f(*(const float4*)(hr + k4*4), *(const float4*)(wr + k4*4), acc);
      float val = (oo < 2) ? acc : (oo == 4 ? tanhf_(acc) : __expf(acc));
      out[((size_t)t*NAg + n0 + s)*5 + oo] = val;
    }
    __syncthreads();
  }
}

// ---------------------------------------------------------------------------
extern "C" void kernel_launch(void* const* d_in, const int* in_sizes, int n_in,
                              void* d_out, int out_size, void* d_ws, size_t ws_size,
                              hipStream_t stream)
{
  const float* x      = (const float*)d_in[0];
  const float* ngbrs  = (const float*)d_in[1];
  const float* graphs = (const float*)d_in[2];
  const void*  masks  = d_in[3];
  // d_in[4] = ngbrs_idx (unused by the reference computation)
  const float* dynW   = (const float*)d_in[5];
  const float* dynb   = (const float*)d_in[6];
  const float* eWih   = (const float*)d_in[7];
  const float* eWhh   = (const float*)d_in[8];
  const float* ebih   = (const float*)d_in[9];
  const float* ebhh   = (const float*)d_in[10];
  const float* sW     = (const float*)d_in[11];
  const float* sb     = (const float*)d_in[12];
  const float* hidW   = (const float*)d_in[13];
  const float* hidb   = (const float*)d_in[14];
  const float* socW   = (const float*)d_in[15];
  const float* socb   = (const float*)d_in[16];
  const float* c31W   = (const float*)d_in[17];
  const float* c31b   = (const float*)d_in[18];
  const float* dWih   = (const float*)d_in[19];
  const float* dWhh   = (const float*)d_in[20];
  const float* dbih   = (const float*)d_in[21];
  const float* dbhh   = (const float*)d_in[22];
  const float* outW   = (const float*)d_in[23];
  const float* outb   = (const float*)d_in[24];
  float* out = (float*)d_out;

  char* ws = (char*)d_ws;
  size_t off = 0;
  __hip_bfloat16* E = (__hip_bfloat16*)(ws + off); off += (size_t)T_OBS*SEQ*64*2;   // 75.5 MB
  float* h_all      = (float*)(ws + off);          off += (size_t)SEQ*64*4;          // 9.4 MB
  int*   cells      = (int*)(ws + off);            off += (size_t)NAg*8*4;
  float* xc         = (float*)(ws + off);          off += (size_t)NAg*112*4;
  unsigned short* W1r = (unsigned short*)(ws + off); off += (size_t)9*64*ESTR*2;
  uint2* WhhP       = (uint2*)(ws + off);          off += (size_t)12288*8;

  k_decode_masks<<<16, 256, 0, stream>>>(masks, cells);
  k_prep<<<144, 256, 0, stream>>>(socW, W1r, dWhh, WhhP);
  k_embed_x<<<16384, 256, 0, stream>>>(x, dynW, dynb, E);
  k_embed_agg<<<4096, 256, 0, stream>>>(ngbrs, graphs, dynW, dynb, sW, sb, E);
  k_gru_enc<<<576, 256, 0, stream>>>(E, eWih, eWhh, ebih, ebhh, h_all);
  k_xs<<<512, 256, 0, stream>>>(h_all, hidW, hidb, xc);
  k_soc<<<1024, 256, 0, stream>>>(h_all, cells, W1r, socb, c31W, c31b, xc);
  k_dec<<<256, 256, 0, stream>>>(xc, WhhP, dWih, dbih, dbhh, outW, outb, out);
}

// Round 3
// 840.727 us; speedup vs baseline: 1.6255x; 1.6255x over previous
//
#include <hip/hip_runtime.h>
#include <hip/hip_bf16.h>

#define T_OBS 16
#define NAg   4096
#define Vn    8
#define NV    32768           // NAg*Vn
#define SEQ   36864           // NAg + NV
#define PRED  25
#define ESTR  68              // padded LDS stride for 64-wide seq tiles
#define HSTR  132             // padded LDS stride for 128-wide dec hidden
#define GSTR  388             // padded LDS stride for 384-wide gi
#define XSTR  116             // padded LDS stride for 112-wide xc tile

typedef __bf16 bf16x8 __attribute__((ext_vector_type(8)));
typedef float  f32x4  __attribute__((ext_vector_type(4)));

__device__ __forceinline__ float leakyf(float v){ return v >= 0.f ? v : 0.1f*v; }
__device__ __forceinline__ float sigf(float x){ return 1.f/(1.f+__expf(-x)); }
__device__ __forceinline__ float tanhf_(float x){
  x = fminf(fmaxf(x, -10.f), 10.f);
  float e = __expf(2.f*x);
  return (e-1.f)/(e+1.f);
}
__device__ __forceinline__ float bf2f(unsigned short u){
  union{unsigned int i; float f;} v; v.i = ((unsigned int)u)<<16; return v.f;
}
__device__ __forceinline__ unsigned short f2bf(float f){
  __hip_bfloat16 b = __float2bfloat16(f);
  return *reinterpret_cast<unsigned short*>(&b);
}
__device__ __forceinline__ float bflo(unsigned int u){ union{unsigned int i; float f;} v; v.i = u<<16; return v.f; }
__device__ __forceinline__ float bfhi(unsigned int u){ union{unsigned int i; float f;} v; v.i = u & 0xffff0000u; return v.f; }
__device__ __forceinline__ float dot4f(float4 a, float4 b, float acc){
  return fmaf(a.x,b.x, fmaf(a.y,b.y, fmaf(a.z,b.z, fmaf(a.w,b.w, acc))));
}
__device__ __forceinline__ bf16x8 as_bf16x8(uint4 u){
  union { uint4 a; bf16x8 b; } v; v.a = u; return v.b;
}

// ---------------------------------------------------------------------------
// Decode bool masks -> per-agent 8 selected cell indices.
// ---------------------------------------------------------------------------
__global__ void k_decode_masks(const void* __restrict__ masks, int* __restrict__ cells){
  int n = blockIdx.x*blockDim.x + threadIdx.x;
  if (n >= NAg) return;
  const unsigned char* m8  = (const unsigned char*)masks;
  const int*           m32 = (const int*)masks;
  int tmp[8]; for (int v=0; v<8; ++v) tmp[v] = 0;
  int cnt = 0;
  for (int cc=0; cc<39; ++cc){                 // u8 interpretation (bool bytes)
    size_t base = ((size_t)n*39 + cc)*64;
    if (m8[base] && m8[base+1] && m8[base+33]){ if (cnt<8) tmp[cnt]=cc; cnt++; }
  }
  if (cnt != 8){                               // fallback: 4-byte elements
    cnt = 0;
    for (int cc=0; cc<39; ++cc){
      size_t base = ((size_t)n*39 + cc)*64;
      if (m32[base] != 0){ if (cnt<8) tmp[cnt]=cc; cnt++; }
    }
  }
  for (int v=0; v<8; ++v) cells[n*8+v] = tmp[v];
}

// ---------------------------------------------------------------------------
// One-shot weight re-layouts:
//  W1r : soc_W f32 -> bf16 [kk][o][c pad 68]
//  WhhP: dec_Whh f32 -> uint2[k4][384] (4 packed bf16)
//  Wpk : encoder Wih/Whh -> MFMA B-fragments, bf16.
//        frag f<32 : combined [x|h] K=128 for r,z gates: nt=f>>2 (0..7), kk=f&3
//        f=32..39  : Wih n-gate: nt=8+((f-32)>>1), kk=(f-32)&1
//        f=40..47  : Whh n-gate: nt=8+((f-40)>>1), kk=(f-40)&1
//        element (f, lane l, j): B[k][n], n = nt*16+(l&15), k = kk*32+(l>>4)*8+j
// ---------------------------------------------------------------------------
__global__ void k_prep(const float* __restrict__ socW, unsigned short* __restrict__ W1r,
                       const float* __restrict__ dWhh, uint2* __restrict__ WhhP,
                       const float* __restrict__ eWih, const float* __restrict__ eWhh,
                       unsigned short* __restrict__ Wpk){
  int idx = blockIdx.x*blockDim.x + threadIdx.x;   // 36864 threads
  if (idx < 36864){
    int c  = idx & 63;
    int o  = (idx>>6) & 63;
    int kk = idx >> 12;                            // ky*3+kx, 0..8
    int ky = kk/3, kx = kk%3;
    W1r[(kk*64 + o)*ESTR + c] = f2bf(socW[(o*64 + c)*9 + ky*3 + kx]);
  }
  if (idx < 12288){
    int j  = idx % 384;
    int k4 = idx / 384;
    const float* p = dWhh + (size_t)j*128 + k4*4;
    uint2 u;
    u.x = (unsigned int)f2bf(p[0]) | ((unsigned int)f2bf(p[1])<<16);
    u.y = (unsigned int)f2bf(p[2]) | ((unsigned int)f2bf(p[3])<<16);
    WhhP[k4*384 + j] = u;
  }
  if (idx < 24576){                                // 48 frags * 512 elements
    int f   = idx >> 9;
    int rem = idx & 511;
    int l   = rem >> 3, j = rem & 7;
    int lr  = l & 15, lg = l >> 4;
    float val;
    if (f < 32){
      int nt = f >> 2, kk = f & 3;
      int n  = nt*16 + lr;                         // rows 0..127 = r,z gates
      int k  = kk*32 + lg*8 + j;
      val = (k < 64) ? eWih[(size_t)n*64 + k] : eWhh[(size_t)n*64 + (k-64)];
    } else if (f < 40){
      int q = f - 32;
      int n = (8 + (q>>1))*16 + lr;                // rows 128..191 = n gate
      int k = (q&1)*32 + lg*8 + j;
      val = eWih[(size_t)n*64 + k];
    } else {
      int q = f - 40;
      int n = (8 + (q>>1))*16 + lr;
      int k = (q&1)*32 + lg*8 + j;
      val = eWhh[(size_t)n*64 + k];
    }
    Wpk[f*512 + l*8 + j] = f2bf(val);
  }
}

// ---------------------------------------------------------------------------
// x_e = leaky(x @ dyn_W.T + dyn_b) -> E[t][0..4095][c] (bf16)
// ---------------------------------------------------------------------------
__global__ void k_embed_x(const float* __restrict__ x, const float* __restrict__ dynW,
                          const float* __restrict__ dynb, __hip_bfloat16* __restrict__ E){
  int idx = blockIdx.x*blockDim.x + threadIdx.x;   // 16*4096*64 exactly
  int c = idx & 63;
  int s = (idx >> 6) & 4095;
  int t = idx >> 18;
  float x0 = x[((size_t)t*NAg + s)*2 + 0];
  float x1 = x[((size_t)t*NAg + s)*2 + 1];
  float v = leakyf(fmaf(x0, dynW[c*2+0], fmaf(x1, dynW[c*2+1], dynb[c])));
  E[((size_t)t*SEQ + s)*64 + c] = __float2bfloat16(v);
}

// ---------------------------------------------------------------------------
// Per agent n: ng_e = leaky(dyn(ngbrs)), h = ng_e@sW.T+sb,
// agg[t,w,c] -> E[t][4096+n*8+w][c]
// ---------------------------------------------------------------------------
__global__ __launch_bounds__(256,1) void k_embed_agg(
    const float* __restrict__ ngbrs, const float* __restrict__ graphs,
    const float* __restrict__ dynW, const float* __restrict__ dynb,
    const float* __restrict__ sW, const float* __restrict__ sb,
    __hip_bfloat16* __restrict__ E)
{
  __shared__ float4 SW4[16*128];      // [c4][j]
  __shared__ float  nge[16*8*64];     // [t][v][c]
  __shared__ float  hm [16*8*128];    // [t][v][j]
  __shared__ float  gL[128];
  __shared__ float  sbL[128], dwL[128], dbL[64];
  const int tid = threadIdx.x;
  const int n = blockIdx.x;

  for (int idx=tid; idx<2048; idx+=256){
    int j = idx & 127, c4 = idx >> 7;
    SW4[c4*128 + j] = *(const float4*)(sW + (size_t)j*64 + c4*4);
  }
  if (tid < 128) gL[tid]  = graphs[(size_t)n*128 + tid];
  if (tid < 128) sbL[tid] = sb[tid];
  if (tid < 128) dwL[tid] = dynW[tid];
  if (tid < 64)  dbL[tid] = dynb[tid];
  __syncthreads();

  for (int idx=tid; idx<8192; idx+=256){       // nge
    int c = idx & 63, v = (idx>>6)&7, t = idx>>9;
    const float* p = ngbrs + ((size_t)t*NV + (size_t)n*8 + v)*2;
    nge[idx] = leakyf(fmaf(p[0], dwL[c*2], fmaf(p[1], dwL[c*2+1], dbL[c])));
  }
  __syncthreads();

  #pragma unroll
  for (int p2=0; p2<2; ++p2){                  // hm: 512 tasks (t, jb)
    int task = tid + 256*p2;
    int t = task >> 5, jb = task & 31;
    float acc[8][4];
    #pragma unroll
    for (int jj=0; jj<4; ++jj){ float b = sbL[jb + jj*32];
      #pragma unroll
      for (int v=0; v<8; ++v) acc[v][jj] = b; }
    for (int c4=0; c4<16; ++c4){
      float4 wv[4];
      #pragma unroll
      for (int jj=0; jj<4; ++jj) wv[jj] = SW4[c4*128 + jj*32 + jb];
      #pragma unroll
      for (int v=0; v<8; ++v){
        float4 xv = *(const float4*)(nge + (t*8+v)*64 + c4*4);
        #pragma unroll
        for (int jj=0; jj<4; ++jj) acc[v][jj] = dot4f(wv[jj], xv, acc[v][jj]);
      }
    }
    #pragma unroll
    for (int v=0; v<8; ++v)
      #pragma unroll
      for (int jj=0; jj<4; ++jj)
        hm[(t*8+v)*128 + jj*32 + jb] = acc[v][jj];
  }
  __syncthreads();

  #pragma unroll
  for (int p2=0; p2<8; ++p2){                  // agg + store
    int task = tid + 256*p2;
    int c4 = task & 15, w = (task>>4)&7, t = task>>7;
    float4 acc = make_float4(0.f,0.f,0.f,0.f);
    #pragma unroll
    for (int k=0; k<2; ++k)
      #pragma unroll
      for (int v=0; v<8; ++v){
        float g = gL[(k*8+v)*8 + w];
        float4 h4 = *(const float4*)(hm + (t*8+v)*128 + k*64 + c4*4);
        acc.x = fmaf(g,h4.x,acc.x); acc.y = fmaf(g,h4.y,acc.y);
        acc.z = fmaf(g,h4.z,acc.z); acc.w = fmaf(g,h4.w,acc.w);
      }
    __hip_bfloat16* dst = E + ((size_t)t*SEQ + NAg + (size_t)n*8 + w)*64 + c4*4;
    ushort4 uo;
    uo.x = f2bf(acc.x); uo.y = f2bf(acc.y); uo.z = f2bf(acc.z); uo.w = f2bf(acc.w);
    *reinterpret_cast<ushort4*>(dst) = uo;
  }
}

// ---------------------------------------------------------------------------
// Encoder GRU via MFMA. 1 wave = 16 seqs; 4 waves/block (fully independent,
// no barriers). Weights in VGPRs as pre-packed B-fragments (Wpk). x-fragments
// loaded straight from global E (A-layout contiguous); h round-trips through
// a 2KB/wave XOR-swizzled LDS tile (D-layout writes -> A-layout b128 reads).
// ---------------------------------------------------------------------------
__global__ __launch_bounds__(256,1) void k_gru_enc_mfma(
    const unsigned short* __restrict__ E,
    const unsigned short* __restrict__ Wpk,
    const float* __restrict__ bih, const float* __restrict__ bhh,
    float* __restrict__ h_all)
{
  __shared__ __align__(16) unsigned char hbuf[4*2048];
  const int tid = threadIdx.x;
  const int w  = tid >> 6;
  const int l  = tid & 63;
  const int lr = l & 15;           // A row / D col
  const int lg = l >> 4;           // k-group
  const size_t s0 = (size_t)blockIdx.x*64 + (size_t)w*16;

  // B fragments: 48 x uint4 = 192 VGPRs, resident for the whole kernel
  uint4 bf[48];
  #pragma unroll
  for (int f=0; f<48; ++f)
    bf[f] = *(const uint4*)(Wpk + f*512 + l*8);

  // per-lane biases (depend only on output column)
  float brz_r[4], brz_z[4], bni[4], bnh[4];
  #pragma unroll
  for (int nt=0; nt<4; ++nt){
    int i = nt*16 + lr;
    brz_r[nt] = bih[i]      + bhh[i];
    brz_z[nt] = bih[64+i]   + bhh[64+i];
    bni[nt]   = bih[128+i];
    bnh[nt]   = bhh[128+i];
  }

  unsigned char* hb = hbuf + w*2048;
  {
    uint4 z4 = make_uint4(0,0,0,0);
    *(uint4*)(hb + l*32)      = z4;
    *(uint4*)(hb + l*32 + 16) = z4;
  }

  float hreg[4][4];
  #pragma unroll
  for (int nt=0; nt<4; ++nt)
    #pragma unroll
    for (int j=0; j<4; ++j) hreg[nt][j] = 0.f;

  // prefetch x fragments for t=0
  uint4 ax0, ax1;
  {
    const unsigned short* p = E + (s0 + lr)*64 + lg*8;
    ax0 = *(const uint4*)(p);
    ax1 = *(const uint4*)(p + 32);
  }

  const int swz = (lr & 7) << 4;

  #pragma unroll 1
  for (int t=0; t<T_OBS; ++t){
    // issue next step's x loads early (prefetch)
    int tn = (t < 15) ? t+1 : 15;
    const unsigned short* pn = E + ((size_t)tn*SEQ + s0 + lr)*64 + lg*8;
    uint4 nx0 = *(const uint4*)(pn);
    uint4 nx1 = *(const uint4*)(pn + 32);

    // h fragments from LDS (A-layout, swizzled)
    int hbase = lr*128 + lg*16;
    uint4 ah0 = *(const uint4*)(hb + ((hbase     ) ^ swz));
    uint4 ah1 = *(const uint4*)(hb + ((hbase + 64) ^ swz));

    bf16x8 Ax0 = as_bf16x8(ax0), Ax1 = as_bf16x8(ax1);
    bf16x8 Ah0 = as_bf16x8(ah0), Ah1 = as_bf16x8(ah1);

    f32x4 accRZ[8], accNI[4], accNH[4];
    #pragma unroll
    for (int q=0; q<8; ++q) accRZ[q] = (f32x4){0.f,0.f,0.f,0.f};
    #pragma unroll
    for (int q=0; q<4; ++q){ accNI[q] = (f32x4){0.f,0.f,0.f,0.f}; accNH[q] = (f32x4){0.f,0.f,0.f,0.f}; }

    #pragma unroll
    for (int nt=0; nt<8; ++nt){
      accRZ[nt] = __builtin_amdgcn_mfma_f32_16x16x32_bf16(Ax0, as_bf16x8(bf[nt*4+0]), accRZ[nt], 0,0,0);
      accRZ[nt] = __builtin_amdgcn_mfma_f32_16x16x32_bf16(Ax1, as_bf16x8(bf[nt*4+1]), accRZ[nt], 0,0,0);
      accRZ[nt] = __builtin_amdgcn_mfma_f32_16x16x32_bf16(Ah0, as_bf16x8(bf[nt*4+2]), accRZ[nt], 0,0,0);
      accRZ[nt] = __builtin_amdgcn_mfma_f32_16x16x32_bf16(Ah1, as_bf16x8(bf[nt*4+3]), accRZ[nt], 0,0,0);
    }
    #pragma unroll
    for (int nt=0; nt<4; ++nt){
      accNI[nt] = __builtin_amdgcn_mfma_f32_16x16x32_bf16(Ax0, as_bf16x8(bf[32+nt*2+0]), accNI[nt], 0,0,0);
      accNI[nt] = __builtin_amdgcn_mfma_f32_16x16x32_bf16(Ax1, as_bf16x8(bf[32+nt*2+1]), accNI[nt], 0,0,0);
      accNH[nt] = __builtin_amdgcn_mfma_f32_16x16x32_bf16(Ah0, as_bf16x8(bf[40+nt*2+0]), accNH[nt], 0,0,0);
      accNH[nt] = __builtin_amdgcn_mfma_f32_16x16x32_bf16(Ah1, as_bf16x8(bf[40+nt*2+1]), accNH[nt], 0,0,0);
    }

    // epilogue: gates + h update; write h (bf16) to swizzled LDS tile
    #pragma unroll
    for (int nt=0; nt<4; ++nt){
      #pragma unroll
      for (int j=0; j<4; ++j){
        float r = sigf(accRZ[nt][j]   + brz_r[nt]);
        float z = sigf(accRZ[4+nt][j] + brz_z[nt]);
        float n = tanhf_(fmaf(r, accNH[nt][j] + bnh[nt], accNI[nt][j] + bni[nt]));
        float h = fmaf(z, hreg[nt][j] - n, n);
        hreg[nt][j] = h;
        int row = lg*4 + j;
        int boff = (row*128 + (nt*16 + lr)*2) ^ ((row & 7) << 4);
        *(unsigned short*)(hb + boff) = f2bf(h);
      }
    }
    ax0 = nx0; ax1 = nx1;
  }

  // final h -> h_all (f32)
  #pragma unroll
  for (int nt=0; nt<4; ++nt)
    #pragma unroll
    for (int j=0; j<4; ++j)
      h_all[(s0 + lg*4 + j)*64 + nt*16 + lr] = hreg[nt][j];
}

// ---------------------------------------------------------------------------
// x_s = leaky(h_x @ hid_W.T + hid_b) -> xc[:, 0:32]
// ---------------------------------------------------------------------------
__global__ void k_xs(const float* __restrict__ h_all, const float* __restrict__ hidW,
                     const float* __restrict__ hidb, float* __restrict__ xc){
  int idx = blockIdx.x*blockDim.x + threadIdx.x;   // 4096*32
  int j = idx & 31, n = idx >> 5;
  const float* h = h_all + (size_t)n*64;
  const float* w = hidW + (size_t)j*64;
  float acc = hidb[j];
  for (int k4=0; k4<16; ++k4)
    acc = dot4f(*(const float4*)(h + k4*4), *(const float4*)(w + k4*4), acc);
  xc[(size_t)n*112 + j] = leakyf(acc);
}

// ---------------------------------------------------------------------------
// Social branch: sparse scatter + conv(3x3) + conv(3x1) + maxpool -> xc[:,32:112]
// ---------------------------------------------------------------------------
__global__ __launch_bounds__(256,1) void k_soc(
    const float* __restrict__ h_all, const int* __restrict__ cells,
    const unsigned short* __restrict__ W1r, const float* __restrict__ socb,
    const float* __restrict__ c31W, const float* __restrict__ c31b,
    float* __restrict__ xc)
{
  __shared__ unsigned short W1L[9*64*ESTR];   // [kk][o][c pad68] bf16
  __shared__ float W2L[64*48];                // [o][ky][p]
  __shared__ float hv[4][8][64];
  __shared__ float out1[4][64][12];
  __shared__ float out2[4][16][9];
  __shared__ int   cellsL[4][8];
  __shared__ float b2L[16];
  const int tid = threadIdx.x;
  const int n0 = blockIdx.x * 4;

  {
    const uint4* src = reinterpret_cast<const uint4*>(W1r);
    uint4* dst = reinterpret_cast<uint4*>(W1L);
    for (int idx=tid; idx<(9*64*ESTR)/8; idx+=256) dst[idx] = src[idx];
  }
  {
    const float* hsrc = h_all + ((size_t)NAg + (size_t)n0*8)*64;
    float* hdst = &hv[0][0][0];
    for (int idx=tid; idx<2048; idx+=256) hdst[idx] = hsrc[idx];
  }
  for (int idx=tid; idx<3072; idx+=256){
    int p = idx/192, rem = idx%192, o = rem/3, ky = rem%3;
    W2L[(o*3+ky)*16 + p] = c31W[idx];
  }
  if (tid < 16) b2L[tid] = c31b[tid];
  if (tid < 32){ int ag = tid>>3, v = tid&7; cellsL[ag][v] = cells[(n0+ag)*8 + v]; }
  for (int idx=tid; idx<2816; idx+=256){
    int y = idx%11, o = (idx/11)&63, ag = idx/704;
    out1[ag][o][y] = socb[o];
  }
  __syncthreads();

  const int ag = tid >> 6;      // wave id = agent
  const int o  = tid & 63;
  for (int v=0; v<8; ++v){
    int cc = cellsL[ag][v];
    int gw = cc/13, gh = cc%13;
    const float* hvv = hv[ag][v];
    #pragma unroll
    for (int ky=0; ky<3; ++ky){
      int y = gh - ky;
      if (0 <= y && y < 11){
        const unsigned short* wp = W1L + ((ky*3+gw)*64 + o)*ESTR;
        float acc = 0.f;
        #pragma unroll
        for (int c4=0; c4<16; ++c4){
          ushort4 wv = *(const ushort4*)(wp + c4*4);
          float4  h4 = *(const float4*)(hvv + c4*4);
          acc = fmaf(h4.x, bf2f(wv.x), fmaf(h4.y, bf2f(wv.y),
                fmaf(h4.z, bf2f(wv.z), fmaf(h4.w, bf2f(wv.w), acc))));
        }
        out1[ag][o][y] += acc;
      }
    }
  }
  __syncthreads();
  for (int idx=tid; idx<2816; idx+=256){
    int y = idx%11, oo = (idx/11)&63, a2 = idx/704;
    out1[a2][oo][y] = leakyf(out1[a2][oo][y]);
  }
  __syncthreads();

  #pragma unroll
  for (int pass=0; pass<3; ++pass){              // conv2 (3x1) + leaky
    int lcl = tid & 63;
    int p = lcl & 15, y2 = (lcl >> 4) + pass*4;
    if (y2 < 9){
      float acc = b2L[p];
      for (int oo=0; oo<64; ++oo){
        const float* o1 = &out1[ag][oo][y2];
        const float* w2 = &W2L[oo*48 + p];
        acc = fmaf(o1[0], w2[0], fmaf(o1[1], w2[16], fmaf(o1[2], w2[32], acc)));
      }
      out2[ag][p][y2] = leakyf(acc);
    }
  }
  __syncthreads();

  for (int idx=tid; idx<320; idx+=256){          // maxpool
    int e = idx % 80, a2 = idx / 80;
    int p = e/5, w2 = e%5;
    float val = (w2==0) ? out2[a2][p][0]
                        : fmaxf(out2[a2][p][2*w2-1], out2[a2][p][2*w2]);
    xc[(size_t)(n0+a2)*112 + 32 + e] = val;
  }
}

// ---------------------------------------------------------------------------
// Decoder GRU (gi computed once) + out head.
// ---------------------------------------------------------------------------
__global__ __launch_bounds__(256,1) void k_dec(
    const float* __restrict__ xc, const uint2* __restrict__ WhhP,
    const float* __restrict__ dWih, const float* __restrict__ dbih,
    const float* __restrict__ dbhh, const float* __restrict__ outW,
    const float* __restrict__ outb, float* __restrict__ out)
{
  __shared__ uint2 WH[32*384];          // [k4][j], 4 bf16 each
  __shared__ float gi[16*GSTR];
  __shared__ float hsb[16*HSTR];
  __shared__ float xct[16*XSTR];
  __shared__ float oW[5*HSTR];
  __shared__ float ob[5];
  __shared__ float bhhL[384];
  const int tid = threadIdx.x;
  const int n0 = blockIdx.x * 16;

  for (int idx=tid; idx<12288; idx+=256) WH[idx] = WhhP[idx];
  for (int idx=tid; idx<16*112; idx+=256){
    int s = idx/112, k = idx%112;
    xct[s*XSTR + k] = xc[(size_t)(n0+s)*112 + k];
  }
  for (int idx=tid; idx<640; idx+=256) oW[(idx>>7)*HSTR + (idx&127)] = outW[idx];
  if (tid < 5) ob[tid] = outb[tid];
  for (int idx=tid; idx<384; idx+=256) bhhL[idx] = dbhh[idx];
  for (int idx=tid; idx<16*HSTR; idx+=256) hsb[idx] = 0.f;
  __syncthreads();

  {                                      // gi = xc @ dec_Wih.T + dec_bih (once)
    int s = tid & 15, jq = tid >> 4;
    for (int jj=0; jj<24; ++jj){
      int j = jq*24 + jj;
      float acc = dbih[j];
      const float* w  = dWih + (size_t)j*112;
      const float* xr = xct + s*XSTR;
      for (int k4=0; k4<28; ++k4)
        acc = dot4f(*(const float4*)(w + k4*4), *(const float4*)(xr + k4*4), acc);
      gi[s*GSTR + j] = acc;
    }
  }
  __syncthreads();

  const int ih = tid & 63;
  const int sg = tid >> 6;               // 0..3
  const int sB = sg*4;

  for (int t=0; t<PRED; ++t){
    float aR[2][4], aZ[2][4], aHN[2][4];
    #pragma unroll
    for (int q=0; q<2; ++q){ int i = ih + q*64;
      #pragma unroll
      for (int u=0; u<4; ++u){ aR[q][u]=bhhL[i]; aZ[q][u]=bhhL[128+i]; aHN[q][u]=bhhL[256+i]; }
    }
    for (int k4=0; k4<32; ++k4){
      float4 hv[4];
      #pragma unroll
      for (int u=0; u<4; ++u) hv[u] = *(const float4*)(hsb + (sB+u)*HSTR + k4*4);
      const uint2* Wk = WH + k4*384;
      #pragma unroll
      for (int q=0; q<2; ++q){ int i = ih + q*64;
        uint2 wr = Wk[i], wz = Wk[128+i], wn = Wk[256+i];
        float r0=bflo(wr.x), r1=bfhi(wr.x), r2=bflo(wr.y), r3=bfhi(wr.y);
        float z0=bflo(wz.x), z1=bfhi(wz.x), z2=bflo(wz.y), z3=bfhi(wz.y);
        float n0_=bflo(wn.x), n1=bfhi(wn.x), n2=bflo(wn.y), n3=bfhi(wn.y);
        #pragma unroll
        for (int u=0; u<4; ++u){
          aR[q][u]  = fmaf(r0,hv[u].x, fmaf(r1,hv[u].y, fmaf(r2,hv[u].z, fmaf(r3,hv[u].w, aR[q][u]))));
          aZ[q][u]  = fmaf(z0,hv[u].x, fmaf(z1,hv[u].y, fmaf(z2,hv[u].z, fmaf(z3,hv[u].w, aZ[q][u]))));
          aHN[q][u] = fmaf(n0_,hv[u].x,fmaf(n1,hv[u].y, fmaf(n2,hv[u].z, fmaf(n3,hv[u].w, aHN[q][u]))));
        }
      }
    }
    float hnew[2][4];
    #pragma unroll
    for (int q=0; q<2; ++q){ int i = ih + q*64;
      #pragma unroll
      for (int u=0; u<4; ++u){
        int s = sB + u;
        float r  = sigf(gi[s*GSTR + i]       + aR[q][u]);
        float z  = sigf(gi[s*GSTR + 128 + i] + aZ[q][u]);
        float nn = tanhf_(fmaf(r, aHN[q][u], gi[s*GSTR + 256 + i]));
        float ho = hsb[s*HSTR + i];
        hnew[q][u] = fmaf(z, ho - nn, nn);
      }
    }
    __syncthreads();
    #pragma unroll
    for (int q=0; q<2; ++q){ int i = ih + q*64;
      #pragma unroll
      for (int u=0; u<4; ++u) hsb[(sB+u)*HSTR + i] = hnew[q][u];
    }
    __syncthreads();
    if (tid < 80){                        // output head
      int s = tid/5, oo = tid%5;
      float acc = ob[oo];
      const float* hr = hsb + s*HSTR;
      const float* wr = oW + oo*HSTR;
      for (int k4=0; k4<32; ++k4)
        acc = dot4f(*(const float4*)(hr + k4*4), *(const float4*)(wr + k4*4), acc);
      float val = (oo < 2) ? acc : (oo == 4 ? tanhf_(acc) : __expf(acc));
      out[((size_t)t*NAg + n0 + s)*5 + oo] = val;
    }
    __syncthreads();
  }
}

// ---------------------------------------------------------------------------
extern "C" void kernel_launch(void* const* d_in, const int* in_sizes, int n_in,
                              void* d_out, int out_size, void* d_ws, size_t ws_size,
                              hipStream_t stream)
{
  const float* x      = (const float*)d_in[0];
  const float* ngbrs  = (const float*)d_in[1];
  const float* graphs = (const float*)d_in[2];
  const void*  masks  = d_in[3];
  // d_in[4] = ngbrs_idx (unused by the reference computation)
  const float* dynW   = (const float*)d_in[5];
  const float* dynb   = (const float*)d_in[6];
  const float* eWih   = (const float*)d_in[7];
  const float* eWhh   = (const float*)d_in[8];
  const float* ebih   = (const float*)d_in[9];
  const float* ebhh   = (const float*)d_in[10];
  const float* sW     = (const float*)d_in[11];
  const float* sb     = (const float*)d_in[12];
  const float* hidW   = (const float*)d_in[13];
  const float* hidb   = (const float*)d_in[14];
  const float* socW   = (const float*)d_in[15];
  const float* socb   = (const float*)d_in[16];
  const float* c31W   = (const float*)d_in[17];
  const float* c31b   = (const float*)d_in[18];
  const float* dWih   = (const float*)d_in[19];
  const float* dWhh   = (const float*)d_in[20];
  const float* dbih   = (const float*)d_in[21];
  const float* dbhh   = (const float*)d_in[22];
  const float* outW   = (const float*)d_in[23];
  const float* outb   = (const float*)d_in[24];
  float* out = (float*)d_out;

  char* ws = (char*)d_ws;
  size_t off = 0;
  __hip_bfloat16* E = (__hip_bfloat16*)(ws + off); off += (size_t)T_OBS*SEQ*64*2;   // 75.5 MB
  float* h_all      = (float*)(ws + off);          off += (size_t)SEQ*64*4;          // 9.4 MB
  int*   cells      = (int*)(ws + off);            off += (size_t)NAg*8*4;
  float* xc         = (float*)(ws + off);          off += (size_t)NAg*112*4;
  unsigned short* W1r = (unsigned short*)(ws + off); off += (size_t)9*64*ESTR*2;
  uint2* WhhP       = (uint2*)(ws + off);          off += (size_t)12288*8;
  unsigned short* Wpk = (unsigned short*)(ws + off); off += (size_t)48*512*2;

  k_decode_masks<<<16, 256, 0, stream>>>(masks, cells);
  k_prep<<<144, 256, 0, stream>>>(socW, W1r, dWhh, WhhP, eWih, eWhh, Wpk);
  k_embed_x<<<16384, 256, 0, stream>>>(x, dynW, dynb, E);
  k_embed_agg<<<4096, 256, 0, stream>>>(ngbrs, graphs, dynW, dynb, sW, sb, E);
  k_gru_enc_mfma<<<576, 256, 0, stream>>>((const unsigned short*)E, Wpk, ebih, ebhh, h_all);
  k_xs<<<512, 256, 0, stream>>>(h_all, hidW, hidb, xc);
  k_soc<<<1024, 256, 0, stream>>>(h_all, cells, W1r, socb, c31W, c31b, xc);
  k_dec<<<256, 256, 0, stream>>>(xc, WhhP, dWih, dbih, dbhh, outW, outb, out);
}

// Round 4
// 629.799 us; speedup vs baseline: 2.1698x; 1.3349x over previous
//
#include <hip/hip_runtime.h>
#include <hip/hip_bf16.h>

#define T_OBS 16
#define NAg   4096
#define Vn    8
#define NV    32768           // NAg*Vn
#define SEQ   36864           // NAg + NV
#define PRED  25
#define ESTR  68              // padded LDS stride for 64-wide seq tiles
#define XSTR  116             // padded LDS stride for 112-wide xc tile

typedef __bf16 bf16x8 __attribute__((ext_vector_type(8)));
typedef float  f32x4  __attribute__((ext_vector_type(4)));

__device__ __forceinline__ float leakyf(float v){ return v >= 0.f ? v : 0.1f*v; }
__device__ __forceinline__ float sigf(float x){ return 1.f/(1.f+__expf(-x)); }
__device__ __forceinline__ float tanhf_(float x){
  x = fminf(fmaxf(x, -10.f), 10.f);
  float e = __expf(2.f*x);
  return (e-1.f)/(e+1.f);
}
__device__ __forceinline__ float bf2f(unsigned short u){
  union{unsigned int i; float f;} v; v.i = ((unsigned int)u)<<16; return v.f;
}
__device__ __forceinline__ unsigned short f2bf(float f){
  __hip_bfloat16 b = __float2bfloat16(f);
  return *reinterpret_cast<unsigned short*>(&b);
}
__device__ __forceinline__ float dot4f(float4 a, float4 b, float acc){
  return fmaf(a.x,b.x, fmaf(a.y,b.y, fmaf(a.z,b.z, fmaf(a.w,b.w, acc))));
}
__device__ __forceinline__ bf16x8 as_bf16x8(uint4 u){
  union { uint4 a; bf16x8 b; } v; v.a = u; return v.b;
}

// ---------------------------------------------------------------------------
// Decode bool masks -> per-agent 8 selected cell indices.
// ---------------------------------------------------------------------------
__global__ void k_decode_masks(const void* __restrict__ masks, int* __restrict__ cells){
  int n = blockIdx.x*blockDim.x + threadIdx.x;
  if (n >= NAg) return;
  const unsigned char* m8  = (const unsigned char*)masks;
  const int*           m32 = (const int*)masks;
  int tmp[8]; for (int v=0; v<8; ++v) tmp[v] = 0;
  int cnt = 0;
  for (int cc=0; cc<39; ++cc){                 // u8 interpretation (bool bytes)
    size_t base = ((size_t)n*39 + cc)*64;
    if (m8[base] && m8[base+1] && m8[base+33]){ if (cnt<8) tmp[cnt]=cc; cnt++; }
  }
  if (cnt != 8){                               // fallback: 4-byte elements
    cnt = 0;
    for (int cc=0; cc<39; ++cc){
      size_t base = ((size_t)n*39 + cc)*64;
      if (m32[base] != 0){ if (cnt<8) tmp[cnt]=cc; cnt++; }
    }
  }
  for (int v=0; v<8; ++v) cells[n*8+v] = tmp[v];
}

// ---------------------------------------------------------------------------
// One-shot weight re-layouts:
//  W1r  : soc_W f32 -> bf16 [kk][o][c pad 68]
//  Wpk  : encoder Wih/Whh -> MFMA B-fragments (see R2 comment)
//  WdecF: dec_Whh -> MFMA B-fragments, 8 waves x 3 N-tiles x 4 K-steps
//  WoutF: out_W (5x128, zero-padded to 16 cols) -> 4 K-step B-fragments
// ---------------------------------------------------------------------------
__global__ void k_prep(const float* __restrict__ socW, unsigned short* __restrict__ W1r,
                       const float* __restrict__ eWih, const float* __restrict__ eWhh,
                       unsigned short* __restrict__ Wpk,
                       const float* __restrict__ dWhh, unsigned short* __restrict__ WdecF,
                       const float* __restrict__ outW, unsigned short* __restrict__ WoutF){
  int idx = blockIdx.x*blockDim.x + threadIdx.x;   // 49152 threads
  if (idx < 36864){
    int c  = idx & 63;
    int o  = (idx>>6) & 63;
    int kk = idx >> 12;                            // ky*3+kx, 0..8
    int ky = kk/3, kx = kk%3;
    W1r[(kk*64 + o)*ESTR + c] = f2bf(socW[(o*64 + c)*9 + ky*3 + kx]);
  }
  if (idx < 24576){                                // encoder: 48 frags * 512
    int f   = idx >> 9;
    int rem = idx & 511;
    int l   = rem >> 3, j = rem & 7;
    int lr  = l & 15, lg = l >> 4;
    float val;
    if (f < 32){
      int nt = f >> 2, kk = f & 3;
      int n  = nt*16 + lr;                         // rows 0..127 = r,z gates
      int k  = kk*32 + lg*8 + j;
      val = (k < 64) ? eWih[(size_t)n*64 + k] : eWhh[(size_t)n*64 + (k-64)];
    } else if (f < 40){
      int q = f - 32;
      int n = (8 + (q>>1))*16 + lr;                // rows 128..191 = n gate
      int k = (q&1)*32 + lg*8 + j;
      val = eWih[(size_t)n*64 + k];
    } else {
      int q = f - 40;
      int n = (8 + (q>>1))*16 + lr;
      int k = (q&1)*32 + lg*8 + j;
      val = eWhh[(size_t)n*64 + k];
    }
    Wpk[f*512 + l*8 + j] = f2bf(val);
  }
  if (idx < 49152){                                // decoder: 96 frags * 512
    int f   = idx >> 9;                            // g*12 + nt*4 + kk
    int rem = idx & 511;
    int l   = rem >> 3, j = rem & 7;
    int lr  = l & 15, lg = l >> 4;
    int g = f/12, loc = f%12, nt = loc>>2, kk = loc&3;
    int n = g*48 + nt*16 + lr;
    int k = kk*32 + lg*8 + j;
    WdecF[idx] = f2bf(dWhh[(size_t)n*128 + k]);
  }
  if (idx < 2048){                                 // out head: 4 frags * 512
    int kk  = idx >> 9;
    int rem = idx & 511;
    int l   = rem >> 3, j = rem & 7;
    int lr  = l & 15, lg = l >> 4;
    int k = kk*32 + lg*8 + j;
    float v = (lr < 5) ? outW[(size_t)lr*128 + k] : 0.f;
    WoutF[idx] = f2bf(v);
  }
}

// ---------------------------------------------------------------------------
// x_e = leaky(x @ dyn_W.T + dyn_b) -> E[t][0..4095][c] (bf16)
// ---------------------------------------------------------------------------
__global__ void k_embed_x(const float* __restrict__ x, const float* __restrict__ dynW,
                          const float* __restrict__ dynb, __hip_bfloat16* __restrict__ E){
  int idx = blockIdx.x*blockDim.x + threadIdx.x;   // 16*4096*64 exactly
  int c = idx & 63;
  int s = (idx >> 6) & 4095;
  int t = idx >> 18;
  float x0 = x[((size_t)t*NAg + s)*2 + 0];
  float x1 = x[((size_t)t*NAg + s)*2 + 1];
  float v = leakyf(fmaf(x0, dynW[c*2+0], fmaf(x1, dynW[c*2+1], dynb[c])));
  E[((size_t)t*SEQ + s)*64 + c] = __float2bfloat16(v);
}

// ---------------------------------------------------------------------------
// Per agent n: ng_e = leaky(dyn(ngbrs)), h = ng_e@sW.T+sb,
// agg[t,w,c] -> E[t][4096+n*8+w][c]
// ---------------------------------------------------------------------------
__global__ __launch_bounds__(256,1) void k_embed_agg(
    const float* __restrict__ ngbrs, const float* __restrict__ graphs,
    const float* __restrict__ dynW, const float* __restrict__ dynb,
    const float* __restrict__ sW, const float* __restrict__ sb,
    __hip_bfloat16* __restrict__ E)
{
  __shared__ float4 SW4[16*128];      // [c4][j]
  __shared__ float  nge[16*8*64];     // [t][v][c]
  __shared__ float  hm [16*8*128];    // [t][v][j]
  __shared__ float  gL[128];
  __shared__ float  sbL[128], dwL[128], dbL[64];
  const int tid = threadIdx.x;
  const int n = blockIdx.x;

  for (int idx=tid; idx<2048; idx+=256){
    int j = idx & 127, c4 = idx >> 7;
    SW4[c4*128 + j] = *(const float4*)(sW + (size_t)j*64 + c4*4);
  }
  if (tid < 128) gL[tid]  = graphs[(size_t)n*128 + tid];
  if (tid < 128) sbL[tid] = sb[tid];
  if (tid < 128) dwL[tid] = dynW[tid];
  if (tid < 64)  dbL[tid] = dynb[tid];
  __syncthreads();

  for (int idx=tid; idx<8192; idx+=256){       // nge
    int c = idx & 63, v = (idx>>6)&7, t = idx>>9;
    const float* p = ngbrs + ((size_t)t*NV + (size_t)n*8 + v)*2;
    nge[idx] = leakyf(fmaf(p[0], dwL[c*2], fmaf(p[1], dwL[c*2+1], dbL[c])));
  }
  __syncthreads();

  #pragma unroll
  for (int p2=0; p2<2; ++p2){                  // hm: 512 tasks (t, jb)
    int task = tid + 256*p2;
    int t = task >> 5, jb = task & 31;
    float acc[8][4];
    #pragma unroll
    for (int jj=0; jj<4; ++jj){ float b = sbL[jb + jj*32];
      #pragma unroll
      for (int v=0; v<8; ++v) acc[v][jj] = b; }
    for (int c4=0; c4<16; ++c4){
      float4 wv[4];
      #pragma unroll
      for (int jj=0; jj<4; ++jj) wv[jj] = SW4[c4*128 + jj*32 + jb];
      #pragma unroll
      for (int v=0; v<8; ++v){
        float4 xv = *(const float4*)(nge + (t*8+v)*64 + c4*4);
        #pragma unroll
        for (int jj=0; jj<4; ++jj) acc[v][jj] = dot4f(wv[jj], xv, acc[v][jj]);
      }
    }
    #pragma unroll
    for (int v=0; v<8; ++v)
      #pragma unroll
      for (int jj=0; jj<4; ++jj)
        hm[(t*8+v)*128 + jj*32 + jb] = acc[v][jj];
  }
  __syncthreads();

  #pragma unroll
  for (int p2=0; p2<8; ++p2){                  // agg + store
    int task = tid + 256*p2;
    int c4 = task & 15, w = (task>>4)&7, t = task>>7;
    float4 acc = make_float4(0.f,0.f,0.f,0.f);
    #pragma unroll
    for (int k=0; k<2; ++k)
      #pragma unroll
      for (int v=0; v<8; ++v){
        float g = gL[(k*8+v)*8 + w];
        float4 h4 = *(const float4*)(hm + (t*8+v)*128 + k*64 + c4*4);
        acc.x = fmaf(g,h4.x,acc.x); acc.y = fmaf(g,h4.y,acc.y);
        acc.z = fmaf(g,h4.z,acc.z); acc.w = fmaf(g,h4.w,acc.w);
      }
    __hip_bfloat16* dst = E + ((size_t)t*SEQ + NAg + (size_t)n*8 + w)*64 + c4*4;
    ushort4 uo;
    uo.x = f2bf(acc.x); uo.y = f2bf(acc.y); uo.z = f2bf(acc.z); uo.w = f2bf(acc.w);
    *reinterpret_cast<ushort4*>(dst) = uo;
  }
}

// ---------------------------------------------------------------------------
// Encoder GRU via MFMA (validated R2). 1 wave = 16 seqs, no barriers.
// ---------------------------------------------------------------------------
__global__ __launch_bounds__(256,1) void k_gru_enc_mfma(
    const unsigned short* __restrict__ E,
    const unsigned short* __restrict__ Wpk,
    const float* __restrict__ bih, const float* __restrict__ bhh,
    float* __restrict__ h_all)
{
  __shared__ __align__(16) unsigned char hbuf[4*2048];
  const int tid = threadIdx.x;
  const int w  = tid >> 6;
  const int l  = tid & 63;
  const int lr = l & 15;           // A row / D col
  const int lg = l >> 4;           // k-group
  const size_t s0 = (size_t)blockIdx.x*64 + (size_t)w*16;

  uint4 bf[48];
  #pragma unroll
  for (int f=0; f<48; ++f)
    bf[f] = *(const uint4*)(Wpk + f*512 + l*8);

  float brz_r[4], brz_z[4], bni[4], bnh[4];
  #pragma unroll
  for (int nt=0; nt<4; ++nt){
    int i = nt*16 + lr;
    brz_r[nt] = bih[i]      + bhh[i];
    brz_z[nt] = bih[64+i]   + bhh[64+i];
    bni[nt]   = bih[128+i];
    bnh[nt]   = bhh[128+i];
  }

  unsigned char* hb = hbuf + w*2048;
  {
    uint4 z4 = make_uint4(0,0,0,0);
    *(uint4*)(hb + l*32)      = z4;
    *(uint4*)(hb + l*32 + 16) = z4;
  }

  float hreg[4][4];
  #pragma unroll
  for (int nt=0; nt<4; ++nt)
    #pragma unroll
    for (int j=0; j<4; ++j) hreg[nt][j] = 0.f;

  uint4 ax0, ax1;
  {
    const unsigned short* p = E + (s0 + lr)*64 + lg*8;
    ax0 = *(const uint4*)(p);
    ax1 = *(const uint4*)(p + 32);
  }

  const int swz = (lr & 7) << 4;

  #pragma unroll 1
  for (int t=0; t<T_OBS; ++t){
    int tn = (t < 15) ? t+1 : 15;
    const unsigned short* pn = E + ((size_t)tn*SEQ + s0 + lr)*64 + lg*8;
    uint4 nx0 = *(const uint4*)(pn);
    uint4 nx1 = *(const uint4*)(pn + 32);

    int hbase = lr*128 + lg*16;
    uint4 ah0 = *(const uint4*)(hb + ((hbase     ) ^ swz));
    uint4 ah1 = *(const uint4*)(hb + ((hbase + 64) ^ swz));

    bf16x8 Ax0 = as_bf16x8(ax0), Ax1 = as_bf16x8(ax1);
    bf16x8 Ah0 = as_bf16x8(ah0), Ah1 = as_bf16x8(ah1);

    f32x4 accRZ[8], accNI[4], accNH[4];
    #pragma unroll
    for (int q=0; q<8; ++q) accRZ[q] = (f32x4){0.f,0.f,0.f,0.f};
    #pragma unroll
    for (int q=0; q<4; ++q){ accNI[q] = (f32x4){0.f,0.f,0.f,0.f}; accNH[q] = (f32x4){0.f,0.f,0.f,0.f}; }

    #pragma unroll
    for (int nt=0; nt<8; ++nt){
      accRZ[nt] = __builtin_amdgcn_mfma_f32_16x16x32_bf16(Ax0, as_bf16x8(bf[nt*4+0]), accRZ[nt], 0,0,0);
      accRZ[nt] = __builtin_amdgcn_mfma_f32_16x16x32_bf16(Ax1, as_bf16x8(bf[nt*4+1]), accRZ[nt], 0,0,0);
      accRZ[nt] = __builtin_amdgcn_mfma_f32_16x16x32_bf16(Ah0, as_bf16x8(bf[nt*4+2]), accRZ[nt], 0,0,0);
      accRZ[nt] = __builtin_amdgcn_mfma_f32_16x16x32_bf16(Ah1, as_bf16x8(bf[nt*4+3]), accRZ[nt], 0,0,0);
    }
    #pragma unroll
    for (int nt=0; nt<4; ++nt){
      accNI[nt] = __builtin_amdgcn_mfma_f32_16x16x32_bf16(Ax0, as_bf16x8(bf[32+nt*2+0]), accNI[nt], 0,0,0);
      accNI[nt] = __builtin_amdgcn_mfma_f32_16x16x32_bf16(Ax1, as_bf16x8(bf[32+nt*2+1]), accNI[nt], 0,0,0);
      accNH[nt] = __builtin_amdgcn_mfma_f32_16x16x32_bf16(Ah0, as_bf16x8(bf[40+nt*2+0]), accNH[nt], 0,0,0);
      accNH[nt] = __builtin_amdgcn_mfma_f32_16x16x32_bf16(Ah1, as_bf16x8(bf[40+nt*2+1]), accNH[nt], 0,0,0);
    }

    #pragma unroll
    for (int nt=0; nt<4; ++nt){
      #pragma unroll
      for (int j=0; j<4; ++j){
        float r = sigf(accRZ[nt][j]   + brz_r[nt]);
        float z = sigf(accRZ[4+nt][j] + brz_z[nt]);
        float n = tanhf_(fmaf(r, accNH[nt][j] + bnh[nt], accNI[nt][j] + bni[nt]));
        float h = fmaf(z, hreg[nt][j] - n, n);
        hreg[nt][j] = h;
        int row = lg*4 + j;
        int boff = (row*128 + (nt*16 + lr)*2) ^ ((row & 7) << 4);
        *(unsigned short*)(hb + boff) = f2bf(h);
      }
    }
    ax0 = nx0; ax1 = nx1;
  }

  #pragma unroll
  for (int nt=0; nt<4; ++nt)
    #pragma unroll
    for (int j=0; j<4; ++j)
      h_all[(s0 + lg*4 + j)*64 + nt*16 + lr] = hreg[nt][j];
}

// ---------------------------------------------------------------------------
// x_s = leaky(h_x @ hid_W.T + hid_b) -> xc[:, 0:32]
// ---------------------------------------------------------------------------
__global__ void k_xs(const float* __restrict__ h_all, const float* __restrict__ hidW,
                     const float* __restrict__ hidb, float* __restrict__ xc){
  int idx = blockIdx.x*blockDim.x + threadIdx.x;   // 4096*32
  int j = idx & 31, n = idx >> 5;
  const float* h = h_all + (size_t)n*64;
  const float* w = hidW + (size_t)j*64;
  float acc = hidb[j];
  for (int k4=0; k4<16; ++k4)
    acc = dot4f(*(const float4*)(h + k4*4), *(const float4*)(w + k4*4), acc);
  xc[(size_t)n*112 + j] = leakyf(acc);
}

// ---------------------------------------------------------------------------
// Social branch: sparse scatter + conv(3x3) + conv(3x1) + maxpool -> xc[:,32:112]
// ---------------------------------------------------------------------------
__global__ __launch_bounds__(256,1) void k_soc(
    const float* __restrict__ h_all, const int* __restrict__ cells,
    const unsigned short* __restrict__ W1r, const float* __restrict__ socb,
    const float* __restrict__ c31W, const float* __restrict__ c31b,
    float* __restrict__ xc)
{
  __shared__ unsigned short W1L[9*64*ESTR];   // [kk][o][c pad68] bf16
  __shared__ float W2L[64*48];                // [o][ky][p]
  __shared__ float hv[4][8][64];
  __shared__ float out1[4][64][12];
  __shared__ float out2[4][16][9];
  __shared__ int   cellsL[4][8];
  __shared__ float b2L[16];
  const int tid = threadIdx.x;
  const int n0 = blockIdx.x * 4;

  {
    const uint4* src = reinterpret_cast<const uint4*>(W1r);
    uint4* dst = reinterpret_cast<uint4*>(W1L);
    for (int idx=tid; idx<(9*64*ESTR)/8; idx+=256) dst[idx] = src[idx];
  }
  {
    const float* hsrc = h_all + ((size_t)NAg + (size_t)n0*8)*64;
    float* hdst = &hv[0][0][0];
    for (int idx=tid; idx<2048; idx+=256) hdst[idx] = hsrc[idx];
  }
  for (int idx=tid; idx<3072; idx+=256){
    int p = idx/192, rem = idx%192, o = rem/3, ky = rem%3;
    W2L[(o*3+ky)*16 + p] = c31W[idx];
  }
  if (tid < 16) b2L[tid] = c31b[tid];
  if (tid < 32){ int ag = tid>>3, v = tid&7; cellsL[ag][v] = cells[(n0+ag)*8 + v]; }
  for (int idx=tid; idx<2816; idx+=256){
    int y = idx%11, o = (idx/11)&63, ag = idx/704;
    out1[ag][o][y] = socb[o];
  }
  __syncthreads();

  const int ag = tid >> 6;      // wave id = agent
  const int o  = tid & 63;
  for (int v=0; v<8; ++v){
    int cc = cellsL[ag][v];
    int gw = cc/13, gh = cc%13;
    const float* hvv = hv[ag][v];
    #pragma unroll
    for (int ky=0; ky<3; ++ky){
      int y = gh - ky;
      if (0 <= y && y < 11){
        const unsigned short* wp = W1L + ((ky*3+gw)*64 + o)*ESTR;
        float acc = 0.f;
        #pragma unroll
        for (int c4=0; c4<16; ++c4){
          ushort4 wv = *(const ushort4*)(wp + c4*4);
          float4  h4 = *(const float4*)(hvv + c4*4);
          acc = fmaf(h4.x, bf2f(wv.x), fmaf(h4.y, bf2f(wv.y),
                fmaf(h4.z, bf2f(wv.z), fmaf(h4.w, bf2f(wv.w), acc))));
        }
        out1[ag][o][y] += acc;
      }
    }
  }
  __syncthreads();
  for (int idx=tid; idx<2816; idx+=256){
    int y = idx%11, oo = (idx/11)&63, a2 = idx/704;
    out1[a2][oo][y] = leakyf(out1[a2][oo][y]);
  }
  __syncthreads();

  #pragma unroll
  for (int pass=0; pass<3; ++pass){              // conv2 (3x1) + leaky
    int lcl = tid & 63;
    int p = lcl & 15, y2 = (lcl >> 4) + pass*4;
    if (y2 < 9){
      float acc = b2L[p];
      for (int oo=0; oo<64; ++oo){
        const float* o1 = &out1[ag][oo][y2];
        const float* w2 = &W2L[oo*48 + p];
        acc = fmaf(o1[0], w2[0], fmaf(o1[1], w2[16], fmaf(o1[2], w2[32], acc)));
      }
      out2[ag][p][y2] = leakyf(acc);
    }
  }
  __syncthreads();

  for (int idx=tid; idx<320; idx+=256){          // maxpool
    int e = idx % 80, a2 = idx / 80;
    int p = e/5, w2 = e%5;
    float val = (w2==0) ? out2[a2][p][0]
                        : fmaxf(out2[a2][p][2*w2-1], out2[a2][p][2*w2]);
    xc[(size_t)(n0+a2)*112 + 32 + e] = val;
  }
}

// ---------------------------------------------------------------------------
// Decoder GRU via MFMA + fused output head.
// Block = 16 seqs, 8 waves (512 thr). Wave g owns gate outputs [g*48,g*48+48)
// for the GEMM and h-columns [g*16,g*16+16) for the elementwise update.
// gi (input gates) constant over 25 steps -> registers. h: f32 in registers
// + bf16 XOR-swizzled LDS A-tile. Out head = 1 extra MFMA N-tile on wave 0.
// ---------------------------------------------------------------------------
__global__ __launch_bounds__(512,1) void k_dec_mfma(
    const float* __restrict__ xc, const unsigned short* __restrict__ WdecF,
    const unsigned short* __restrict__ WoutF,
    const float* __restrict__ dWih, const float* __restrict__ dbih,
    const float* __restrict__ dbhh, const float* __restrict__ outb,
    float* __restrict__ out)
{
  __shared__ float Gm[384*16];                       // [n][s] f32
  __shared__ __align__(16) unsigned char Hb[16*256]; // h bf16, A-layout, swizzled
  __shared__ float xct[16*XSTR];
  const int tid = threadIdx.x;
  const int g   = tid >> 6;        // wave 0..7
  const int l   = tid & 63;
  const int lr  = l & 15, lg = l >> 4;
  const int n0  = blockIdx.x * 16;
  const int i   = g*16 + lr;       // owned h column (0..127)

  // stage xc tile; zero h buffer
  for (int idx=tid; idx<16*112; idx+=512){
    int s = idx/112, k = idx%112;
    xct[s*XSTR + k] = xc[(size_t)(n0+s)*112 + k];
  }
  *(uint2*)(Hb + tid*8) = make_uint2(0,0);
  __syncthreads();

  // gi = xc @ dWih.T + dbih  (once) -> Gm[j][s]
  {
    int s = tid & 15, jq = tid >> 4;                 // jq 0..31
    const float* xr = xct + s*XSTR;
    for (int jj=0; jj<12; ++jj){
      int j = jq*12 + jj;
      float acc = dbih[j];
      const float* wp = dWih + (size_t)j*112;
      for (int k4=0; k4<28; ++k4)
        acc = dot4f(*(const float4*)(wp + k4*4), *(const float4*)(xr + k4*4), acc);
      Gm[j*16 + s] = acc;
    }
  }
  __syncthreads();

  // per-lane constants: gi for owned (column i, seqs lg*4..+3), biases
  float gi_r[4], gi_z[4], gi_n[4];
  #pragma unroll
  for (int u=0; u<4; ++u){
    int s = lg*4 + u;
    gi_r[u] = Gm[(      i)*16 + s];
    gi_z[u] = Gm[(128 + i)*16 + s];
    gi_n[u] = Gm[(256 + i)*16 + s];
  }
  const float bh_r = dbhh[i], bh_z = dbhh[128+i], bh_n = dbhh[256+i];
  const float obv  = (lr < 5) ? outb[lr] : 0.f;
  __syncthreads();                                   // Gm reused below

  // B-fragments
  uint4 bgf[12];
  #pragma unroll
  for (int f=0; f<12; ++f)
    bgf[f] = *(const uint4*)(WdecF + (size_t)(g*12 + f)*512 + l*8);
  uint4 bof[4];
  #pragma unroll
  for (int kk=0; kk<4; ++kk)
    bof[kk] = *(const uint4*)(WoutF + (size_t)kk*512 + l*8);

  float hreg[4] = {0.f, 0.f, 0.f, 0.f};
  const int swz = (lr & 7) << 4;

  #pragma unroll 1
  for (int t=0; t<PRED; ++t){
    // A-frags = h_t from swizzled LDS
    uint4 ah[4];
    #pragma unroll
    for (int kk=0; kk<4; ++kk)
      ah[kk] = *(const uint4*)(Hb + ((lr*256 + kk*64 + lg*16) ^ swz));

    // fused out head for h_t (t>=1 -> out step t-1), wave 0 only
    if (g == 0 && t > 0){
      f32x4 accO = (f32x4){0.f,0.f,0.f,0.f};
      #pragma unroll
      for (int kk=0; kk<4; ++kk)
        accO = __builtin_amdgcn_mfma_f32_16x16x32_bf16(as_bf16x8(ah[kk]), as_bf16x8(bof[kk]), accO, 0,0,0);
      if (lr < 5){
        #pragma unroll
        for (int u=0; u<4; ++u){
          float a = accO[u] + obv;
          float val = (lr < 2) ? a : (lr == 4 ? tanhf_(a) : __expf(a));
          out[((size_t)(t-1)*NAg + n0 + lg*4 + u)*5 + lr] = val;
        }
      }
    }

    // gate GEMM: 3 N-tiles x 4 K-steps
    f32x4 acc[3];
    #pragma unroll
    for (int nt=0; nt<3; ++nt) acc[nt] = (f32x4){0.f,0.f,0.f,0.f};
    #pragma unroll
    for (int nt=0; nt<3; ++nt)
      #pragma unroll
      for (int kk=0; kk<4; ++kk)
        acc[nt] = __builtin_amdgcn_mfma_f32_16x16x32_bf16(as_bf16x8(ah[kk]), as_bf16x8(bgf[nt*4+kk]), acc[nt], 0,0,0);

    #pragma unroll
    for (int nt=0; nt<3; ++nt)
      *(f32x4*)(Gm + (g*48 + nt*16 + lr)*16 + lg*4) = acc[nt];
    __syncthreads();

    // elementwise GRU update for owned column
    float4 rp = *(const float4*)(Gm + (      i)*16 + lg*4);
    float4 zp = *(const float4*)(Gm + (128 + i)*16 + lg*4);
    float4 hp = *(const float4*)(Gm + (256 + i)*16 + lg*4);
    const float* rpa = &rp.x; const float* zpa = &zp.x; const float* hpa = &hp.x;
    #pragma unroll
    for (int u=0; u<4; ++u){
      float r  = sigf(gi_r[u] + rpa[u] + bh_r);
      float z  = sigf(gi_z[u] + zpa[u] + bh_z);
      float nn = tanhf_(fmaf(r, hpa[u] + bh_n, gi_n[u]));
      float h  = fmaf(z, hreg[u] - nn, nn);
      hreg[u] = h;
      int s = lg*4 + u;
      *(unsigned short*)(Hb + ((s*256 + i*2) ^ ((s & 7) << 4))) = f2bf(h);
    }
    __syncthreads();
  }

  // tail: out head for h_PRED (step PRED-1)
  if (g == 0){
    uint4 ah[4];
    #pragma unroll
    for (int kk=0; kk<4; ++kk)
      ah[kk] = *(const uint4*)(Hb + ((lr*256 + kk*64 + lg*16) ^ swz));
    f32x4 accO = (f32x4){0.f,0.f,0.f,0.f};
    #pragma unroll
    for (int kk=0; kk<4; ++kk)
      accO = __builtin_amdgcn_mfma_f32_16x16x32_bf16(as_bf16x8(ah[kk]), as_bf16x8(bof[kk]), accO, 0,0,0);
    if (lr < 5){
      #pragma unroll
      for (int u=0; u<4; ++u){
        float a = accO[u] + obv;
        float val = (lr < 2) ? a : (lr == 4 ? tanhf_(a) : __expf(a));
        out[((size_t)(PRED-1)*NAg + n0 + lg*4 + u)*5 + lr] = val;
      }
    }
  }
}

// ---------------------------------------------------------------------------
extern "C" void kernel_launch(void* const* d_in, const int* in_sizes, int n_in,
                              void* d_out, int out_size, void* d_ws, size_t ws_size,
                              hipStream_t stream)
{
  const float* x      = (const float*)d_in[0];
  const float* ngbrs  = (const float*)d_in[1];
  const float* graphs = (const float*)d_in[2];
  const void*  masks  = d_in[3];
  // d_in[4] = ngbrs_idx (unused by the reference computation)
  const float* dynW   = (const float*)d_in[5];
  const float* dynb   = (const float*)d_in[6];
  const float* eWih   = (const float*)d_in[7];
  const float* eWhh   = (const float*)d_in[8];
  const float* ebih   = (const float*)d_in[9];
  const float* ebhh   = (const float*)d_in[10];
  const float* sW     = (const float*)d_in[11];
  const float* sb     = (const float*)d_in[12];
  const float* hidW   = (const float*)d_in[13];
  const float* hidb   = (const float*)d_in[14];
  const float* socW   = (const float*)d_in[15];
  const float* socb   = (const float*)d_in[16];
  const float* c31W   = (const float*)d_in[17];
  const float* c31b   = (const float*)d_in[18];
  const float* dWih   = (const float*)d_in[19];
  const float* dWhh   = (const float*)d_in[20];
  const float* dbih   = (const float*)d_in[21];
  const float* dbhh   = (const float*)d_in[22];
  const float* outW   = (const float*)d_in[23];
  const float* outb   = (const float*)d_in[24];
  float* out = (float*)d_out;

  char* ws = (char*)d_ws;
  size_t off = 0;
  __hip_bfloat16* E = (__hip_bfloat16*)(ws + off); off += (size_t)T_OBS*SEQ*64*2;   // 75.5 MB
  float* h_all      = (float*)(ws + off);          off += (size_t)SEQ*64*4;          // 9.4 MB
  int*   cells      = (int*)(ws + off);            off += (size_t)NAg*8*4;
  float* xc         = (float*)(ws + off);          off += (size_t)NAg*112*4;
  unsigned short* W1r = (unsigned short*)(ws + off); off += (size_t)9*64*ESTR*2;
  unsigned short* Wpk = (unsigned short*)(ws + off); off += (size_t)48*512*2;
  unsigned short* WdecF = (unsigned short*)(ws + off); off += (size_t)96*512*2;
  unsigned short* WoutF = (unsigned short*)(ws + off); off += (size_t)4*512*2;

  k_decode_masks<<<16, 256, 0, stream>>>(masks, cells);
  k_prep<<<192, 256, 0, stream>>>(socW, W1r, eWih, eWhh, Wpk, dWhh, WdecF, outW, WoutF);
  k_embed_x<<<16384, 256, 0, stream>>>(x, dynW, dynb, E);
  k_embed_agg<<<4096, 256, 0, stream>>>(ngbrs, graphs, dynW, dynb, sW, sb, E);
  k_gru_enc_mfma<<<576, 256, 0, stream>>>((const unsigned short*)E, Wpk, ebih, ebhh, h_all);
  k_xs<<<512, 256, 0, stream>>>(h_all, hidW, hidb, xc);
  k_soc<<<1024, 256, 0, stream>>>(h_all, cells, W1r, socb, c31W, c31b, xc);
  k_dec_mfma<<<256, 512, 0, stream>>>(xc, WdecF, WoutF, dWih, dbih, dbhh, outb, out);
}

// Round 5
// 427.087 us; speedup vs baseline: 3.1997x; 1.4746x over previous
//
#include <hip/hip_runtime.h>
#include <hip/hip_bf16.h>

#define T_OBS 16
#define NAg   4096
#define Vn    8
#define NV    32768           // NAg*Vn
#define SEQ   36864           // NAg + NV
#define PRED  25
#define ESTR  68              // padded LDS stride for 64-wide seq tiles
#define XSTR  116             // padded LDS stride for 112-wide xc tile

typedef __bf16 bf16x8 __attribute__((ext_vector_type(8)));
typedef float  f32x4  __attribute__((ext_vector_type(4)));

__device__ __forceinline__ float leakyf(float v){ return v >= 0.f ? v : 0.1f*v; }
__device__ __forceinline__ float sigf(float x){ return 1.f/(1.f+__expf(-x)); }
__device__ __forceinline__ float tanhf_(float x){
  x = fminf(fmaxf(x, -10.f), 10.f);
  float e = __expf(2.f*x);
  return (e-1.f)/(e+1.f);
}
__device__ __forceinline__ float bf2f(unsigned short u){
  union{unsigned int i; float f;} v; v.i = ((unsigned int)u)<<16; return v.f;
}
__device__ __forceinline__ unsigned short f2bf(float f){
  __hip_bfloat16 b = __float2bfloat16(f);
  return *reinterpret_cast<unsigned short*>(&b);
}
__device__ __forceinline__ float dot4f(float4 a, float4 b, float acc){
  return fmaf(a.x,b.x, fmaf(a.y,b.y, fmaf(a.z,b.z, fmaf(a.w,b.w, acc))));
}
__device__ __forceinline__ bf16x8 as_bf16x8(uint4 u){
  union { uint4 a; bf16x8 b; } v; v.a = u; return v.b;
}

// ---------------------------------------------------------------------------
// Decode bool masks -> per-agent 8 selected cell indices.
// ---------------------------------------------------------------------------
__global__ void k_decode_masks(const void* __restrict__ masks, int* __restrict__ cells){
  int n = blockIdx.x*blockDim.x + threadIdx.x;
  if (n >= NAg) return;
  const unsigned char* m8  = (const unsigned char*)masks;
  const int*           m32 = (const int*)masks;
  int tmp[8]; for (int v=0; v<8; ++v) tmp[v] = 0;
  int cnt = 0;
  for (int cc=0; cc<39; ++cc){                 // u8 interpretation (bool bytes)
    size_t base = ((size_t)n*39 + cc)*64;
    if (m8[base] && m8[base+1] && m8[base+33]){ if (cnt<8) tmp[cnt]=cc; cnt++; }
  }
  if (cnt != 8){                               // fallback: 4-byte elements
    cnt = 0;
    for (int cc=0; cc<39; ++cc){
      size_t base = ((size_t)n*39 + cc)*64;
      if (m32[base] != 0){ if (cnt<8) tmp[cnt]=cc; cnt++; }
    }
  }
  for (int v=0; v<8; ++v) cells[n*8+v] = tmp[v];
}

// ---------------------------------------------------------------------------
// One-shot weight re-layouts:
//  W1r  : soc_W f32 -> bf16 [kk][o][c pad 68]
//  Wpk  : encoder Wih/Whh -> MFMA B-fragments
//  WdecF: dec_Whh -> MFMA B-fragments, 8 waves x 3 N-tiles x 4 K-steps
//  WoutF: out_W (5x128, zero-padded to 16 cols) -> 4 K-step B-fragments
//  SWF  : s_W (128,64) -> 16 MFMA B-fragments (8 N-tiles x 2 K-steps)
// ---------------------------------------------------------------------------
__global__ void k_prep(const float* __restrict__ socW, unsigned short* __restrict__ W1r,
                       const float* __restrict__ eWih, const float* __restrict__ eWhh,
                       unsigned short* __restrict__ Wpk,
                       const float* __restrict__ dWhh, unsigned short* __restrict__ WdecF,
                       const float* __restrict__ outW, unsigned short* __restrict__ WoutF,
                       const float* __restrict__ sW, unsigned short* __restrict__ SWF){
  int idx = blockIdx.x*blockDim.x + threadIdx.x;   // 49152 threads
  if (idx < 36864){
    int c  = idx & 63;
    int o  = (idx>>6) & 63;
    int kk = idx >> 12;                            // ky*3+kx, 0..8
    int ky = kk/3, kx = kk%3;
    W1r[(kk*64 + o)*ESTR + c] = f2bf(socW[(o*64 + c)*9 + ky*3 + kx]);
  }
  if (idx < 24576){                                // encoder: 48 frags * 512
    int f   = idx >> 9;
    int rem = idx & 511;
    int l   = rem >> 3, j = rem & 7;
    int lr  = l & 15, lg = l >> 4;
    float val;
    if (f < 32){
      int nt = f >> 2, kk = f & 3;
      int n  = nt*16 + lr;                         // rows 0..127 = r,z gates
      int k  = kk*32 + lg*8 + j;
      val = (k < 64) ? eWih[(size_t)n*64 + k] : eWhh[(size_t)n*64 + (k-64)];
    } else if (f < 40){
      int q = f - 32;
      int n = (8 + (q>>1))*16 + lr;                // rows 128..191 = n gate
      int k = (q&1)*32 + lg*8 + j;
      val = eWih[(size_t)n*64 + k];
    } else {
      int q = f - 40;
      int n = (8 + (q>>1))*16 + lr;
      int k = (q&1)*32 + lg*8 + j;
      val = eWhh[(size_t)n*64 + k];
    }
    Wpk[f*512 + l*8 + j] = f2bf(val);
  }
  if (idx < 49152){                                // decoder: 96 frags * 512
    int f   = idx >> 9;                            // g*12 + nt*4 + kk
    int rem = idx & 511;
    int l   = rem >> 3, j = rem & 7;
    int lr  = l & 15, lg = l >> 4;
    int g = f/12, loc = f%12, nt = loc>>2, kk = loc&3;
    int n = g*48 + nt*16 + lr;
    int k = kk*32 + lg*8 + j;
    WdecF[idx] = f2bf(dWhh[(size_t)n*128 + k]);
  }
  if (idx < 2048){                                 // out head: 4 frags * 512
    int kk  = idx >> 9;
    int rem = idx & 511;
    int l   = rem >> 3, j = rem & 7;
    int lr  = l & 15, lg = l >> 4;
    int k = kk*32 + lg*8 + j;
    float v = (lr < 5) ? outW[(size_t)lr*128 + k] : 0.f;
    WoutF[idx] = f2bf(v);
  }
  if (idx < 8192){                                 // s_W: 16 frags * 512
    int f   = idx >> 9;                            // nt*2 + kk
    int rem = idx & 511;
    int l   = rem >> 3, j = rem & 7;
    int lr  = l & 15, lg = l >> 4;
    int nt = f >> 1, kk = f & 1;
    int nn = nt*16 + lr;
    int k  = kk*32 + lg*8 + j;
    SWF[idx] = f2bf(sW[(size_t)nn*64 + k]);
  }
}

// ---------------------------------------------------------------------------
// x_e = leaky(x @ dyn_W.T + dyn_b) -> E[t][0..4095][c] (bf16)
// ---------------------------------------------------------------------------
__global__ void k_embed_x(const float* __restrict__ x, const float* __restrict__ dynW,
                          const float* __restrict__ dynb, __hip_bfloat16* __restrict__ E){
  int idx = blockIdx.x*blockDim.x + threadIdx.x;   // 16*4096*64 exactly
  int c = idx & 63;
  int s = (idx >> 6) & 4095;
  int t = idx >> 18;
  float x0 = x[((size_t)t*NAg + s)*2 + 0];
  float x1 = x[((size_t)t*NAg + s)*2 + 1];
  float v = leakyf(fmaf(x0, dynW[c*2+0], fmaf(x1, dynW[c*2+1], dynb[c])));
  E[((size_t)t*SEQ + s)*64 + c] = __float2bfloat16(v);
}

// ---------------------------------------------------------------------------
// Per agent n (fused, MFMA): ng_e (bf16, swizzled LDS) -> H = ng_e@sW.T+sb via
// MFMA (bf16 hm) -> graph einsum (VALU f32) -> E[t][4096+n*8+w][c].
// 4 waves; wave w owns M-tiles {2w, 2w+1} of the 128x128x64 GEMM.
// ---------------------------------------------------------------------------
__global__ __launch_bounds__(256,2) void k_embed_agg_mfma(
    const float* __restrict__ ngbrs, const float* __restrict__ graphs,
    const float* __restrict__ dynW, const float* __restrict__ dynb,
    const unsigned short* __restrict__ SWF, const float* __restrict__ sb,
    __hip_bfloat16* __restrict__ E)
{
  __shared__ __align__(16) unsigned char ngeb[128*128];   // bf16 [row][64] swizzled
  __shared__ __align__(16) unsigned short hm[128*136];    // bf16 [tv][128 pad 136]
  __shared__ float2 pL[128];
  __shared__ float  gL[128];
  __shared__ float2 dwL[64];
  __shared__ float  dbL[64];
  const int tid = threadIdx.x;
  const int n = blockIdx.x;

  if (tid < 128) gL[tid] = graphs[(size_t)n*128 + tid];
  if (tid < 64)  dwL[tid] = *(const float2*)(dynW + tid*2);
  if (tid < 64)  dbL[tid] = dynb[tid];
  if (tid < 128){
    int t = tid >> 3, v = tid & 7;
    pL[tid] = *(const float2*)(ngbrs + ((size_t)t*NV + (size_t)n*8 + v)*2);
  }
  __syncthreads();

  // nge = leaky(dyn(ngbrs)) -> bf16 swizzled LDS rows tv=0..127
  #pragma unroll
  for (int p=0; p<4; ++p){
    int chunk = tid + p*256;          // 1024: row*8 + c8
    int row = chunk >> 3, c8 = chunk & 7;
    float2 xy = pL[row];
    union { unsigned short s[8]; uint4 u; } ou;
    #pragma unroll
    for (int jj=0; jj<8; ++jj){
      int c = c8*8 + jj;
      ou.s[jj] = f2bf(leakyf(fmaf(xy.x, dwL[c].x, fmaf(xy.y, dwL[c].y, dbL[c]))));
    }
    *(uint4*)(ngeb + ((row*128 + c8*16) ^ ((row&7)<<4))) = ou.u;
  }
  __syncthreads();

  // H = nge @ sW.T + sb  (MFMA), store bf16 to hm
  const int w4 = tid >> 6, l = tid & 63, lr = l & 15, lg = l >> 4;
  {
    uint4 bsw[16];
    #pragma unroll
    for (int f=0; f<16; ++f) bsw[f] = *(const uint4*)(SWF + f*512 + l*8);
    float sbv[8];
    #pragma unroll
    for (int nt=0; nt<8; ++nt) sbv[nt] = sb[nt*16 + lr];

    f32x4 acc[2][8];
    #pragma unroll
    for (int m=0; m<2; ++m)
      #pragma unroll
      for (int nt=0; nt<8; ++nt)
        acc[m][nt] = (f32x4){sbv[nt], sbv[nt], sbv[nt], sbv[nt]};

    #pragma unroll
    for (int m=0; m<2; ++m){
      int row = (w4*2+m)*16 + lr;
      int rb = row*128, sz = (row&7)<<4;
      uint4 a0 = *(const uint4*)(ngeb + ((rb      + lg*16) ^ sz));
      uint4 a1 = *(const uint4*)(ngeb + ((rb + 64 + lg*16) ^ sz));
      bf16x8 A0 = as_bf16x8(a0), A1 = as_bf16x8(a1);
      #pragma unroll
      for (int nt=0; nt<8; ++nt){
        acc[m][nt] = __builtin_amdgcn_mfma_f32_16x16x32_bf16(A0, as_bf16x8(bsw[nt*2+0]), acc[m][nt], 0,0,0);
        acc[m][nt] = __builtin_amdgcn_mfma_f32_16x16x32_bf16(A1, as_bf16x8(bsw[nt*2+1]), acc[m][nt], 0,0,0);
      }
    }
    #pragma unroll
    for (int m=0; m<2; ++m)
      #pragma unroll
      for (int nt=0; nt<8; ++nt)
        #pragma unroll
        for (int jj=0; jj<4; ++jj)
          hm[((w4*2+m)*16 + lg*4 + jj)*136 + nt*16 + lr] = f2bf(acc[m][nt][jj]);
  }
  __syncthreads();

  // agg: E[t][n*8+w][c] = sum_{k,v} H[t*8+v][k*64+c] * g[k][v][w]
  #pragma unroll
  for (int p=0; p<4; ++p){
    int task = tid + p*256;           // 1024: t*64 + wv*8 + c8
    int c8 = task & 7, wv = (task>>3)&7, t = task >> 6;
    float a8[8];
    #pragma unroll
    for (int jj=0; jj<8; ++jj) a8[jj] = 0.f;
    #pragma unroll
    for (int k=0; k<2; ++k){
      #pragma unroll
      for (int v=0; v<8; ++v){
        float g = gL[k*64 + v*8 + wv];
        uint4 hv4 = *(const uint4*)(hm + (t*8+v)*136 + k*64 + c8*8);
        const unsigned short* hh = (const unsigned short*)&hv4;
        #pragma unroll
        for (int jj=0; jj<8; ++jj) a8[jj] = fmaf(g, bf2f(hh[jj]), a8[jj]);
      }
    }
    union { unsigned short s[8]; uint4 u; } ou;
    #pragma unroll
    for (int jj=0; jj<8; ++jj) ou.s[jj] = f2bf(a8[jj]);
    *(uint4*)((unsigned short*)E + ((size_t)t*SEQ + NAg + (size_t)n*8 + wv)*64 + c8*8) = ou.u;
  }
}

// ---------------------------------------------------------------------------
// Encoder GRU via MFMA (validated R2). 1 wave = 16 seqs, no barriers.
// ---------------------------------------------------------------------------
__global__ __launch_bounds__(256,1) void k_gru_enc_mfma(
    const unsigned short* __restrict__ E,
    const unsigned short* __restrict__ Wpk,
    const float* __restrict__ bih, const float* __restrict__ bhh,
    float* __restrict__ h_all)
{
  __shared__ __align__(16) unsigned char hbuf[4*2048];
  const int tid = threadIdx.x;
  const int w  = tid >> 6;
  const int l  = tid & 63;
  const int lr = l & 15;           // A row / D col
  const int lg = l >> 4;           // k-group
  const size_t s0 = (size_t)blockIdx.x*64 + (size_t)w*16;

  uint4 bf[48];
  #pragma unroll
  for (int f=0; f<48; ++f)
    bf[f] = *(const uint4*)(Wpk + f*512 + l*8);

  float brz_r[4], brz_z[4], bni[4], bnh[4];
  #pragma unroll
  for (int nt=0; nt<4; ++nt){
    int i = nt*16 + lr;
    brz_r[nt] = bih[i]      + bhh[i];
    brz_z[nt] = bih[64+i]   + bhh[64+i];
    bni[nt]   = bih[128+i];
    bnh[nt]   = bhh[128+i];
  }

  unsigned char* hb = hbuf + w*2048;
  {
    uint4 z4 = make_uint4(0,0,0,0);
    *(uint4*)(hb + l*32)      = z4;
    *(uint4*)(hb + l*32 + 16) = z4;
  }

  float hreg[4][4];
  #pragma unroll
  for (int nt=0; nt<4; ++nt)
    #pragma unroll
    for (int j=0; j<4; ++j) hreg[nt][j] = 0.f;

  uint4 ax0, ax1;
  {
    const unsigned short* p = E + (s0 + lr)*64 + lg*8;
    ax0 = *(const uint4*)(p);
    ax1 = *(const uint4*)(p + 32);
  }

  const int swz = (lr & 7) << 4;

  #pragma unroll 1
  for (int t=0; t<T_OBS; ++t){
    int tn = (t < 15) ? t+1 : 15;
    const unsigned short* pn = E + ((size_t)tn*SEQ + s0 + lr)*64 + lg*8;
    uint4 nx0 = *(const uint4*)(pn);
    uint4 nx1 = *(const uint4*)(pn + 32);

    int hbase = lr*128 + lg*16;
    uint4 ah0 = *(const uint4*)(hb + ((hbase     ) ^ swz));
    uint4 ah1 = *(const uint4*)(hb + ((hbase + 64) ^ swz));

    bf16x8 Ax0 = as_bf16x8(ax0), Ax1 = as_bf16x8(ax1);
    bf16x8 Ah0 = as_bf16x8(ah0), Ah1 = as_bf16x8(ah1);

    f32x4 accRZ[8], accNI[4], accNH[4];
    #pragma unroll
    for (int q=0; q<8; ++q) accRZ[q] = (f32x4){0.f,0.f,0.f,0.f};
    #pragma unroll
    for (int q=0; q<4; ++q){ accNI[q] = (f32x4){0.f,0.f,0.f,0.f}; accNH[q] = (f32x4){0.f,0.f,0.f,0.f}; }

    #pragma unroll
    for (int nt=0; nt<8; ++nt){
      accRZ[nt] = __builtin_amdgcn_mfma_f32_16x16x32_bf16(Ax0, as_bf16x8(bf[nt*4+0]), accRZ[nt], 0,0,0);
      accRZ[nt] = __builtin_amdgcn_mfma_f32_16x16x32_bf16(Ax1, as_bf16x8(bf[nt*4+1]), accRZ[nt], 0,0,0);
      accRZ[nt] = __builtin_amdgcn_mfma_f32_16x16x32_bf16(Ah0, as_bf16x8(bf[nt*4+2]), accRZ[nt], 0,0,0);
      accRZ[nt] = __builtin_amdgcn_mfma_f32_16x16x32_bf16(Ah1, as_bf16x8(bf[nt*4+3]), accRZ[nt], 0,0,0);
    }
    #pragma unroll
    for (int nt=0; nt<4; ++nt){
      accNI[nt] = __builtin_amdgcn_mfma_f32_16x16x32_bf16(Ax0, as_bf16x8(bf[32+nt*2+0]), accNI[nt], 0,0,0);
      accNI[nt] = __builtin_amdgcn_mfma_f32_16x16x32_bf16(Ax1, as_bf16x8(bf[32+nt*2+1]), accNI[nt], 0,0,0);
      accNH[nt] = __builtin_amdgcn_mfma_f32_16x16x32_bf16(Ah0, as_bf16x8(bf[40+nt*2+0]), accNH[nt], 0,0,0);
      accNH[nt] = __builtin_amdgcn_mfma_f32_16x16x32_bf16(Ah1, as_bf16x8(bf[40+nt*2+1]), accNH[nt], 0,0,0);
    }

    #pragma unroll
    for (int nt=0; nt<4; ++nt){
      #pragma unroll
      for (int j=0; j<4; ++j){
        float r = sigf(accRZ[nt][j]   + brz_r[nt]);
        float z = sigf(accRZ[4+nt][j] + brz_z[nt]);
        float n = tanhf_(fmaf(r, accNH[nt][j] + bnh[nt], accNI[nt][j] + bni[nt]));
        float h = fmaf(z, hreg[nt][j] - n, n);
        hreg[nt][j] = h;
        int row = lg*4 + j;
        int boff = (row*128 + (nt*16 + lr)*2) ^ ((row & 7) << 4);
        *(unsigned short*)(hb + boff) = f2bf(h);
      }
    }
    ax0 = nx0; ax1 = nx1;
  }

  #pragma unroll
  for (int nt=0; nt<4; ++nt)
    #pragma unroll
    for (int j=0; j<4; ++j)
      h_all[(s0 + lg*4 + j)*64 + nt*16 + lr] = hreg[nt][j];
}

// ---------------------------------------------------------------------------
// x_s = leaky(h_x @ hid_W.T + hid_b) -> xc[:, 0:32]
// ---------------------------------------------------------------------------
__global__ void k_xs(const float* __restrict__ h_all, const float* __restrict__ hidW,
                     const float* __restrict__ hidb, float* __restrict__ xc){
  int idx = blockIdx.x*blockDim.x + threadIdx.x;   // 4096*32
  int j = idx & 31, n = idx >> 5;
  const float* h = h_all + (size_t)n*64;
  const float* w = hidW + (size_t)j*64;
  float acc = hidb[j];
  for (int k4=0; k4<16; ++k4)
    acc = dot4f(*(const float4*)(h + k4*4), *(const float4*)(w + k4*4), acc);
  xc[(size_t)n*112 + j] = leakyf(acc);
}

// ---------------------------------------------------------------------------
// Social branch: sparse scatter + conv(3x3) + conv(3x1) + maxpool -> xc[:,32:112]
// ---------------------------------------------------------------------------
__global__ __launch_bounds__(256,1) void k_soc(
    const float* __restrict__ h_all, const int* __restrict__ cells,
    const unsigned short* __restrict__ W1r, const float* __restrict__ socb,
    const float* __restrict__ c31W, const float* __restrict__ c31b,
    float* __restrict__ xc)
{
  __shared__ unsigned short W1L[9*64*ESTR];   // [kk][o][c pad68] bf16
  __shared__ float W2L[64*48];                // [o][ky][p]
  __shared__ float hv[4][8][64];
  __shared__ float out1[4][64][12];
  __shared__ float out2[4][16][9];
  __shared__ int   cellsL[4][8];
  __shared__ float b2L[16];
  const int tid = threadIdx.x;
  const int n0 = blockIdx.x * 4;

  {
    const uint4* src = reinterpret_cast<const uint4*>(W1r);
    uint4* dst = reinterpret_cast<uint4*>(W1L);
    for (int idx=tid; idx<(9*64*ESTR)/8; idx+=256) dst[idx] = src[idx];
  }
  {
    const float* hsrc = h_all + ((size_t)NAg + (size_t)n0*8)*64;
    float* hdst = &hv[0][0][0];
    for (int idx=tid; idx<2048; idx+=256) hdst[idx] = hsrc[idx];
  }
  for (int idx=tid; idx<3072; idx+=256){
    int p = idx/192, rem = idx%192, o = rem/3, ky = rem%3;
    W2L[(o*3+ky)*16 + p] = c31W[idx];
  }
  if (tid < 16) b2L[tid] = c31b[tid];
  if (tid < 32){ int ag = tid>>3, v = tid&7; cellsL[ag][v] = cells[(n0+ag)*8 + v]; }
  for (int idx=tid; idx<2816; idx+=256){
    int y = idx%11, o = (idx/11)&63, ag = idx/704;
    out1[ag][o][y] = socb[o];
  }
  __syncthreads();

  const int ag = tid >> 6;      // wave id = agent
  const int o  = tid & 63;
  for (int v=0; v<8; ++v){
    int cc = cellsL[ag][v];
    int gw = cc/13, gh = cc%13;
    const float* hvv = hv[ag][v];
    #pragma unroll
    for (int ky=0; ky<3; ++ky){
      int y = gh - ky;
      if (0 <= y && y < 11){
        const unsigned short* wp = W1L + ((ky*3+gw)*64 + o)*ESTR;
        float acc = 0.f;
        #pragma unroll
        for (int c4=0; c4<16; ++c4){
          ushort4 wv = *(const ushort4*)(wp + c4*4);
          float4  h4 = *(const float4*)(hvv + c4*4);
          acc = fmaf(h4.x, bf2f(wv.x), fmaf(h4.y, bf2f(wv.y),
                fmaf(h4.z, bf2f(wv.z), fmaf(h4.w, bf2f(wv.w), acc))));
        }
        out1[ag][o][y] += acc;
      }
    }
  }
  __syncthreads();
  for (int idx=tid; idx<2816; idx+=256){
    int y = idx%11, oo = (idx/11)&63, a2 = idx/704;
    out1[a2][oo][y] = leakyf(out1[a2][oo][y]);
  }
  __syncthreads();

  #pragma unroll
  for (int pass=0; pass<3; ++pass){              // conv2 (3x1) + leaky
    int lcl = tid & 63;
    int p = lcl & 15, y2 = (lcl >> 4) + pass*4;
    if (y2 < 9){
      float acc = b2L[p];
      for (int oo=0; oo<64; ++oo){
        const float* o1 = &out1[ag][oo][y2];
        const float* w2 = &W2L[oo*48 + p];
        acc = fmaf(o1[0], w2[0], fmaf(o1[1], w2[16], fmaf(o1[2], w2[32], acc)));
      }
      out2[ag][p][y2] = leakyf(acc);
    }
  }
  __syncthreads();

  for (int idx=tid; idx<320; idx+=256){          // maxpool
    int e = idx % 80, a2 = idx / 80;
    int p = e/5, w2 = e%5;
    float val = (w2==0) ? out2[a2][p][0]
                        : fmaxf(out2[a2][p][2*w2-1], out2[a2][p][2*w2]);
    xc[(size_t)(n0+a2)*112 + 32 + e] = val;
  }
}

// ---------------------------------------------------------------------------
// Decoder GRU via MFMA + fused output head (validated R3).
// ---------------------------------------------------------------------------
__global__ __launch_bounds__(512,1) void k_dec_mfma(
    const float* __restrict__ xc, const unsigned short* __restrict__ WdecF,
    const unsigned short* __restrict__ WoutF,
    const float* __restrict__ dWih, const float* __restrict__ dbih,
    const float* __restrict__ dbhh, const float* __restrict__ outb,
    float* __restrict__ out)
{
  __shared__ float Gm[384*16];                       // [n][s] f32
  __shared__ __align__(16) unsigned char Hb[16*256]; // h bf16, A-layout, swizzled
  __shared__ float xct[16*XSTR];
  const int tid = threadIdx.x;
  const int g   = tid >> 6;        // wave 0..7
  const int l   = tid & 63;
  const int lr  = l & 15, lg = l >> 4;
  const int n0  = blockIdx.x * 16;
  const int i   = g*16 + lr;       // owned h column (0..127)

  for (int idx=tid; idx<16*112; idx+=512){
    int s = idx/112, k = idx%112;
    xct[s*XSTR + k] = xc[(size_t)(n0+s)*112 + k];
  }
  *(uint2*)(Hb + tid*8) = make_uint2(0,0);
  __syncthreads();

  {
    int s = tid & 15, jq = tid >> 4;                 // jq 0..31
    const float* xr = xct + s*XSTR;
    for (int jj=0; jj<12; ++jj){
      int j = jq*12 + jj;
      float acc = dbih[j];
      const float* wp = dWih + (size_t)j*112;
      for (int k4=0; k4<28; ++k4)
        acc = dot4f(*(const float4*)(wp + k4*4), *(const float4*)(xr + k4*4), acc);
      Gm[j*16 + s] = acc;
    }
  }
  __syncthreads();

  float gi_r[4], gi_z[4], gi_n[4];
  #pragma unroll
  for (int u=0; u<4; ++u){
    int s = lg*4 + u;
    gi_r[u] = Gm[(      i)*16 + s];
    gi_z[u] = Gm[(128 + i)*16 + s];
    gi_n[u] = Gm[(256 + i)*16 + s];
  }
  const float bh_r = dbhh[i], bh_z = dbhh[128+i], bh_n = dbhh[256+i];
  const float obv  = (lr < 5) ? outb[lr] : 0.f;
  __syncthreads();                                   // Gm reused below

  uint4 bgf[12];
  #pragma unroll
  for (int f=0; f<12; ++f)
    bgf[f] = *(const uint4*)(WdecF + (size_t)(g*12 + f)*512 + l*8);
  uint4 bof[4];
  #pragma unroll
  for (int kk=0; kk<4; ++kk)
    bof[kk] = *(const uint4*)(WoutF + (size_t)kk*512 + l*8);

  float hreg[4] = {0.f, 0.f, 0.f, 0.f};
  const int swz = (lr & 7) << 4;

  #pragma unroll 1
  for (int t=0; t<PRED; ++t){
    uint4 ah[4];
    #pragma unroll
    for (int kk=0; kk<4; ++kk)
      ah[kk] = *(const uint4*)(Hb + ((lr*256 + kk*64 + lg*16) ^ swz));

    if (g == 0 && t > 0){
      f32x4 accO = (f32x4){0.f,0.f,0.f,0.f};
      #pragma unroll
      for (int kk=0; kk<4; ++kk)
        accO = __builtin_amdgcn_mfma_f32_16x16x32_bf16(as_bf16x8(ah[kk]), as_bf16x8(bof[kk]), accO, 0,0,0);
      if (lr < 5){
        #pragma unroll
        for (int u=0; u<4; ++u){
          float a = accO[u] + obv;
          float val = (lr < 2) ? a : (lr == 4 ? tanhf_(a) : __expf(a));
          out[((size_t)(t-1)*NAg + n0 + lg*4 + u)*5 + lr] = val;
        }
      }
    }

    f32x4 acc[3];
    #pragma unroll
    for (int nt=0; nt<3; ++nt) acc[nt] = (f32x4){0.f,0.f,0.f,0.f};
    #pragma unroll
    for (int nt=0; nt<3; ++nt)
      #pragma unroll
      for (int kk=0; kk<4; ++kk)
        acc[nt] = __builtin_amdgcn_mfma_f32_16x16x32_bf16(as_bf16x8(ah[kk]), as_bf16x8(bgf[nt*4+kk]), acc[nt], 0,0,0);

    #pragma unroll
    for (int nt=0; nt<3; ++nt)
      *(f32x4*)(Gm + (g*48 + nt*16 + lr)*16 + lg*4) = acc[nt];
    __syncthreads();

    float4 rp = *(const float4*)(Gm + (      i)*16 + lg*4);
    float4 zp = *(const float4*)(Gm + (128 + i)*16 + lg*4);
    float4 hp = *(const float4*)(Gm + (256 + i)*16 + lg*4);
    const float* rpa = &rp.x; const float* zpa = &zp.x; const float* hpa = &hp.x;
    #pragma unroll
    for (int u=0; u<4; ++u){
      float r  = sigf(gi_r[u] + rpa[u] + bh_r);
      float z  = sigf(gi_z[u] + zpa[u] + bh_z);
      float nn = tanhf_(fmaf(r, hpa[u] + bh_n, gi_n[u]));
      float h  = fmaf(z, hreg[u] - nn, nn);
      hreg[u] = h;
      int s = lg*4 + u;
      *(unsigned short*)(Hb + ((s*256 + i*2) ^ ((s & 7) << 4))) = f2bf(h);
    }
    __syncthreads();
  }

  if (g == 0){
    uint4 ah[4];
    #pragma unroll
    for (int kk=0; kk<4; ++kk)
      ah[kk] = *(const uint4*)(Hb + ((lr*256 + kk*64 + lg*16) ^ swz));
    f32x4 accO = (f32x4){0.f,0.f,0.f,0.f};
    #pragma unroll
    for (int kk=0; kk<4; ++kk)
      accO = __builtin_amdgcn_mfma_f32_16x16x32_bf16(as_bf16x8(ah[kk]), as_bf16x8(bof[kk]), accO, 0,0,0);
    if (lr < 5){
      #pragma unroll
      for (int u=0; u<4; ++u){
        float a = accO[u] + obv;
        float val = (lr < 2) ? a : (lr == 4 ? tanhf_(a) : __expf(a));
        out[((size_t)(PRED-1)*NAg + n0 + lg*4 + u)*5 + lr] = val;
      }
    }
  }
}

// ---------------------------------------------------------------------------
extern "C" void kernel_launch(void* const* d_in, const int* in_sizes, int n_in,
                              void* d_out, int out_size, void* d_ws, size_t ws_size,
                              hipStream_t stream)
{
  const float* x      = (const float*)d_in[0];
  const float* ngbrs  = (const float*)d_in[1];
  const float* graphs = (const float*)d_in[2];
  const void*  masks  = d_in[3];
  // d_in[4] = ngbrs_idx (unused by the reference computation)
  const float* dynW   = (const float*)d_in[5];
  const float* dynb   = (const float*)d_in[6];
  const float* eWih   = (const float*)d_in[7];
  const float* eWhh   = (const float*)d_in[8];
  const float* ebih   = (const float*)d_in[9];
  const float* ebhh   = (const float*)d_in[10];
  const float* sW     = (const float*)d_in[11];
  const float* sb     = (const float*)d_in[12];
  const float* hidW   = (const float*)d_in[13];
  const float* hidb   = (const float*)d_in[14];
  const float* socW   = (const float*)d_in[15];
  const float* socb   = (const float*)d_in[16];
  const float* c31W   = (const float*)d_in[17];
  const float* c31b   = (const float*)d_in[18];
  const float* dWih   = (const float*)d_in[19];
  const float* dWhh   = (const float*)d_in[20];
  const float* dbih   = (const float*)d_in[21];
  const float* dbhh   = (const float*)d_in[22];
  const float* outW   = (const float*)d_in[23];
  const float* outb   = (const float*)d_in[24];
  float* out = (float*)d_out;

  char* ws = (char*)d_ws;
  size_t off = 0;
  __hip_bfloat16* E = (__hip_bfloat16*)(ws + off); off += (size_t)T_OBS*SEQ*64*2;   // 75.5 MB
  float* h_all      = (float*)(ws + off);          off += (size_t)SEQ*64*4;          // 9.4 MB
  int*   cells      = (int*)(ws + off);            off += (size_t)NAg*8*4;
  float* xc         = (float*)(ws + off);          off += (size_t)NAg*112*4;
  unsigned short* W1r = (unsigned short*)(ws + off); off += (size_t)9*64*ESTR*2;
  unsigned short* Wpk = (unsigned short*)(ws + off); off += (size_t)48*512*2;
  unsigned short* WdecF = (unsigned short*)(ws + off); off += (size_t)96*512*2;
  unsigned short* WoutF = (unsigned short*)(ws + off); off += (size_t)4*512*2;
  unsigned short* SWF = (unsigned short*)(ws + off); off += (size_t)16*512*2;

  k_decode_masks<<<16, 256, 0, stream>>>(masks, cells);
  k_prep<<<192, 256, 0, stream>>>(socW, W1r, eWih, eWhh, Wpk, dWhh, WdecF, outW, WoutF, sW, SWF);
  k_embed_x<<<16384, 256, 0, stream>>>(x, dynW, dynb, E);
  k_embed_agg_mfma<<<4096, 256, 0, stream>>>(ngbrs, graphs, dynW, dynb, SWF, sb, E);
  k_gru_enc_mfma<<<576, 256, 0, stream>>>((const unsigned short*)E, Wpk, ebih, ebhh, h_all);
  k_xs<<<512, 256, 0, stream>>>(h_all, hidW, hidb, xc);
  k_soc<<<1024, 256, 0, stream>>>(h_all, cells, W1r, socb, c31W, c31b, xc);
  k_dec_mfma<<<256, 512, 0, stream>>>(xc, WdecF, WoutF, dWih, dbih, dbhh, outb, out);
}

// Round 6
// 347.832 us; speedup vs baseline: 3.9288x; 1.2279x over previous
//
#include <hip/hip_runtime.h>
#include <hip/hip_bf16.h>

#define T_OBS 16
#define NAg   4096
#define Vn    8
#define NV    32768           // NAg*Vn
#define SEQ   36864           // NAg + NV
#define PRED  25
#define XSTR  116             // padded LDS stride for 112-wide xc tile

typedef __bf16 bf16x8 __attribute__((ext_vector_type(8)));
typedef float  f32x4  __attribute__((ext_vector_type(4)));

__device__ __forceinline__ float leakyf(float v){ return v >= 0.f ? v : 0.1f*v; }
__device__ __forceinline__ float sigf(float x){ return 1.f/(1.f+__expf(-x)); }
__device__ __forceinline__ float tanhf_(float x){
  x = fminf(fmaxf(x, -10.f), 10.f);
  float e = __expf(2.f*x);
  return (e-1.f)/(e+1.f);
}
__device__ __forceinline__ float bf2f(unsigned short u){
  union{unsigned int i; float f;} v; v.i = ((unsigned int)u)<<16; return v.f;
}
__device__ __forceinline__ unsigned short f2bf(float f){
  __hip_bfloat16 b = __float2bfloat16(f);
  return *reinterpret_cast<unsigned short*>(&b);
}
__device__ __forceinline__ float dot4f(float4 a, float4 b, float acc){
  return fmaf(a.x,b.x, fmaf(a.y,b.y, fmaf(a.z,b.z, fmaf(a.w,b.w, acc))));
}
__device__ __forceinline__ bf16x8 as_bf16x8(uint4 u){
  union { uint4 a; bf16x8 b; } v; v.a = u; return v.b;
}
__device__ __forceinline__ uint4 pack8bf(float4 a, float4 b){
  union{ unsigned short s[8]; uint4 u; } o;
  o.s[0]=f2bf(a.x); o.s[1]=f2bf(a.y); o.s[2]=f2bf(a.z); o.s[3]=f2bf(a.w);
  o.s[4]=f2bf(b.x); o.s[5]=f2bf(b.y); o.s[6]=f2bf(b.z); o.s[7]=f2bf(b.w);
  return o.u;
}

// ---------------------------------------------------------------------------
// Decode bool masks -> per-agent 8 selected cell indices.
// ---------------------------------------------------------------------------
__global__ void k_decode_masks(const void* __restrict__ masks, int* __restrict__ cells){
  int n = blockIdx.x*blockDim.x + threadIdx.x;
  if (n >= NAg) return;
  const unsigned char* m8  = (const unsigned char*)masks;
  const int*           m32 = (const int*)masks;
  int tmp[8]; for (int v=0; v<8; ++v) tmp[v] = 0;
  int cnt = 0;
  for (int cc=0; cc<39; ++cc){                 // u8 interpretation (bool bytes)
    size_t base = ((size_t)n*39 + cc)*64;
    if (m8[base] && m8[base+1] && m8[base+33]){ if (cnt<8) tmp[cnt]=cc; cnt++; }
  }
  if (cnt != 8){                               // fallback: 4-byte elements
    cnt = 0;
    for (int cc=0; cc<39; ++cc){
      size_t base = ((size_t)n*39 + cc)*64;
      if (m32[base] != 0){ if (cnt<8) tmp[cnt]=cc; cnt++; }
    }
  }
  for (int v=0; v<8; ++v) cells[n*8+v] = tmp[v];
}

// ---------------------------------------------------------------------------
// One-shot weight re-layouts:
//  Wpk  : encoder Wih/Whh -> MFMA B-fragments
//  WdecF: dec_Whh -> MFMA B-fragments, 8 waves x 3 N-tiles x 4 K-steps
//  WoutF: out_W (5x128, zero-padded to 16 cols) -> 4 K-step B-fragments
//  SWF  : s_W (128,64) -> 16 MFMA B-fragments (8 N-tiles x 2 K-steps)
//  WsocF: soc_W -> 72 MFMA B-fragments (4 waves x 9 kk x 2 K-steps)
// ---------------------------------------------------------------------------
__global__ void k_prep(const float* __restrict__ eWih, const float* __restrict__ eWhh,
                       unsigned short* __restrict__ Wpk,
                       const float* __restrict__ dWhh, unsigned short* __restrict__ WdecF,
                       const float* __restrict__ outW, unsigned short* __restrict__ WoutF,
                       const float* __restrict__ sW, unsigned short* __restrict__ SWF,
                       const float* __restrict__ socW, unsigned short* __restrict__ WsocF){
  int idx = blockIdx.x*blockDim.x + threadIdx.x;   // 49152 threads
  if (idx < 24576){                                // encoder: 48 frags * 512
    int f   = idx >> 9;
    int rem = idx & 511;
    int l   = rem >> 3, j = rem & 7;
    int lr  = l & 15, lg = l >> 4;
    float val;
    if (f < 32){
      int nt = f >> 2, kk = f & 3;
      int n  = nt*16 + lr;                         // rows 0..127 = r,z gates
      int k  = kk*32 + lg*8 + j;
      val = (k < 64) ? eWih[(size_t)n*64 + k] : eWhh[(size_t)n*64 + (k-64)];
    } else if (f < 40){
      int q = f - 32;
      int n = (8 + (q>>1))*16 + lr;                // rows 128..191 = n gate
      int k = (q&1)*32 + lg*8 + j;
      val = eWih[(size_t)n*64 + k];
    } else {
      int q = f - 40;
      int n = (8 + (q>>1))*16 + lr;
      int k = (q&1)*32 + lg*8 + j;
      val = eWhh[(size_t)n*64 + k];
    }
    Wpk[f*512 + l*8 + j] = f2bf(val);
  }
  if (idx < 49152){                                // decoder: 96 frags * 512
    int f   = idx >> 9;                            // g*12 + nt*4 + kk
    int rem = idx & 511;
    int l   = rem >> 3, j = rem & 7;
    int lr  = l & 15, lg = l >> 4;
    int g = f/12, loc = f%12, nt = loc>>2, kk = loc&3;
    int n = g*48 + nt*16 + lr;
    int k = kk*32 + lg*8 + j;
    WdecF[idx] = f2bf(dWhh[(size_t)n*128 + k]);
  }
  if (idx < 2048){                                 // out head: 4 frags * 512
    int kk  = idx >> 9;
    int rem = idx & 511;
    int l   = rem >> 3, j = rem & 7;
    int lr  = l & 15, lg = l >> 4;
    int k = kk*32 + lg*8 + j;
    float v = (lr < 5) ? outW[(size_t)lr*128 + k] : 0.f;
    WoutF[idx] = f2bf(v);
  }
  if (idx < 8192){                                 // s_W: 16 frags * 512
    int f   = idx >> 9;                            // nt*2 + kk
    int rem = idx & 511;
    int l   = rem >> 3, j = rem & 7;
    int lr  = l & 15, lg = l >> 4;
    int nt = f >> 1, kk = f & 1;
    int nn = nt*16 + lr;
    int k  = kk*32 + lg*8 + j;
    SWF[idx] = f2bf(sW[(size_t)nn*64 + k]);
  }
  if (idx < 36864){                                // soc conv1: 72 frags * 512
    int f   = idx >> 9;                            // (w*9+kk)*2+ks
    int rem = idx & 511;
    int l   = rem >> 3, j = rem & 7;
    int lr  = l & 15, lg = l >> 4;
    int w = f/18, loc = f%18, kk = loc>>1, ks = loc&1;
    int o = w*16 + lr;
    int c = ks*32 + lg*8 + j;
    WsocF[idx] = f2bf(socW[(size_t)o*576 + c*9 + kk]);
  }
}

// ---------------------------------------------------------------------------
// x_e = leaky(x @ dyn_W.T + dyn_b) -> E[t][0..4095][c] (bf16)
// ---------------------------------------------------------------------------
__global__ void k_embed_x(const float* __restrict__ x, const float* __restrict__ dynW,
                          const float* __restrict__ dynb, __hip_bfloat16* __restrict__ E){
  int idx = blockIdx.x*blockDim.x + threadIdx.x;   // 16*4096*64 exactly
  int c = idx & 63;
  int s = (idx >> 6) & 4095;
  int t = idx >> 18;
  float x0 = x[((size_t)t*NAg + s)*2 + 0];
  float x1 = x[((size_t)t*NAg + s)*2 + 1];
  float v = leakyf(fmaf(x0, dynW[c*2+0], fmaf(x1, dynW[c*2+1], dynb[c])));
  E[((size_t)t*SEQ + s)*64 + c] = __float2bfloat16(v);
}

// ---------------------------------------------------------------------------
// Per agent n (fused, MFMA): ng_e (bf16, swizzled LDS) -> H = ng_e@sW.T+sb via
// MFMA (bf16 hm) -> graph einsum (VALU f32) -> E[t][4096+n*8+w][c].
// ---------------------------------------------------------------------------
__global__ __launch_bounds__(256,2) void k_embed_agg_mfma(
    const float* __restrict__ ngbrs, const float* __restrict__ graphs,
    const float* __restrict__ dynW, const float* __restrict__ dynb,
    const unsigned short* __restrict__ SWF, const float* __restrict__ sb,
    __hip_bfloat16* __restrict__ E)
{
  __shared__ __align__(16) unsigned char ngeb[128*128];   // bf16 [row][64] swizzled
  __shared__ __align__(16) unsigned short hm[128*136];    // bf16 [tv][128 pad 136]
  __shared__ float2 pL[128];
  __shared__ float  gL[128];
  __shared__ float2 dwL[64];
  __shared__ float  dbL[64];
  const int tid = threadIdx.x;
  const int n = blockIdx.x;

  if (tid < 128) gL[tid] = graphs[(size_t)n*128 + tid];
  if (tid < 64)  dwL[tid] = *(const float2*)(dynW + tid*2);
  if (tid < 64)  dbL[tid] = dynb[tid];
  if (tid < 128){
    int t = tid >> 3, v = tid & 7;
    pL[tid] = *(const float2*)(ngbrs + ((size_t)t*NV + (size_t)n*8 + v)*2);
  }
  __syncthreads();

  #pragma unroll
  for (int p=0; p<4; ++p){
    int chunk = tid + p*256;          // 1024: row*8 + c8
    int row = chunk >> 3, c8 = chunk & 7;
    float2 xy = pL[row];
    union { unsigned short s[8]; uint4 u; } ou;
    #pragma unroll
    for (int jj=0; jj<8; ++jj){
      int c = c8*8 + jj;
      ou.s[jj] = f2bf(leakyf(fmaf(xy.x, dwL[c].x, fmaf(xy.y, dwL[c].y, dbL[c]))));
    }
    *(uint4*)(ngeb + ((row*128 + c8*16) ^ ((row&7)<<4))) = ou.u;
  }
  __syncthreads();

  const int w4 = tid >> 6, l = tid & 63, lr = l & 15, lg = l >> 4;
  {
    uint4 bsw[16];
    #pragma unroll
    for (int f=0; f<16; ++f) bsw[f] = *(const uint4*)(SWF + f*512 + l*8);
    float sbv[8];
    #pragma unroll
    for (int nt=0; nt<8; ++nt) sbv[nt] = sb[nt*16 + lr];

    f32x4 acc[2][8];
    #pragma unroll
    for (int m=0; m<2; ++m)
      #pragma unroll
      for (int nt=0; nt<8; ++nt)
        acc[m][nt] = (f32x4){sbv[nt], sbv[nt], sbv[nt], sbv[nt]};

    #pragma unroll
    for (int m=0; m<2; ++m){
      int row = (w4*2+m)*16 + lr;
      int rb = row*128, sz = (row&7)<<4;
      uint4 a0 = *(const uint4*)(ngeb + ((rb      + lg*16) ^ sz));
      uint4 a1 = *(const uint4*)(ngeb + ((rb + 64 + lg*16) ^ sz));
      bf16x8 A0 = as_bf16x8(a0), A1 = as_bf16x8(a1);
      #pragma unroll
      for (int nt=0; nt<8; ++nt){
        acc[m][nt] = __builtin_amdgcn_mfma_f32_16x16x32_bf16(A0, as_bf16x8(bsw[nt*2+0]), acc[m][nt], 0,0,0);
        acc[m][nt] = __builtin_amdgcn_mfma_f32_16x16x32_bf16(A1, as_bf16x8(bsw[nt*2+1]), acc[m][nt], 0,0,0);
      }
    }
    #pragma unroll
    for (int m=0; m<2; ++m)
      #pragma unroll
      for (int nt=0; nt<8; ++nt)
        #pragma unroll
        for (int jj=0; jj<4; ++jj)
          hm[((w4*2+m)*16 + lg*4 + jj)*136 + nt*16 + lr] = f2bf(acc[m][nt][jj]);
  }
  __syncthreads();

  #pragma unroll
  for (int p=0; p<4; ++p){
    int task = tid + p*256;           // 1024: t*64 + wv*8 + c8
    int c8 = task & 7, wv = (task>>3)&7, t = task >> 6;
    float a8[8];
    #pragma unroll
    for (int jj=0; jj<8; ++jj) a8[jj] = 0.f;
    #pragma unroll
    for (int k=0; k<2; ++k){
      #pragma unroll
      for (int v=0; v<8; ++v){
        float g = gL[k*64 + v*8 + wv];
        uint4 hv4 = *(const uint4*)(hm + (t*8+v)*136 + k*64 + c8*8);
        const unsigned short* hh = (const unsigned short*)&hv4;
        #pragma unroll
        for (int jj=0; jj<8; ++jj) a8[jj] = fmaf(g, bf2f(hh[jj]), a8[jj]);
      }
    }
    union { unsigned short s[8]; uint4 u; } ou;
    #pragma unroll
    for (int jj=0; jj<8; ++jj) ou.s[jj] = f2bf(a8[jj]);
    *(uint4*)((unsigned short*)E + ((size_t)t*SEQ + NAg + (size_t)n*8 + wv)*64 + c8*8) = ou.u;
  }
}

// ---------------------------------------------------------------------------
// Encoder GRU via MFMA (validated R2). 1 wave = 16 seqs, no barriers.
// ---------------------------------------------------------------------------
__global__ __launch_bounds__(256,1) void k_gru_enc_mfma(
    const unsigned short* __restrict__ E,
    const unsigned short* __restrict__ Wpk,
    const float* __restrict__ bih, const float* __restrict__ bhh,
    float* __restrict__ h_all)
{
  __shared__ __align__(16) unsigned char hbuf[4*2048];
  const int tid = threadIdx.x;
  const int w  = tid >> 6;
  const int l  = tid & 63;
  const int lr = l & 15;           // A row / D col
  const int lg = l >> 4;           // k-group
  const size_t s0 = (size_t)blockIdx.x*64 + (size_t)w*16;

  uint4 bf[48];
  #pragma unroll
  for (int f=0; f<48; ++f)
    bf[f] = *(const uint4*)(Wpk + f*512 + l*8);

  float brz_r[4], brz_z[4], bni[4], bnh[4];
  #pragma unroll
  for (int nt=0; nt<4; ++nt){
    int i = nt*16 + lr;
    brz_r[nt] = bih[i]      + bhh[i];
    brz_z[nt] = bih[64+i]   + bhh[64+i];
    bni[nt]   = bih[128+i];
    bnh[nt]   = bhh[128+i];
  }

  unsigned char* hb = hbuf + w*2048;
  {
    uint4 z4 = make_uint4(0,0,0,0);
    *(uint4*)(hb + l*32)      = z4;
    *(uint4*)(hb + l*32 + 16) = z4;
  }

  float hreg[4][4];
  #pragma unroll
  for (int nt=0; nt<4; ++nt)
    #pragma unroll
    for (int j=0; j<4; ++j) hreg[nt][j] = 0.f;

  uint4 ax0, ax1;
  {
    const unsigned short* p = E + (s0 + lr)*64 + lg*8;
    ax0 = *(const uint4*)(p);
    ax1 = *(const uint4*)(p + 32);
  }

  const int swz = (lr & 7) << 4;

  #pragma unroll 1
  for (int t=0; t<T_OBS; ++t){
    int tn = (t < 15) ? t+1 : 15;
    const unsigned short* pn = E + ((size_t)tn*SEQ + s0 + lr)*64 + lg*8;
    uint4 nx0 = *(const uint4*)(pn);
    uint4 nx1 = *(const uint4*)(pn + 32);

    int hbase = lr*128 + lg*16;
    uint4 ah0 = *(const uint4*)(hb + ((hbase     ) ^ swz));
    uint4 ah1 = *(const uint4*)(hb + ((hbase + 64) ^ swz));

    bf16x8 Ax0 = as_bf16x8(ax0), Ax1 = as_bf16x8(ax1);
    bf16x8 Ah0 = as_bf16x8(ah0), Ah1 = as_bf16x8(ah1);

    f32x4 accRZ[8], accNI[4], accNH[4];
    #pragma unroll
    for (int q=0; q<8; ++q) accRZ[q] = (f32x4){0.f,0.f,0.f,0.f};
    #pragma unroll
    for (int q=0; q<4; ++q){ accNI[q] = (f32x4){0.f,0.f,0.f,0.f}; accNH[q] = (f32x4){0.f,0.f,0.f,0.f}; }

    #pragma unroll
    for (int nt=0; nt<8; ++nt){
      accRZ[nt] = __builtin_amdgcn_mfma_f32_16x16x32_bf16(Ax0, as_bf16x8(bf[nt*4+0]), accRZ[nt], 0,0,0);
      accRZ[nt] = __builtin_amdgcn_mfma_f32_16x16x32_bf16(Ax1, as_bf16x8(bf[nt*4+1]), accRZ[nt], 0,0,0);
      accRZ[nt] = __builtin_amdgcn_mfma_f32_16x16x32_bf16(Ah0, as_bf16x8(bf[nt*4+2]), accRZ[nt], 0,0,0);
      accRZ[nt] = __builtin_amdgcn_mfma_f32_16x16x32_bf16(Ah1, as_bf16x8(bf[nt*4+3]), accRZ[nt], 0,0,0);
    }
    #pragma unroll
    for (int nt=0; nt<4; ++nt){
      accNI[nt] = __builtin_amdgcn_mfma_f32_16x16x32_bf16(Ax0, as_bf16x8(bf[32+nt*2+0]), accNI[nt], 0,0,0);
      accNI[nt] = __builtin_amdgcn_mfma_f32_16x16x32_bf16(Ax1, as_bf16x8(bf[32+nt*2+1]), accNI[nt], 0,0,0);
      accNH[nt] = __builtin_amdgcn_mfma_f32_16x16x32_bf16(Ah0, as_bf16x8(bf[40+nt*2+0]), accNH[nt], 0,0,0);
      accNH[nt] = __builtin_amdgcn_mfma_f32_16x16x32_bf16(Ah1, as_bf16x8(bf[40+nt*2+1]), accNH[nt], 0,0,0);
    }

    #pragma unroll
    for (int nt=0; nt<4; ++nt){
      #pragma unroll
      for (int j=0; j<4; ++j){
        float r = sigf(accRZ[nt][j]   + brz_r[nt]);
        float z = sigf(accRZ[4+nt][j] + brz_z[nt]);
        float n = tanhf_(fmaf(r, accNH[nt][j] + bnh[nt], accNI[nt][j] + bni[nt]));
        float h = fmaf(z, hreg[nt][j] - n, n);
        hreg[nt][j] = h;
        int row = lg*4 + j;
        int boff = (row*128 + (nt*16 + lr)*2) ^ ((row & 7) << 4);
        *(unsigned short*)(hb + boff) = f2bf(h);
      }
    }
    ax0 = nx0; ax1 = nx1;
  }

  #pragma unroll
  for (int nt=0; nt<4; ++nt)
    #pragma unroll
    for (int j=0; j<4; ++j)
      h_all[(s0 + lg*4 + j)*64 + nt*16 + lr] = hreg[nt][j];
}

// ---------------------------------------------------------------------------
// x_s = leaky(h_x @ hid_W.T + hid_b) -> xc[:, 0:32]
// ---------------------------------------------------------------------------
__global__ void k_xs(const float* __restrict__ h_all, const float* __restrict__ hidW,
                     const float* __restrict__ hidb, float* __restrict__ xc){
  int idx = blockIdx.x*blockDim.x + threadIdx.x;   // 4096*32
  int j = idx & 31, n = idx >> 5;
  const float* h = h_all + (size_t)n*64;
  const float* w = hidW + (size_t)j*64;
  float acc = hidb[j];
  for (int k4=0; k4<16; ++k4)
    acc = dot4f(*(const float4*)(h + k4*4), *(const float4*)(w + k4*4), acc);
  xc[(size_t)n*112 + j] = leakyf(acc);
}

// ---------------------------------------------------------------------------
// Social branch via MFMA: Q[kk][v][o] = W1[kk] @ hv[v] for all 9 kk (dense
// GEMM, weights in VGPRs), then sparse scatter-add into out1, conv2(3x1),
// maxpool. Block = 8 agents, 4 waves; wave w owns o in [w*16, w*16+16).
// ---------------------------------------------------------------------------
__global__ __launch_bounds__(256,3) void k_soc_mfma(
    const float* __restrict__ h_all, const int* __restrict__ cells,
    const unsigned short* __restrict__ WsocF, const float* __restrict__ socb,
    const float* __restrict__ c31W, const float* __restrict__ c31b,
    float* __restrict__ xc)
{
  __shared__ unsigned short Qb[9*8*64];   // 9 KB  [kk][v][o] bf16
  __shared__ float o1p[4*64*17];          // 17 KB scatter partials (y shifted +2)
  __shared__ float o1[64*12];             // 3 KB  out1 (y 0..10)
  __shared__ float c2p[4*144];            // 2.25 KB conv2 partials
  __shared__ float W2L[64*48];            // 12 KB [o][ky][p]
  __shared__ float socbL[64];
  __shared__ float b2L[16];
  __shared__ int   cellsL[64];            // [a][v]

  const int tid = threadIdx.x;
  const int w  = tid >> 6;
  const int l  = tid & 63;
  const int lr = l & 15, lg = l >> 4;
  const int n0 = blockIdx.x * 8;

  for (int idx=tid; idx<3072; idx+=256){
    int p = idx/192, rem = idx%192, o = rem/3, ky = rem%3;
    W2L[(o*3+ky)*16 + p] = c31W[idx];
  }
  if (tid < 64) socbL[tid] = socb[tid];
  if (tid < 16) b2L[tid]  = c31b[tid];
  if (tid < 64) cellsL[tid] = cells[n0*8 + tid];

  // B fragments: 18 per wave (9 kk x 2 K-steps) = 72 VGPRs
  uint4 bs[18];
  #pragma unroll
  for (int f=0; f<18; ++f)
    bs[f] = *(const uint4*)(WsocF + (size_t)(w*18 + f)*512 + l*8);
  __syncthreads();

  #pragma unroll 1
  for (int a=0; a<8; ++a){
    // A-frags: rows lr<8 = hv[v=lr] (f32 -> bf16), rows 8..15 zero
    uint4 ax0u = make_uint4(0,0,0,0), ax1u = make_uint4(0,0,0,0);
    if (lr < 8){
      const float* hp = h_all + ((size_t)NAg + (size_t)(n0+a)*8 + lr)*64 + lg*8;
      float4 f0 = *(const float4*)(hp);
      float4 f1 = *(const float4*)(hp + 4);
      float4 f2 = *(const float4*)(hp + 32);
      float4 f3 = *(const float4*)(hp + 36);
      ax0u = pack8bf(f0, f1);
      ax1u = pack8bf(f2, f3);
    }
    bf16x8 A0 = as_bf16x8(ax0u), A1 = as_bf16x8(ax1u);

    f32x4 acc[9];
    #pragma unroll
    for (int kk=0; kk<9; ++kk) acc[kk] = (f32x4){0.f,0.f,0.f,0.f};
    #pragma unroll
    for (int kk=0; kk<9; ++kk){
      acc[kk] = __builtin_amdgcn_mfma_f32_16x16x32_bf16(A0, as_bf16x8(bs[kk*2+0]), acc[kk], 0,0,0);
      acc[kk] = __builtin_amdgcn_mfma_f32_16x16x32_bf16(A1, as_bf16x8(bs[kk*2+1]), acc[kk], 0,0,0);
    }

    __syncthreads();               // prev agent's consumers done; Qb/o1p free

    if (lg < 2){                   // write Q rows v = lg*4+j (0..7)
      #pragma unroll
      for (int kk=0; kk<9; ++kk)
        #pragma unroll
        for (int j=0; j<4; ++j)
          Qb[(kk*8 + lg*4 + j)*64 + w*16 + lr] = f2bf(acc[kk][j]);
    }
    for (int idx=tid; idx<2816; idx+=256){     // zero read-slots of o1p
      int q = idx/704, r = idx%704;
      int o = r/11, y = r%11;
      o1p[(q*64 + o)*17 + y + 2] = 0.f;
    }
    __syncthreads();

    {                              // sparse scatter: quarter q does 6 (v,ky) pairs
      int o = tid & 63, q = tid >> 6;
      #pragma unroll
      for (int p6=0; p6<6; ++p6){
        int pr = q*6 + p6;
        int v = pr/3, ky = pr%3;
        int cc = cellsL[a*8 + v];
        int gw = cc/13, gh = cc - gw*13;
        float val = bf2f(Qb[((ky*3+gw)*8 + v)*64 + o]);
        o1p[(q*64 + o)*17 + (gh - ky + 2)] += val;
      }
    }
    __syncthreads();

    for (int idx=tid; idx<704; idx+=256){      // reduce + bias + leaky -> o1
      int o = idx/11, y = idx%11;
      float s = socbL[o];
      #pragma unroll
      for (int q=0; q<4; ++q) s += o1p[(q*64 + o)*17 + y + 2];
      o1[o*12 + y] = leakyf(s);
    }
    __syncthreads();

    {                              // conv2 partials: quarter q covers oo in [q*16,q*16+16)
      int q = tid >> 6, l2 = tid & 63;
      for (int e=l2; e<144; e+=64){
        int p = e & 15, y2 = e >> 4;
        float accv = 0.f;
        #pragma unroll
        for (int oi=0; oi<16; ++oi){
          int oo = q*16 + oi;
          const float* o1r = o1 + oo*12 + y2;
          const float* w2r = W2L + oo*48 + p;
          accv = fmaf(o1r[0], w2r[0], fmaf(o1r[1], w2r[16], fmaf(o1r[2], w2r[32], accv)));
        }
        c2p[q*144 + e] = accv;
      }
    }
    __syncthreads();

    if (tid < 80){                 // fused out2 + leaky + maxpool + store
      int p = tid/5, ww = tid%5;
      float v0, v1;
      {
        int y2 = (ww == 0) ? 0 : 2*ww - 1;
        float s = b2L[p];
        #pragma unroll
        for (int q=0; q<4; ++q) s += c2p[q*144 + y2*16 + p];
        v0 = leakyf(s);
      }
      if (ww == 0) v1 = v0;
      else {
        int y2 = 2*ww;
        float s = b2L[p];
        #pragma unroll
        for (int q=0; q<4; ++q) s += c2p[q*144 + y2*16 + p];
        v1 = leakyf(s);
      }
      xc[(size_t)(n0+a)*112 + 32 + p*5 + ww] = fmaxf(v0, v1);
    }
  }
}

// ---------------------------------------------------------------------------
// Decoder GRU via MFMA + fused output head (validated R3).
// ---------------------------------------------------------------------------
__global__ __launch_bounds__(512,1) void k_dec_mfma(
    const float* __restrict__ xc, const unsigned short* __restrict__ WdecF,
    const unsigned short* __restrict__ WoutF,
    const float* __restrict__ dWih, const float* __restrict__ dbih,
    const float* __restrict__ dbhh, const float* __restrict__ outb,
    float* __restrict__ out)
{
  __shared__ float Gm[384*16];                       // [n][s] f32
  __shared__ __align__(16) unsigned char Hb[16*256]; // h bf16, A-layout, swizzled
  __shared__ float xct[16*XSTR];
  const int tid = threadIdx.x;
  const int g   = tid >> 6;        // wave 0..7
  const int l   = tid & 63;
  const int lr  = l & 15, lg = l >> 4;
  const int n0  = blockIdx.x * 16;
  const int i   = g*16 + lr;       // owned h column (0..127)

  for (int idx=tid; idx<16*112; idx+=512){
    int s = idx/112, k = idx%112;
    xct[s*XSTR + k] = xc[(size_t)(n0+s)*112 + k];
  }
  *(uint2*)(Hb + tid*8) = make_uint2(0,0);
  __syncthreads();

  {
    int s = tid & 15, jq = tid >> 4;                 // jq 0..31
    const float* xr = xct + s*XSTR;
    for (int jj=0; jj<12; ++jj){
      int j = jq*12 + jj;
      float acc = dbih[j];
      const float* wp = dWih + (size_t)j*112;
      for (int k4=0; k4<28; ++k4)
        acc = dot4f(*(const float4*)(wp + k4*4), *(const float4*)(xr + k4*4), acc);
      Gm[j*16 + s] = acc;
    }
  }
  __syncthreads();

  float gi_r[4], gi_z[4], gi_n[4];
  #pragma unroll
  for (int u=0; u<4; ++u){
    int s = lg*4 + u;
    gi_r[u] = Gm[(      i)*16 + s];
    gi_z[u] = Gm[(128 + i)*16 + s];
    gi_n[u] = Gm[(256 + i)*16 + s];
  }
  const float bh_r = dbhh[i], bh_z = dbhh[128+i], bh_n = dbhh[256+i];
  const float obv  = (lr < 5) ? outb[lr] : 0.f;
  __syncthreads();                                   // Gm reused below

  uint4 bgf[12];
  #pragma unroll
  for (int f=0; f<12; ++f)
    bgf[f] = *(const uint4*)(WdecF + (size_t)(g*12 + f)*512 + l*8);
  uint4 bof[4];
  #pragma unroll
  for (int kk=0; kk<4; ++kk)
    bof[kk] = *(const uint4*)(WoutF + (size_t)kk*512 + l*8);

  float hreg[4] = {0.f, 0.f, 0.f, 0.f};
  const int swz = (lr & 7) << 4;

  #pragma unroll 1
  for (int t=0; t<PRED; ++t){
    uint4 ah[4];
    #pragma unroll
    for (int kk=0; kk<4; ++kk)
      ah[kk] = *(const uint4*)(Hb + ((lr*256 + kk*64 + lg*16) ^ swz));

    if (g == 0 && t > 0){
      f32x4 accO = (f32x4){0.f,0.f,0.f,0.f};
      #pragma unroll
      for (int kk=0; kk<4; ++kk)
        accO = __builtin_amdgcn_mfma_f32_16x16x32_bf16(as_bf16x8(ah[kk]), as_bf16x8(bof[kk]), accO, 0,0,0);
      if (lr < 5){
        #pragma unroll
        for (int u=0; u<4; ++u){
          float a = accO[u] + obv;
          float val = (lr < 2) ? a : (lr == 4 ? tanhf_(a) : __expf(a));
          out[((size_t)(t-1)*NAg + n0 + lg*4 + u)*5 + lr] = val;
        }
      }
    }

    f32x4 acc[3];
    #pragma unroll
    for (int nt=0; nt<3; ++nt) acc[nt] = (f32x4){0.f,0.f,0.f,0.f};
    #pragma unroll
    for (int nt=0; nt<3; ++nt)
      #pragma unroll
      for (int kk=0; kk<4; ++kk)
        acc[nt] = __builtin_amdgcn_mfma_f32_16x16x32_bf16(as_bf16x8(ah[kk]), as_bf16x8(bgf[nt*4+kk]), acc[nt], 0,0,0);

    #pragma unroll
    for (int nt=0; nt<3; ++nt)
      *(f32x4*)(Gm + (g*48 + nt*16 + lr)*16 + lg*4) = acc[nt];
    __syncthreads();

    float4 rp = *(const float4*)(Gm + (      i)*16 + lg*4);
    float4 zp = *(const float4*)(Gm + (128 + i)*16 + lg*4);
    float4 hp = *(const float4*)(Gm + (256 + i)*16 + lg*4);
    const float* rpa = &rp.x; const float* zpa = &zp.x; const float* hpa = &hp.x;
    #pragma unroll
    for (int u=0; u<4; ++u){
      float r  = sigf(gi_r[u] + rpa[u] + bh_r);
      float z  = sigf(gi_z[u] + zpa[u] + bh_z);
      float nn = tanhf_(fmaf(r, hpa[u] + bh_n, gi_n[u]));
      float h  = fmaf(z, hreg[u] - nn, nn);
      hreg[u] = h;
      int s = lg*4 + u;
      *(unsigned short*)(Hb + ((s*256 + i*2) ^ ((s & 7) << 4))) = f2bf(h);
    }
    __syncthreads();
  }

  if (g == 0){
    uint4 ah[4];
    #pragma unroll
    for (int kk=0; kk<4; ++kk)
      ah[kk] = *(const uint4*)(Hb + ((lr*256 + kk*64 + lg*16) ^ swz));
    f32x4 accO = (f32x4){0.f,0.f,0.f,0.f};
    #pragma unroll
    for (int kk=0; kk<4; ++kk)
      accO = __builtin_amdgcn_mfma_f32_16x16x32_bf16(as_bf16x8(ah[kk]), as_bf16x8(bof[kk]), accO, 0,0,0);
    if (lr < 5){
      #pragma unroll
      for (int u=0; u<4; ++u){
        float a = accO[u] + obv;
        float val = (lr < 2) ? a : (lr == 4 ? tanhf_(a) : __expf(a));
        out[((size_t)(PRED-1)*NAg + n0 + lg*4 + u)*5 + lr] = val;
      }
    }
  }
}

// ---------------------------------------------------------------------------
extern "C" void kernel_launch(void* const* d_in, const int* in_sizes, int n_in,
                              void* d_out, int out_size, void* d_ws, size_t ws_size,
                              hipStream_t stream)
{
  const float* x      = (const float*)d_in[0];
  const float* ngbrs  = (const float*)d_in[1];
  const float* graphs = (const float*)d_in[2];
  const void*  masks  = d_in[3];
  // d_in[4] = ngbrs_idx (unused by the reference computation)
  const float* dynW   = (const float*)d_in[5];
  const float* dynb   = (const float*)d_in[6];
  const float* eWih   = (const float*)d_in[7];
  const float* eWhh   = (const float*)d_in[8];
  const float* ebih   = (const float*)d_in[9];
  const float* ebhh   = (const float*)d_in[10];
  const float* sW     = (const float*)d_in[11];
  const float* sb     = (const float*)d_in[12];
  const float* hidW   = (const float*)d_in[13];
  const float* hidb   = (const float*)d_in[14];
  const float* socW   = (const float*)d_in[15];
  const float* socb   = (const float*)d_in[16];
  const float* c31W   = (const float*)d_in[17];
  const float* c31b   = (const float*)d_in[18];
  const float* dWih   = (const float*)d_in[19];
  const float* dWhh   = (const float*)d_in[20];
  const float* dbih   = (const float*)d_in[21];
  const float* dbhh   = (const float*)d_in[22];
  const float* outW   = (const float*)d_in[23];
  const float* outb   = (const float*)d_in[24];
  float* out = (float*)d_out;

  char* ws = (char*)d_ws;
  size_t off = 0;
  __hip_bfloat16* E = (__hip_bfloat16*)(ws + off); off += (size_t)T_OBS*SEQ*64*2;   // 75.5 MB
  float* h_all      = (float*)(ws + off);          off += (size_t)SEQ*64*4;          // 9.4 MB
  int*   cells      = (int*)(ws + off);            off += (size_t)NAg*8*4;
  float* xc         = (float*)(ws + off);          off += (size_t)NAg*112*4;
  unsigned short* Wpk = (unsigned short*)(ws + off); off += (size_t)48*512*2;
  unsigned short* WdecF = (unsigned short*)(ws + off); off += (size_t)96*512*2;
  unsigned short* WoutF = (unsigned short*)(ws + off); off += (size_t)4*512*2;
  unsigned short* SWF = (unsigned short*)(ws + off); off += (size_t)16*512*2;
  unsigned short* WsocF = (unsigned short*)(ws + off); off += (size_t)72*512*2;

  k_decode_masks<<<16, 256, 0, stream>>>(masks, cells);
  k_prep<<<192, 256, 0, stream>>>(eWih, eWhh, Wpk, dWhh, WdecF, outW, WoutF, sW, SWF, socW, WsocF);
  k_embed_x<<<16384, 256, 0, stream>>>(x, dynW, dynb, E);
  k_embed_agg_mfma<<<4096, 256, 0, stream>>>(ngbrs, graphs, dynW, dynb, SWF, sb, E);
  k_gru_enc_mfma<<<576, 256, 0, stream>>>((const unsigned short*)E, Wpk, ebih, ebhh, h_all);
  k_xs<<<512, 256, 0, stream>>>(h_all, hidW, hidb, xc);
  k_soc_mfma<<<512, 256, 0, stream>>>(h_all, cells, WsocF, socb, c31W, c31b, xc);
  k_dec_mfma<<<256, 512, 0, stream>>>(xc, WdecF, WoutF, dWih, dbih, dbhh, outb, out);
}

// Round 7
// 308.889 us; speedup vs baseline: 4.4241x; 1.1261x over previous
//
#include <hip/hip_runtime.h>
#include <hip/hip_bf16.h>

#define T_OBS 16
#define NAg   4096
#define Vn    8
#define NV    32768           // NAg*Vn
#define SEQ   36864           // NAg + NV
#define PRED  25
#define XSTR  116             // padded LDS stride for 112-wide xc tile

typedef __bf16 bf16x8 __attribute__((ext_vector_type(8)));
typedef float  f32x4  __attribute__((ext_vector_type(4)));

__device__ __forceinline__ float leakyf(float v){ return v >= 0.f ? v : 0.1f*v; }
__device__ __forceinline__ float sigf(float x){ return 1.f/(1.f+__expf(-x)); }
__device__ __forceinline__ float tanhf_(float x){
  x = fminf(fmaxf(x, -10.f), 10.f);
  float e = __expf(2.f*x);
  return (e-1.f)/(e+1.f);
}
// branch-free tanh: 2/(1+e^{-2x}) - 1; exp saturation gives exact +-1 tails
__device__ __forceinline__ float tanh2f(float x){
  return fmaf(2.f, 1.f/(1.f+__expf(-2.f*x)), -1.f);
}
__device__ __forceinline__ float bf2f(unsigned short u){
  union{unsigned int i; float f;} v; v.i = ((unsigned int)u)<<16; return v.f;
}
__device__ __forceinline__ unsigned short f2bf(float f){
  __hip_bfloat16 b = __float2bfloat16(f);
  return *reinterpret_cast<unsigned short*>(&b);
}
__device__ __forceinline__ float dot4f(float4 a, float4 b, float acc){
  return fmaf(a.x,b.x, fmaf(a.y,b.y, fmaf(a.z,b.z, fmaf(a.w,b.w, acc))));
}
__device__ __forceinline__ bf16x8 as_bf16x8(uint4 u){
  union { uint4 a; bf16x8 b; } v; v.a = u; return v.b;
}
__device__ __forceinline__ uint4 pack8bf(float4 a, float4 b){
  union{ unsigned short s[8]; uint4 u; } o;
  o.s[0]=f2bf(a.x); o.s[1]=f2bf(a.y); o.s[2]=f2bf(a.z); o.s[3]=f2bf(a.w);
  o.s[4]=f2bf(b.x); o.s[5]=f2bf(b.y); o.s[6]=f2bf(b.z); o.s[7]=f2bf(b.w);
  return o.u;
}

// ---------------------------------------------------------------------------
// Decode bool masks -> per-agent 8 selected cell indices.
// ---------------------------------------------------------------------------
__global__ void k_decode_masks(const void* __restrict__ masks, int* __restrict__ cells){
  int n = blockIdx.x*blockDim.x + threadIdx.x;
  if (n >= NAg) return;
  const unsigned char* m8  = (const unsigned char*)masks;
  const int*           m32 = (const int*)masks;
  int tmp[8]; for (int v=0; v<8; ++v) tmp[v] = 0;
  int cnt = 0;
  for (int cc=0; cc<39; ++cc){                 // u8 interpretation (bool bytes)
    size_t base = ((size_t)n*39 + cc)*64;
    if (m8[base] && m8[base+1] && m8[base+33]){ if (cnt<8) tmp[cnt]=cc; cnt++; }
  }
  if (cnt != 8){                               // fallback: 4-byte elements
    cnt = 0;
    for (int cc=0; cc<39; ++cc){
      size_t base = ((size_t)n*39 + cc)*64;
      if (m32[base] != 0){ if (cnt<8) tmp[cnt]=cc; cnt++; }
    }
  }
  for (int v=0; v<8; ++v) cells[n*8+v] = tmp[v];
}

// ---------------------------------------------------------------------------
// One-shot weight re-layouts (unchanged from R5).
// ---------------------------------------------------------------------------
__global__ void k_prep(const float* __restrict__ eWih, const float* __restrict__ eWhh,
                       unsigned short* __restrict__ Wpk,
                       const float* __restrict__ dWhh, unsigned short* __restrict__ WdecF,
                       const float* __restrict__ outW, unsigned short* __restrict__ WoutF,
                       const float* __restrict__ sW, unsigned short* __restrict__ SWF,
                       const float* __restrict__ socW, unsigned short* __restrict__ WsocF){
  int idx = blockIdx.x*blockDim.x + threadIdx.x;   // 49152 threads
  if (idx < 24576){                                // encoder: 48 frags * 512
    int f   = idx >> 9;
    int rem = idx & 511;
    int l   = rem >> 3, j = rem & 7;
    int lr  = l & 15, lg = l >> 4;
    float val;
    if (f < 32){
      int nt = f >> 2, kk = f & 3;
      int n  = nt*16 + lr;                         // rows 0..127 = r,z gates
      int k  = kk*32 + lg*8 + j;
      val = (k < 64) ? eWih[(size_t)n*64 + k] : eWhh[(size_t)n*64 + (k-64)];
    } else if (f < 40){
      int q = f - 32;
      int n = (8 + (q>>1))*16 + lr;                // rows 128..191 = n gate
      int k = (q&1)*32 + lg*8 + j;
      val = eWih[(size_t)n*64 + k];
    } else {
      int q = f - 40;
      int n = (8 + (q>>1))*16 + lr;
      int k = (q&1)*32 + lg*8 + j;
      val = eWhh[(size_t)n*64 + k];
    }
    Wpk[f*512 + l*8 + j] = f2bf(val);
  }
  if (idx < 49152){                                // decoder: 96 frags * 512
    int f   = idx >> 9;                            // g*12 + nt*4 + kk
    int rem = idx & 511;
    int l   = rem >> 3, j = rem & 7;
    int lr  = l & 15, lg = l >> 4;
    int g = f/12, loc = f%12, nt = loc>>2, kk = loc&3;
    int n = g*48 + nt*16 + lr;
    int k = kk*32 + lg*8 + j;
    WdecF[idx] = f2bf(dWhh[(size_t)n*128 + k]);
  }
  if (idx < 2048){                                 // out head: 4 frags * 512
    int kk  = idx >> 9;
    int rem = idx & 511;
    int l   = rem >> 3, j = rem & 7;
    int lr  = l & 15, lg = l >> 4;
    int k = kk*32 + lg*8 + j;
    float v = (lr < 5) ? outW[(size_t)lr*128 + k] : 0.f;
    WoutF[idx] = f2bf(v);
  }
  if (idx < 8192){                                 // s_W: 16 frags * 512
    int f   = idx >> 9;                            // nt*2 + kk
    int rem = idx & 511;
    int l   = rem >> 3, j = rem & 7;
    int lr  = l & 15, lg = l >> 4;
    int nt = f >> 1, kk = f & 1;
    int nn = nt*16 + lr;
    int k  = kk*32 + lg*8 + j;
    SWF[idx] = f2bf(sW[(size_t)nn*64 + k]);
  }
  if (idx < 36864){                                // soc conv1: 72 frags * 512
    int f   = idx >> 9;                            // (w*9+kk)*2+ks
    int rem = idx & 511;
    int l   = rem >> 3, j = rem & 7;
    int lr  = l & 15, lg = l >> 4;
    int w = f/18, loc = f%18, kk = loc>>1, ks = loc&1;
    int o = w*16 + lr;
    int c = ks*32 + lg*8 + j;
    WsocF[idx] = f2bf(socW[(size_t)o*576 + c*9 + kk]);
  }
}

// ---------------------------------------------------------------------------
// x_e = leaky(x @ dyn_W.T + dyn_b) -> E[t][0..4095][c] (bf16)
// ---------------------------------------------------------------------------
__global__ void k_embed_x(const float* __restrict__ x, const float* __restrict__ dynW,
                          const float* __restrict__ dynb, __hip_bfloat16* __restrict__ E){
  int idx = blockIdx.x*blockDim.x + threadIdx.x;   // 16*4096*64 exactly
  int c = idx & 63;
  int s = (idx >> 6) & 4095;
  int t = idx >> 18;
  float x0 = x[((size_t)t*NAg + s)*2 + 0];
  float x1 = x[((size_t)t*NAg + s)*2 + 1];
  float v = leakyf(fmaf(x0, dynW[c*2+0], fmaf(x1, dynW[c*2+1], dynb[c])));
  E[((size_t)t*SEQ + s)*64 + c] = __float2bfloat16(v);
}

// ---------------------------------------------------------------------------
// Per agent n (fused, MFMA): ng_e -> H = ng_e@sW.T+sb -> graph einsum -> E.
// (validated R4)
// ---------------------------------------------------------------------------
__global__ __launch_bounds__(256,2) void k_embed_agg_mfma(
    const float* __restrict__ ngbrs, const float* __restrict__ graphs,
    const float* __restrict__ dynW, const float* __restrict__ dynb,
    const unsigned short* __restrict__ SWF, const float* __restrict__ sb,
    __hip_bfloat16* __restrict__ E)
{
  __shared__ __align__(16) unsigned char ngeb[128*128];   // bf16 [row][64] swizzled
  __shared__ __align__(16) unsigned short hm[128*136];    // bf16 [tv][128 pad 136]
  __shared__ float2 pL[128];
  __shared__ float  gL[128];
  __shared__ float2 dwL[64];
  __shared__ float  dbL[64];
  const int tid = threadIdx.x;
  const int n = blockIdx.x;

  if (tid < 128) gL[tid] = graphs[(size_t)n*128 + tid];
  if (tid < 64)  dwL[tid] = *(const float2*)(dynW + tid*2);
  if (tid < 64)  dbL[tid] = dynb[tid];
  if (tid < 128){
    int t = tid >> 3, v = tid & 7;
    pL[tid] = *(const float2*)(ngbrs + ((size_t)t*NV + (size_t)n*8 + v)*2);
  }
  __syncthreads();

  #pragma unroll
  for (int p=0; p<4; ++p){
    int chunk = tid + p*256;          // 1024: row*8 + c8
    int row = chunk >> 3, c8 = chunk & 7;
    float2 xy = pL[row];
    union { unsigned short s[8]; uint4 u; } ou;
    #pragma unroll
    for (int jj=0; jj<8; ++jj){
      int c = c8*8 + jj;
      ou.s[jj] = f2bf(leakyf(fmaf(xy.x, dwL[c].x, fmaf(xy.y, dwL[c].y, dbL[c]))));
    }
    *(uint4*)(ngeb + ((row*128 + c8*16) ^ ((row&7)<<4))) = ou.u;
  }
  __syncthreads();

  const int w4 = tid >> 6, l = tid & 63, lr = l & 15, lg = l >> 4;
  {
    uint4 bsw[16];
    #pragma unroll
    for (int f=0; f<16; ++f) bsw[f] = *(const uint4*)(SWF + f*512 + l*8);
    float sbv[8];
    #pragma unroll
    for (int nt=0; nt<8; ++nt) sbv[nt] = sb[nt*16 + lr];

    f32x4 acc[2][8];
    #pragma unroll
    for (int m=0; m<2; ++m)
      #pragma unroll
      for (int nt=0; nt<8; ++nt)
        acc[m][nt] = (f32x4){sbv[nt], sbv[nt], sbv[nt], sbv[nt]};

    #pragma unroll
    for (int m=0; m<2; ++m){
      int row = (w4*2+m)*16 + lr;
      int rb = row*128, sz = (row&7)<<4;
      uint4 a0 = *(const uint4*)(ngeb + ((rb      + lg*16) ^ sz));
      uint4 a1 = *(const uint4*)(ngeb + ((rb + 64 + lg*16) ^ sz));
      bf16x8 A0 = as_bf16x8(a0), A1 = as_bf16x8(a1);
      #pragma unroll
      for (int nt=0; nt<8; ++nt){
        acc[m][nt] = __builtin_amdgcn_mfma_f32_16x16x32_bf16(A0, as_bf16x8(bsw[nt*2+0]), acc[m][nt], 0,0,0);
        acc[m][nt] = __builtin_amdgcn_mfma_f32_16x16x32_bf16(A1, as_bf16x8(bsw[nt*2+1]), acc[m][nt], 0,0,0);
      }
    }
    #pragma unroll
    for (int m=0; m<2; ++m)
      #pragma unroll
      for (int nt=0; nt<8; ++nt)
        #pragma unroll
        for (int jj=0; jj<4; ++jj)
          hm[((w4*2+m)*16 + lg*4 + jj)*136 + nt*16 + lr] = f2bf(acc[m][nt][jj]);
  }
  __syncthreads();

  #pragma unroll
  for (int p=0; p<4; ++p){
    int task = tid + p*256;           // 1024: t*64 + wv*8 + c8
    int c8 = task & 7, wv = (task>>3)&7, t = task >> 6;
    float a8[8];
    #pragma unroll
    for (int jj=0; jj<8; ++jj) a8[jj] = 0.f;
    #pragma unroll
    for (int k=0; k<2; ++k){
      #pragma unroll
      for (int v=0; v<8; ++v){
        float g = gL[k*64 + v*8 + wv];
        uint4 hv4 = *(const uint4*)(hm + (t*8+v)*136 + k*64 + c8*8);
        const unsigned short* hh = (const unsigned short*)&hv4;
        #pragma unroll
        for (int jj=0; jj<8; ++jj) a8[jj] = fmaf(g, bf2f(hh[jj]), a8[jj]);
      }
    }
    union { unsigned short s[8]; uint4 u; } ou;
    #pragma unroll
    for (int jj=0; jj<8; ++jj) ou.s[jj] = f2bf(a8[jj]);
    *(uint4*)((unsigned short*)E + ((size_t)t*SEQ + NAg + (size_t)n*8 + wv)*64 + c8*8) = ou.u;
  }
}

// ---------------------------------------------------------------------------
// Encoder GRU via MFMA, gate-split across 4 waves for occupancy.
// Block = 16 seqs (2304 blocks). Wave w owns rz N-tiles {2w,2w+1} + nI/nH
// tile w (12 B-frags in VGPRs). Gate pre-acts -> Gm (f32 LDS) -> barrier ->
// each lane updates 4 h elements (col i=l, seqs w*4..w*4+3), h bf16 -> Hb.
// ---------------------------------------------------------------------------
__global__ __launch_bounds__(256,4) void k_gru_enc_mfma(
    const unsigned short* __restrict__ E,
    const unsigned short* __restrict__ Wpk,
    const float* __restrict__ bih, const float* __restrict__ bhh,
    float* __restrict__ h_all)
{
  __shared__ float Gm[256*16];                        // 16 KB gate pre-acts [row][s]
  __shared__ __align__(16) unsigned char Hb[16*128];  // 2 KB h bf16, swizzled
  const int tid = threadIdx.x;
  const int w  = tid >> 6;         // wave 0..3
  const int l  = tid & 63;
  const int lr = l & 15;           // A row (seq) / B col-in-tile
  const int lg = l >> 4;
  const size_t s0 = (size_t)blockIdx.x * 16;

  // B fragments: 12 per wave (rz tiles 2w,2w+1 = frags 8w..8w+7; nI 32+2w..;
  // nH 40+2w..)
  uint4 bf[12];
  #pragma unroll
  for (int q=0; q<8; ++q) bf[q]   = *(const uint4*)(Wpk + (8*w + q)*512 + l*8);
  #pragma unroll
  for (int q=0; q<2; ++q) bf[8+q] = *(const uint4*)(Wpk + (32 + 2*w + q)*512 + l*8);
  #pragma unroll
  for (int q=0; q<2; ++q) bf[10+q]= *(const uint4*)(Wpk + (40 + 2*w + q)*512 + l*8);

  // epilogue constants for owned column i=l
  const float brz_r = bih[l]     + bhh[l];
  const float brz_z = bih[64+l]  + bhh[64+l];
  const float bni   = bih[128+l];
  const float bnh   = bhh[128+l];

  // zero Hb
  *(uint4*)(Hb + tid*8) = make_uint4(0,0,0,0);  // 256*8 = 2048 B exactly... (uint2)
  // (uint4 would be 4096; fix: use uint2)
  __syncthreads();
  if (tid < 256) *(uint2*)(Hb + tid*8) = make_uint2(0,0);
  __syncthreads();

  float hreg[4] = {0.f,0.f,0.f,0.f};

  // prefetch x fragments for t=0 (A rows = seqs s0+lr)
  uint4 ax0, ax1;
  {
    const unsigned short* p = E + (s0 + lr)*64 + lg*8;
    ax0 = *(const uint4*)(p);
    ax1 = *(const uint4*)(p + 32);
  }

  const int swz = (lr & 7) << 4;

  #pragma unroll 1
  for (int t=0; t<T_OBS; ++t){
    int tn = (t < 15) ? t+1 : 15;
    const unsigned short* pn = E + ((size_t)tn*SEQ + s0 + lr)*64 + lg*8;
    uint4 nx0 = *(const uint4*)(pn);
    uint4 nx1 = *(const uint4*)(pn + 32);

    // h A-frags from swizzled Hb (row = seq lr, 64 cols bf16 = 128 B/row)
    uint4 ah0 = *(const uint4*)(Hb + ((lr*128 + lg*16) ^ swz));
    uint4 ah1 = *(const uint4*)(Hb + ((lr*128 + 64 + lg*16) ^ swz));

    bf16x8 Ax0 = as_bf16x8(ax0), Ax1 = as_bf16x8(ax1);
    bf16x8 Ah0 = as_bf16x8(ah0), Ah1 = as_bf16x8(ah1);

    f32x4 accRZ[2], accNI, accNH;
    #pragma unroll
    for (int m=0; m<2; ++m) accRZ[m] = (f32x4){0.f,0.f,0.f,0.f};
    accNI = (f32x4){0.f,0.f,0.f,0.f};
    accNH = (f32x4){0.f,0.f,0.f,0.f};

    #pragma unroll
    for (int m=0; m<2; ++m){
      accRZ[m] = __builtin_amdgcn_mfma_f32_16x16x32_bf16(Ax0, as_bf16x8(bf[m*4+0]), accRZ[m], 0,0,0);
      accRZ[m] = __builtin_amdgcn_mfma_f32_16x16x32_bf16(Ax1, as_bf16x8(bf[m*4+1]), accRZ[m], 0,0,0);
      accRZ[m] = __builtin_amdgcn_mfma_f32_16x16x32_bf16(Ah0, as_bf16x8(bf[m*4+2]), accRZ[m], 0,0,0);
      accRZ[m] = __builtin_amdgcn_mfma_f32_16x16x32_bf16(Ah1, as_bf16x8(bf[m*4+3]), accRZ[m], 0,0,0);
    }
    accNI = __builtin_amdgcn_mfma_f32_16x16x32_bf16(Ax0, as_bf16x8(bf[8]),  accNI, 0,0,0);
    accNI = __builtin_amdgcn_mfma_f32_16x16x32_bf16(Ax1, as_bf16x8(bf[9]),  accNI, 0,0,0);
    accNH = __builtin_amdgcn_mfma_f32_16x16x32_bf16(Ah0, as_bf16x8(bf[10]), accNH, 0,0,0);
    accNH = __builtin_amdgcn_mfma_f32_16x16x32_bf16(Ah1, as_bf16x8(bf[11]), accNH, 0,0,0);

    // gate pre-acts -> Gm[row][s]; D: col=lr (gate), row=lg*4+reg (seq)
    #pragma unroll
    for (int m=0; m<2; ++m)
      *(f32x4*)(Gm + ((2*w+m)*16 + lr)*16 + lg*4) = accRZ[m];
    *(f32x4*)(Gm + (128 + w*16 + lr)*16 + lg*4) = accNI;
    *(f32x4*)(Gm + (192 + w*16 + lr)*16 + lg*4) = accNH;
    __syncthreads();

    // elementwise: lane owns h col i=l, seqs w*4..w*4+3
    float4 rp = *(const float4*)(Gm + (      l)*16 + w*4);
    float4 zp = *(const float4*)(Gm + ( 64 + l)*16 + w*4);
    float4 ip = *(const float4*)(Gm + (128 + l)*16 + w*4);
    float4 hp = *(const float4*)(Gm + (192 + l)*16 + w*4);
    const float* rpa = &rp.x; const float* zpa = &zp.x;
    const float* ipa = &ip.x; const float* hpa = &hp.x;
    #pragma unroll
    for (int u=0; u<4; ++u){
      float r  = sigf(rpa[u] + brz_r);
      float z  = sigf(zpa[u] + brz_z);
      float nn = tanh2f(fmaf(r, hpa[u] + bnh, ipa[u] + bni));
      float h  = fmaf(z, hreg[u] - nn, nn);
      hreg[u]  = h;
      int s = w*4 + u;
      *(unsigned short*)(Hb + ((s*128 + l*2) ^ ((s & 7) << 4))) = f2bf(h);
    }
    __syncthreads();

    ax0 = nx0; ax1 = nx1;
  }

  // final h -> h_all (f32), coalesced over l
  #pragma unroll
  for (int u=0; u<4; ++u)
    h_all[(s0 + w*4 + u)*64 + l] = hreg[u];
}

// ---------------------------------------------------------------------------
// x_s = leaky(h_x @ hid_W.T + hid_b) -> xc[:, 0:32]
// ---------------------------------------------------------------------------
__global__ void k_xs(const float* __restrict__ h_all, const float* __restrict__ hidW,
                     const float* __restrict__ hidb, float* __restrict__ xc){
  int idx = blockIdx.x*blockDim.x + threadIdx.x;   // 4096*32
  int j = idx & 31, n = idx >> 5;
  const float* h = h_all + (size_t)n*64;
  const float* w = hidW + (size_t)j*64;
  float acc = hidb[j];
  for (int k4=0; k4<16; ++k4)
    acc = dot4f(*(const float4*)(h + k4*4), *(const float4*)(w + k4*4), acc);
  xc[(size_t)n*112 + j] = leakyf(acc);
}

// ---------------------------------------------------------------------------
// Social branch via MFMA (validated R5).
// ---------------------------------------------------------------------------
__global__ __launch_bounds__(256,3) void k_soc_mfma(
    const float* __restrict__ h_all, const int* __restrict__ cells,
    const unsigned short* __restrict__ WsocF, const float* __restrict__ socb,
    const float* __restrict__ c31W, const float* __restrict__ c31b,
    float* __restrict__ xc)
{
  __shared__ unsigned short Qb[9*8*64];   // 9 KB  [kk][v][o] bf16
  __shared__ float o1p[4*64*17];          // 17 KB scatter partials (y shifted +2)
  __shared__ float o1[64*12];             // 3 KB  out1 (y 0..10)
  __shared__ float c2p[4*144];            // 2.25 KB conv2 partials
  __shared__ float W2L[64*48];            // 12 KB [o][ky][p]
  __shared__ float socbL[64];
  __shared__ float b2L[16];
  __shared__ int   cellsL[64];            // [a][v]

  const int tid = threadIdx.x;
  const int w  = tid >> 6;
  const int l  = tid & 63;
  const int lr = l & 15, lg = l >> 4;
  const int n0 = blockIdx.x * 8;

  for (int idx=tid; idx<3072; idx+=256){
    int p = idx/192, rem = idx%192, o = rem/3, ky = rem%3;
    W2L[(o*3+ky)*16 + p] = c31W[idx];
  }
  if (tid < 64) socbL[tid] = socb[tid];
  if (tid < 16) b2L[tid]  = c31b[tid];
  if (tid < 64) cellsL[tid] = cells[n0*8 + tid];

  uint4 bs[18];
  #pragma unroll
  for (int f=0; f<18; ++f)
    bs[f] = *(const uint4*)(WsocF + (size_t)(w*18 + f)*512 + l*8);
  __syncthreads();

  #pragma unroll 1
  for (int a=0; a<8; ++a){
    uint4 ax0u = make_uint4(0,0,0,0), ax1u = make_uint4(0,0,0,0);
    if (lr < 8){
      const float* hp = h_all + ((size_t)NAg + (size_t)(n0+a)*8 + lr)*64 + lg*8;
      float4 f0 = *(const float4*)(hp);
      float4 f1 = *(const float4*)(hp + 4);
      float4 f2 = *(const float4*)(hp + 32);
      float4 f3 = *(const float4*)(hp + 36);
      ax0u = pack8bf(f0, f1);
      ax1u = pack8bf(f2, f3);
    }
    bf16x8 A0 = as_bf16x8(ax0u), A1 = as_bf16x8(ax1u);

    f32x4 acc[9];
    #pragma unroll
    for (int kk=0; kk<9; ++kk) acc[kk] = (f32x4){0.f,0.f,0.f,0.f};
    #pragma unroll
    for (int kk=0; kk<9; ++kk){
      acc[kk] = __builtin_amdgcn_mfma_f32_16x16x32_bf16(A0, as_bf16x8(bs[kk*2+0]), acc[kk], 0,0,0);
      acc[kk] = __builtin_amdgcn_mfma_f32_16x16x32_bf16(A1, as_bf16x8(bs[kk*2+1]), acc[kk], 0,0,0);
    }

    __syncthreads();

    if (lg < 2){
      #pragma unroll
      for (int kk=0; kk<9; ++kk)
        #pragma unroll
        for (int j=0; j<4; ++j)
          Qb[(kk*8 + lg*4 + j)*64 + w*16 + lr] = f2bf(acc[kk][j]);
    }
    for (int idx=tid; idx<2816; idx+=256){
      int q = idx/704, r = idx%704;
      int o = r/11, y = r%11;
      o1p[(q*64 + o)*17 + y + 2] = 0.f;
    }
    __syncthreads();

    {
      int o = tid & 63, q = tid >> 6;
      #pragma unroll
      for (int p6=0; p6<6; ++p6){
        int pr = q*6 + p6;
        int v = pr/3, ky = pr%3;
        int cc = cellsL[a*8 + v];
        int gw = cc/13, gh = cc - gw*13;
        float val = bf2f(Qb[((ky*3+gw)*8 + v)*64 + o]);
        o1p[(q*64 + o)*17 + (gh - ky + 2)] += val;
      }
    }
    __syncthreads();

    for (int idx=tid; idx<704; idx+=256){
      int o = idx/11, y = idx%11;
      float s = socbL[o];
      #pragma unroll
      for (int q=0; q<4; ++q) s += o1p[(q*64 + o)*17 + y + 2];
      o1[o*12 + y] = leakyf(s);
    }
    __syncthreads();

    {
      int q = tid >> 6, l2 = tid & 63;
      for (int e=l2; e<144; e+=64){
        int p = e & 15, y2 = e >> 4;
        float accv = 0.f;
        #pragma unroll
        for (int oi=0; oi<16; ++oi){
          int oo = q*16 + oi;
          const float* o1r = o1 + oo*12 + y2;
          const float* w2r = W2L + oo*48 + p;
          accv = fmaf(o1r[0], w2r[0], fmaf(o1r[1], w2r[16], fmaf(o1r[2], w2r[32], accv)));
        }
        c2p[q*144 + e] = accv;
      }
    }
    __syncthreads();

    if (tid < 80){
      int p = tid/5, ww = tid%5;
      float v0, v1;
      {
        int y2 = (ww == 0) ? 0 : 2*ww - 1;
        float s = b2L[p];
        #pragma unroll
        for (int q=0; q<4; ++q) s += c2p[q*144 + y2*16 + p];
        v0 = leakyf(s);
      }
      if (ww == 0) v1 = v0;
      else {
        int y2 = 2*ww;
        float s = b2L[p];
        #pragma unroll
        for (int q=0; q<4; ++q) s += c2p[q*144 + y2*16 + p];
        v1 = leakyf(s);
      }
      xc[(size_t)(n0+a)*112 + 32 + p*5 + ww] = fmaxf(v0, v1);
    }
  }
}

// ---------------------------------------------------------------------------
// Decoder GRU via MFMA + fused output head (validated R3).
// ---------------------------------------------------------------------------
__global__ __launch_bounds__(512,1) void k_dec_mfma(
    const float* __restrict__ xc, const unsigned short* __restrict__ WdecF,
    const unsigned short* __restrict__ WoutF,
    const float* __restrict__ dWih, const float* __restrict__ dbih,
    const float* __restrict__ dbhh, const float* __restrict__ outb,
    float* __restrict__ out)
{
  __shared__ float Gm[384*16];                       // [n][s] f32
  __shared__ __align__(16) unsigned char Hb[16*256]; // h bf16, A-layout, swizzled
  __shared__ float xct[16*XSTR];
  const int tid = threadIdx.x;
  const int g   = tid >> 6;        // wave 0..7
  const int l   = tid & 63;
  const int lr  = l & 15, lg = l >> 4;
  const int n0  = blockIdx.x * 16;
  const int i   = g*16 + lr;       // owned h column (0..127)

  for (int idx=tid; idx<16*112; idx+=512){
    int s = idx/112, k = idx%112;
    xct[s*XSTR + k] = xc[(size_t)(n0+s)*112 + k];
  }
  *(uint2*)(Hb + tid*8) = make_uint2(0,0);
  __syncthreads();

  {
    int s = tid & 15, jq = tid >> 4;                 // jq 0..31
    const float* xr = xct + s*XSTR;
    for (int jj=0; jj<12; ++jj){
      int j = jq*12 + jj;
      float acc = dbih[j];
      const float* wp = dWih + (size_t)j*112;
      for (int k4=0; k4<28; ++k4)
        acc = dot4f(*(const float4*)(wp + k4*4), *(const float4*)(xr + k4*4), acc);
      Gm[j*16 + s] = acc;
    }
  }
  __syncthreads();

  float gi_r[4], gi_z[4], gi_n[4];
  #pragma unroll
  for (int u=0; u<4; ++u){
    int s = lg*4 + u;
    gi_r[u] = Gm[(      i)*16 + s];
    gi_z[u] = Gm[(128 + i)*16 + s];
    gi_n[u] = Gm[(256 + i)*16 + s];
  }
  const float bh_r = dbhh[i], bh_z = dbhh[128+i], bh_n = dbhh[256+i];
  const float obv  = (lr < 5) ? outb[lr] : 0.f;
  __syncthreads();                                   // Gm reused below

  uint4 bgf[12];
  #pragma unroll
  for (int f=0; f<12; ++f)
    bgf[f] = *(const uint4*)(WdecF + (size_t)(g*12 + f)*512 + l*8);
  uint4 bof[4];
  #pragma unroll
  for (int kk=0; kk<4; ++kk)
    bof[kk] = *(const uint4*)(WoutF + (size_t)kk*512 + l*8);

  float hreg[4] = {0.f, 0.f, 0.f, 0.f};
  const int swz = (lr & 7) << 4;

  #pragma unroll 1
  for (int t=0; t<PRED; ++t){
    uint4 ah[4];
    #pragma unroll
    for (int kk=0; kk<4; ++kk)
      ah[kk] = *(const uint4*)(Hb + ((lr*256 + kk*64 + lg*16) ^ swz));

    if (g == 0 && t > 0){
      f32x4 accO = (f32x4){0.f,0.f,0.f,0.f};
      #pragma unroll
      for (int kk=0; kk<4; ++kk)
        accO = __builtin_amdgcn_mfma_f32_16x16x32_bf16(as_bf16x8(ah[kk]), as_bf16x8(bof[kk]), accO, 0,0,0);
      if (lr < 5){
        #pragma unroll
        for (int u=0; u<4; ++u){
          float a = accO[u] + obv;
          float val = (lr < 2) ? a : (lr == 4 ? tanhf_(a) : __expf(a));
          out[((size_t)(t-1)*NAg + n0 + lg*4 + u)*5 + lr] = val;
        }
      }
    }

    f32x4 acc[3];
    #pragma unroll
    for (int nt=0; nt<3; ++nt) acc[nt] = (f32x4){0.f,0.f,0.f,0.f};
    #pragma unroll
    for (int nt=0; nt<3; ++nt)
      #pragma unroll
      for (int kk=0; kk<4; ++kk)
        acc[nt] = __builtin_amdgcn_mfma_f32_16x16x32_bf16(as_bf16x8(ah[kk]), as_bf16x8(bgf[nt*4+kk]), acc[nt], 0,0,0);

    #pragma unroll
    for (int nt=0; nt<3; ++nt)
      *(f32x4*)(Gm + (g*48 + nt*16 + lr)*16 + lg*4) = acc[nt];
    __syncthreads();

    float4 rp = *(const float4*)(Gm + (      i)*16 + lg*4);
    float4 zp = *(const float4*)(Gm + (128 + i)*16 + lg*4);
    float4 hp = *(const float4*)(Gm + (256 + i)*16 + lg*4);
    const float* rpa = &rp.x; const float* zpa = &zp.x; const float* hpa = &hp.x;
    #pragma unroll
    for (int u=0; u<4; ++u){
      float r  = sigf(gi_r[u] + rpa[u] + bh_r);
      float z  = sigf(gi_z[u] + zpa[u] + bh_z);
      float nn = tanhf_(fmaf(r, hpa[u] + bh_n, gi_n[u]));
      float h  = fmaf(z, hreg[u] - nn, nn);
      hreg[u] = h;
      int s = lg*4 + u;
      *(unsigned short*)(Hb + ((s*256 + i*2) ^ ((s & 7) << 4))) = f2bf(h);
    }
    __syncthreads();
  }

  if (g == 0){
    uint4 ah[4];
    #pragma unroll
    for (int kk=0; kk<4; ++kk)
      ah[kk] = *(const uint4*)(Hb + ((lr*256 + kk*64 + lg*16) ^ swz));
    f32x4 accO = (f32x4){0.f,0.f,0.f,0.f};
    #pragma unroll
    for (int kk=0; kk<4; ++kk)
      accO = __builtin_amdgcn_mfma_f32_16x16x32_bf16(as_bf16x8(ah[kk]), as_bf16x8(bof[kk]), accO, 0,0,0);
    if (lr < 5){
      #pragma unroll
      for (int u=0; u<4; ++u){
        float a = accO[u] + obv;
        float val = (lr < 2) ? a : (lr == 4 ? tanhf_(a) : __expf(a));
        out[((size_t)(PRED-1)*NAg + n0 + lg*4 + u)*5 + lr] = val;
      }
    }
  }
}

// ---------------------------------------------------------------------------
extern "C" void kernel_launch(void* const* d_in, const int* in_sizes, int n_in,
                              void* d_out, int out_size, void* d_ws, size_t ws_size,
                              hipStream_t stream)
{
  const float* x      = (const float*)d_in[0];
  const float* ngbrs  = (const float*)d_in[1];
  const float* graphs = (const float*)d_in[2];
  const void*  masks  = d_in[3];
  // d_in[4] = ngbrs_idx (unused by the reference computation)
  const float* dynW   = (const float*)d_in[5];
  const float* dynb   = (const float*)d_in[6];
  const float* eWih   = (const float*)d_in[7];
  const float* eWhh   = (const float*)d_in[8];
  const float* ebih   = (const float*)d_in[9];
  const float* ebhh   = (const float*)d_in[10];
  const float* sW     = (const float*)d_in[11];
  const float* sb     = (const float*)d_in[12];
  const float* hidW   = (const float*)d_in[13];
  const float* hidb   = (const float*)d_in[14];
  const float* socW   = (const float*)d_in[15];
  const float* socb   = (const float*)d_in[16];
  const float* c31W   = (const float*)d_in[17];
  const float* c31b   = (const float*)d_in[18];
  const float* dWih   = (const float*)d_in[19];
  const float* dWhh   = (const float*)d_in[20];
  const float* dbih   = (const float*)d_in[21];
  const float* dbhh   = (const float*)d_in[22];
  const float* outW   = (const float*)d_in[23];
  const float* outb   = (const float*)d_in[24];
  float* out = (float*)d_out;

  char* ws = (char*)d_ws;
  size_t off = 0;
  __hip_bfloat16* E = (__hip_bfloat16*)(ws + off); off += (size_t)T_OBS*SEQ*64*2;   // 75.5 MB
  float* h_all      = (float*)(ws + off);          off += (size_t)SEQ*64*4;          // 9.4 MB
  int*   cells      = (int*)(ws + off);            off += (size_t)NAg*8*4;
  float* xc         = (float*)(ws + off);          off += (size_t)NAg*112*4;
  unsigned short* Wpk = (unsigned short*)(ws + off); off += (size_t)48*512*2;
  unsigned short* WdecF = (unsigned short*)(ws + off); off += (size_t)96*512*2;
  unsigned short* WoutF = (unsigned short*)(ws + off); off += (size_t)4*512*2;
  unsigned short* SWF = (unsigned short*)(ws + off); off += (size_t)16*512*2;
  unsigned short* WsocF = (unsigned short*)(ws + off); off += (size_t)72*512*2;

  k_decode_masks<<<16, 256, 0, stream>>>(masks, cells);
  k_prep<<<192, 256, 0, stream>>>(eWih, eWhh, Wpk, dWhh, WdecF, outW, WoutF, sW, SWF, socW, WsocF);
  k_embed_x<<<16384, 256, 0, stream>>>(x, dynW, dynb, E);
  k_embed_agg_mfma<<<4096, 256, 0, stream>>>(ngbrs, graphs, dynW, dynb, SWF, sb, E);
  k_gru_enc_mfma<<<2304, 256, 0, stream>>>((const unsigned short*)E, Wpk, ebih, ebhh, h_all);
  k_xs<<<512, 256, 0, stream>>>(h_all, hidW, hidb, xc);
  k_soc_mfma<<<512, 256, 0, stream>>>(h_all, cells, WsocF, socb, c31W, c31b, xc);
  k_dec_mfma<<<256, 512, 0, stream>>>(xc, WdecF, WoutF, dWih, dbih, dbhh, outb, out);
}

// Round 8
// 298.676 us; speedup vs baseline: 4.5754x; 1.0342x over previous
//
#include <hip/hip_runtime.h>
#include <hip/hip_bf16.h>

#define T_OBS 16
#define NAg   4096
#define Vn    8
#define NV    32768           // NAg*Vn
#define SEQ   36864           // NAg + NV
#define PRED  25
#define XSTR  116             // padded LDS stride for 112-wide xc tile

typedef __bf16 bf16x8 __attribute__((ext_vector_type(8)));
typedef float  f32x4  __attribute__((ext_vector_type(4)));

__device__ __forceinline__ float leakyf(float v){ return v >= 0.f ? v : 0.1f*v; }
__device__ __forceinline__ float sigf(float x){ return 1.f/(1.f+__expf(-x)); }
__device__ __forceinline__ float tanhf_(float x){
  x = fminf(fmaxf(x, -10.f), 10.f);
  float e = __expf(2.f*x);
  return (e-1.f)/(e+1.f);
}
// branch-free tanh: 2/(1+e^{-2x}) - 1; exp saturation gives exact +-1 tails
__device__ __forceinline__ float tanh2f(float x){
  return fmaf(2.f, 1.f/(1.f+__expf(-2.f*x)), -1.f);
}
__device__ __forceinline__ float bf2f(unsigned short u){
  union{unsigned int i; float f;} v; v.i = ((unsigned int)u)<<16; return v.f;
}
__device__ __forceinline__ unsigned short f2bf(float f){
  __hip_bfloat16 b = __float2bfloat16(f);
  return *reinterpret_cast<unsigned short*>(&b);
}
__device__ __forceinline__ float dot4f(float4 a, float4 b, float acc){
  return fmaf(a.x,b.x, fmaf(a.y,b.y, fmaf(a.z,b.z, fmaf(a.w,b.w, acc))));
}
__device__ __forceinline__ bf16x8 as_bf16x8(uint4 u){
  union { uint4 a; bf16x8 b; } v; v.a = u; return v.b;
}
__device__ __forceinline__ uint4 pack8bf(float4 a, float4 b){
  union{ unsigned short s[8]; uint4 u; } o;
  o.s[0]=f2bf(a.x); o.s[1]=f2bf(a.y); o.s[2]=f2bf(a.z); o.s[3]=f2bf(a.w);
  o.s[4]=f2bf(b.x); o.s[5]=f2bf(b.y); o.s[6]=f2bf(b.z); o.s[7]=f2bf(b.w);
  return o.u;
}

// ---------------------------------------------------------------------------
// Decode bool masks -> per-agent 8 selected cell indices.
// ---------------------------------------------------------------------------
__global__ void k_decode_masks(const void* __restrict__ masks, int* __restrict__ cells){
  int n = blockIdx.x*blockDim.x + threadIdx.x;
  if (n >= NAg) return;
  const unsigned char* m8  = (const unsigned char*)masks;
  const int*           m32 = (const int*)masks;
  int tmp[8]; for (int v=0; v<8; ++v) tmp[v] = 0;
  int cnt = 0;
  for (int cc=0; cc<39; ++cc){                 // u8 interpretation (bool bytes)
    size_t base = ((size_t)n*39 + cc)*64;
    if (m8[base] && m8[base+1] && m8[base+33]){ if (cnt<8) tmp[cnt]=cc; cnt++; }
  }
  if (cnt != 8){                               // fallback: 4-byte elements
    cnt = 0;
    for (int cc=0; cc<39; ++cc){
      size_t base = ((size_t)n*39 + cc)*64;
      if (m32[base] != 0){ if (cnt<8) tmp[cnt]=cc; cnt++; }
    }
  }
  for (int v=0; v<8; ++v) cells[n*8+v] = tmp[v];
}

// ---------------------------------------------------------------------------
// One-shot weight re-layouts (unchanged from R5).
// ---------------------------------------------------------------------------
__global__ void k_prep(const float* __restrict__ eWih, const float* __restrict__ eWhh,
                       unsigned short* __restrict__ Wpk,
                       const float* __restrict__ dWhh, unsigned short* __restrict__ WdecF,
                       const float* __restrict__ outW, unsigned short* __restrict__ WoutF,
                       const float* __restrict__ sW, unsigned short* __restrict__ SWF,
                       const float* __restrict__ socW, unsigned short* __restrict__ WsocF){
  int idx = blockIdx.x*blockDim.x + threadIdx.x;   // 49152 threads
  if (idx < 24576){                                // encoder: 48 frags * 512
    int f   = idx >> 9;
    int rem = idx & 511;
    int l   = rem >> 3, j = rem & 7;
    int lr  = l & 15, lg = l >> 4;
    float val;
    if (f < 32){
      int nt = f >> 2, kk = f & 3;
      int n  = nt*16 + lr;                         // rows 0..127 = r,z gates
      int k  = kk*32 + lg*8 + j;
      val = (k < 64) ? eWih[(size_t)n*64 + k] : eWhh[(size_t)n*64 + (k-64)];
    } else if (f < 40){
      int q = f - 32;
      int n = (8 + (q>>1))*16 + lr;                // rows 128..191 = n gate
      int k = (q&1)*32 + lg*8 + j;
      val = eWih[(size_t)n*64 + k];
    } else {
      int q = f - 40;
      int n = (8 + (q>>1))*16 + lr;
      int k = (q&1)*32 + lg*8 + j;
      val = eWhh[(size_t)n*64 + k];
    }
    Wpk[f*512 + l*8 + j] = f2bf(val);
  }
  if (idx < 49152){                                // decoder: 96 frags * 512
    int f   = idx >> 9;                            // g*12 + nt*4 + kk
    int rem = idx & 511;
    int l   = rem >> 3, j = rem & 7;
    int lr  = l & 15, lg = l >> 4;
    int g = f/12, loc = f%12, nt = loc>>2, kk = loc&3;
    int n = g*48 + nt*16 + lr;
    int k = kk*32 + lg*8 + j;
    WdecF[idx] = f2bf(dWhh[(size_t)n*128 + k]);
  }
  if (idx < 2048){                                 // out head: 4 frags * 512
    int kk  = idx >> 9;
    int rem = idx & 511;
    int l   = rem >> 3, j = rem & 7;
    int lr  = l & 15, lg = l >> 4;
    int k = kk*32 + lg*8 + j;
    float v = (lr < 5) ? outW[(size_t)lr*128 + k] : 0.f;
    WoutF[idx] = f2bf(v);
  }
  if (idx < 8192){                                 // s_W: 16 frags * 512
    int f   = idx >> 9;                            // nt*2 + kk
    int rem = idx & 511;
    int l   = rem >> 3, j = rem & 7;
    int lr  = l & 15, lg = l >> 4;
    int nt = f >> 1, kk = f & 1;
    int nn = nt*16 + lr;
    int k  = kk*32 + lg*8 + j;
    SWF[idx] = f2bf(sW[(size_t)nn*64 + k]);
  }
  if (idx < 36864){                                // soc conv1: 72 frags * 512
    int f   = idx >> 9;                            // (w*9+kk)*2+ks
    int rem = idx & 511;
    int l   = rem >> 3, j = rem & 7;
    int lr  = l & 15, lg = l >> 4;
    int w = f/18, loc = f%18, kk = loc>>1, ks = loc&1;
    int o = w*16 + lr;
    int c = ks*32 + lg*8 + j;
    WsocF[idx] = f2bf(socW[(size_t)o*576 + c*9 + kk]);
  }
}

// ---------------------------------------------------------------------------
// x_e = leaky(x @ dyn_W.T + dyn_b) -> E[t][0..4095][c] (bf16)
// ---------------------------------------------------------------------------
__global__ void k_embed_x(const float* __restrict__ x, const float* __restrict__ dynW,
                          const float* __restrict__ dynb, __hip_bfloat16* __restrict__ E){
  int idx = blockIdx.x*blockDim.x + threadIdx.x;   // 16*4096*64 exactly
  int c = idx & 63;
  int s = (idx >> 6) & 4095;
  int t = idx >> 18;
  float x0 = x[((size_t)t*NAg + s)*2 + 0];
  float x1 = x[((size_t)t*NAg + s)*2 + 1];
  float v = leakyf(fmaf(x0, dynW[c*2+0], fmaf(x1, dynW[c*2+1], dynb[c])));
  E[((size_t)t*SEQ + s)*64 + c] = __float2bfloat16(v);
}

// ---------------------------------------------------------------------------
// Per agent n (fused, MFMA): ng_e -> H = ng_e@sW.T+sb -> graph einsum -> E.
// (validated R4)
// ---------------------------------------------------------------------------
__global__ __launch_bounds__(256,2) void k_embed_agg_mfma(
    const float* __restrict__ ngbrs, const float* __restrict__ graphs,
    const float* __restrict__ dynW, const float* __restrict__ dynb,
    const unsigned short* __restrict__ SWF, const float* __restrict__ sb,
    __hip_bfloat16* __restrict__ E)
{
  __shared__ __align__(16) unsigned char ngeb[128*128];   // bf16 [row][64] swizzled
  __shared__ __align__(16) unsigned short hm[128*136];    // bf16 [tv][128 pad 136]
  __shared__ float2 pL[128];
  __shared__ float  gL[128];
  __shared__ float2 dwL[64];
  __shared__ float  dbL[64];
  const int tid = threadIdx.x;
  const int n = blockIdx.x;

  if (tid < 128) gL[tid] = graphs[(size_t)n*128 + tid];
  if (tid < 64)  dwL[tid] = *(const float2*)(dynW + tid*2);
  if (tid < 64)  dbL[tid] = dynb[tid];
  if (tid < 128){
    int t = tid >> 3, v = tid & 7;
    pL[tid] = *(const float2*)(ngbrs + ((size_t)t*NV + (size_t)n*8 + v)*2);
  }
  __syncthreads();

  #pragma unroll
  for (int p=0; p<4; ++p){
    int chunk = tid + p*256;          // 1024: row*8 + c8
    int row = chunk >> 3, c8 = chunk & 7;
    float2 xy = pL[row];
    union { unsigned short s[8]; uint4 u; } ou;
    #pragma unroll
    for (int jj=0; jj<8; ++jj){
      int c = c8*8 + jj;
      ou.s[jj] = f2bf(leakyf(fmaf(xy.x, dwL[c].x, fmaf(xy.y, dwL[c].y, dbL[c]))));
    }
    *(uint4*)(ngeb + ((row*128 + c8*16) ^ ((row&7)<<4))) = ou.u;
  }
  __syncthreads();

  const int w4 = tid >> 6, l = tid & 63, lr = l & 15, lg = l >> 4;
  {
    uint4 bsw[16];
    #pragma unroll
    for (int f=0; f<16; ++f) bsw[f] = *(const uint4*)(SWF + f*512 + l*8);
    float sbv[8];
    #pragma unroll
    for (int nt=0; nt<8; ++nt) sbv[nt] = sb[nt*16 + lr];

    f32x4 acc[2][8];
    #pragma unroll
    for (int m=0; m<2; ++m)
      #pragma unroll
      for (int nt=0; nt<8; ++nt)
        acc[m][nt] = (f32x4){sbv[nt], sbv[nt], sbv[nt], sbv[nt]};

    #pragma unroll
    for (int m=0; m<2; ++m){
      int row = (w4*2+m)*16 + lr;
      int rb = row*128, sz = (row&7)<<4;
      uint4 a0 = *(const uint4*)(ngeb + ((rb      + lg*16) ^ sz));
      uint4 a1 = *(const uint4*)(ngeb + ((rb + 64 + lg*16) ^ sz));
      bf16x8 A0 = as_bf16x8(a0), A1 = as_bf16x8(a1);
      #pragma unroll
      for (int nt=0; nt<8; ++nt){
        acc[m][nt] = __builtin_amdgcn_mfma_f32_16x16x32_bf16(A0, as_bf16x8(bsw[nt*2+0]), acc[m][nt], 0,0,0);
        acc[m][nt] = __builtin_amdgcn_mfma_f32_16x16x32_bf16(A1, as_bf16x8(bsw[nt*2+1]), acc[m][nt], 0,0,0);
      }
    }
    #pragma unroll
    for (int m=0; m<2; ++m)
      #pragma unroll
      for (int nt=0; nt<8; ++nt)
        #pragma unroll
        for (int jj=0; jj<4; ++jj)
          hm[((w4*2+m)*16 + lg*4 + jj)*136 + nt*16 + lr] = f2bf(acc[m][nt][jj]);
  }
  __syncthreads();

  #pragma unroll
  for (int p=0; p<4; ++p){
    int task = tid + p*256;           // 1024: t*64 + wv*8 + c8
    int c8 = task & 7, wv = (task>>3)&7, t = task >> 6;
    float a8[8];
    #pragma unroll
    for (int jj=0; jj<8; ++jj) a8[jj] = 0.f;
    #pragma unroll
    for (int k=0; k<2; ++k){
      #pragma unroll
      for (int v=0; v<8; ++v){
        float g = gL[k*64 + v*8 + wv];
        uint4 hv4 = *(const uint4*)(hm + (t*8+v)*136 + k*64 + c8*8);
        const unsigned short* hh = (const unsigned short*)&hv4;
        #pragma unroll
        for (int jj=0; jj<8; ++jj) a8[jj] = fmaf(g, bf2f(hh[jj]), a8[jj]);
      }
    }
    union { unsigned short s[8]; uint4 u; } ou;
    #pragma unroll
    for (int jj=0; jj<8; ++jj) ou.s[jj] = f2bf(a8[jj]);
    *(uint4*)((unsigned short*)E + ((size_t)t*SEQ + NAg + (size_t)n*8 + wv)*64 + c8*8) = ou.u;
  }
}

// ---------------------------------------------------------------------------
// Encoder GRU via MFMA, full-gate-per-wave partition (no gate LDS exchange).
// Block = 16 seqs, 4 waves. Wave w owns h-columns [w*16, w*16+16) for ALL
// gates: B-frags rz tiles {w, 4+w} + nI/nH tile w (12 frags, VGPRs).
// Epilogue entirely in registers; h round-trips via double-buffered 2KB
// swizzled bf16 Hb (1 barrier/step).
// ---------------------------------------------------------------------------
__global__ __launch_bounds__(256,4) void k_gru_enc_mfma(
    const unsigned short* __restrict__ E,
    const unsigned short* __restrict__ Wpk,
    const float* __restrict__ bih, const float* __restrict__ bhh,
    float* __restrict__ h_all)
{
  __shared__ __align__(16) unsigned char Hb[2][2048];
  const int tid = threadIdx.x;
  const int w  = tid >> 6;         // wave 0..3
  const int l  = tid & 63;
  const int lr = l & 15;           // A row (seq) / D col
  const int lg = l >> 4;
  const size_t s0 = (size_t)blockIdx.x * 16;
  const int i  = w*16 + lr;        // owned h column

  // B fragments: r tile w (frags 4w..4w+3), z tile 4+w (frags 16+4w..+3),
  // nI (32+2w, 33+2w), nH (40+2w, 41+2w)
  uint4 bf[12];
  #pragma unroll
  for (int q=0; q<4; ++q) bf[q]   = *(const uint4*)(Wpk + (4*w + q)*512 + l*8);
  #pragma unroll
  for (int q=0; q<4; ++q) bf[4+q] = *(const uint4*)(Wpk + (16 + 4*w + q)*512 + l*8);
  #pragma unroll
  for (int q=0; q<2; ++q) bf[8+q] = *(const uint4*)(Wpk + (32 + 2*w + q)*512 + l*8);
  #pragma unroll
  for (int q=0; q<2; ++q) bf[10+q]= *(const uint4*)(Wpk + (40 + 2*w + q)*512 + l*8);

  const float b_r = bih[i]     + bhh[i];
  const float b_z = bih[64+i]  + bhh[64+i];
  const float bni = bih[128+i];
  const float bnh = bhh[128+i];

  // zero both Hb buffers: 256 threads x 16 B = 4096 B
  *(uint4*)(&Hb[0][0] + tid*16) = make_uint4(0,0,0,0);
  __syncthreads();

  float hreg[4] = {0.f,0.f,0.f,0.f};

  uint4 ax0, ax1;
  {
    const unsigned short* p = E + (s0 + lr)*64 + lg*8;
    ax0 = *(const uint4*)(p);
    ax1 = *(const uint4*)(p + 32);
  }

  const int swz = (lr & 7) << 4;
  int cur = 0;

  #pragma unroll 1
  for (int t=0; t<T_OBS; ++t){
    int tn = (t < 15) ? t+1 : 15;
    const unsigned short* pn = E + ((size_t)tn*SEQ + s0 + lr)*64 + lg*8;
    uint4 nx0 = *(const uint4*)(pn);
    uint4 nx1 = *(const uint4*)(pn + 32);

    const unsigned char* hc = Hb[cur];
    uint4 ah0 = *(const uint4*)(hc + ((lr*128      + lg*16) ^ swz));
    uint4 ah1 = *(const uint4*)(hc + ((lr*128 + 64 + lg*16) ^ swz));

    bf16x8 Ax0 = as_bf16x8(ax0), Ax1 = as_bf16x8(ax1);
    bf16x8 Ah0 = as_bf16x8(ah0), Ah1 = as_bf16x8(ah1);

    f32x4 aR  = (f32x4){0.f,0.f,0.f,0.f};
    f32x4 aZ  = (f32x4){0.f,0.f,0.f,0.f};
    f32x4 aNI = (f32x4){0.f,0.f,0.f,0.f};
    f32x4 aNH = (f32x4){0.f,0.f,0.f,0.f};

    aR  = __builtin_amdgcn_mfma_f32_16x16x32_bf16(Ax0, as_bf16x8(bf[0]),  aR,  0,0,0);
    aR  = __builtin_amdgcn_mfma_f32_16x16x32_bf16(Ax1, as_bf16x8(bf[1]),  aR,  0,0,0);
    aR  = __builtin_amdgcn_mfma_f32_16x16x32_bf16(Ah0, as_bf16x8(bf[2]),  aR,  0,0,0);
    aR  = __builtin_amdgcn_mfma_f32_16x16x32_bf16(Ah1, as_bf16x8(bf[3]),  aR,  0,0,0);
    aZ  = __builtin_amdgcn_mfma_f32_16x16x32_bf16(Ax0, as_bf16x8(bf[4]),  aZ,  0,0,0);
    aZ  = __builtin_amdgcn_mfma_f32_16x16x32_bf16(Ax1, as_bf16x8(bf[5]),  aZ,  0,0,0);
    aZ  = __builtin_amdgcn_mfma_f32_16x16x32_bf16(Ah0, as_bf16x8(bf[6]),  aZ,  0,0,0);
    aZ  = __builtin_amdgcn_mfma_f32_16x16x32_bf16(Ah1, as_bf16x8(bf[7]),  aZ,  0,0,0);
    aNI = __builtin_amdgcn_mfma_f32_16x16x32_bf16(Ax0, as_bf16x8(bf[8]),  aNI, 0,0,0);
    aNI = __builtin_amdgcn_mfma_f32_16x16x32_bf16(Ax1, as_bf16x8(bf[9]),  aNI, 0,0,0);
    aNH = __builtin_amdgcn_mfma_f32_16x16x32_bf16(Ah0, as_bf16x8(bf[10]), aNH, 0,0,0);
    aNH = __builtin_amdgcn_mfma_f32_16x16x32_bf16(Ah1, as_bf16x8(bf[11]), aNH, 0,0,0);

    unsigned char* hn = Hb[cur^1];
    #pragma unroll
    for (int u=0; u<4; ++u){
      float r  = sigf(aR[u] + b_r);
      float z  = sigf(aZ[u] + b_z);
      float nn = tanh2f(fmaf(r, aNH[u] + bnh, aNI[u] + bni));
      float h  = fmaf(z, hreg[u] - nn, nn);
      hreg[u]  = h;
      int s = lg*4 + u;
      *(unsigned short*)(hn + ((s*128 + i*2) ^ ((s & 7) << 4))) = f2bf(h);
    }
    __syncthreads();
    cur ^= 1;
    ax0 = nx0; ax1 = nx1;
  }

  #pragma unroll
  for (int u=0; u<4; ++u)
    h_all[(s0 + lg*4 + u)*64 + i] = hreg[u];
}

// ---------------------------------------------------------------------------
// x_s = leaky(h_x @ hid_W.T + hid_b) -> xc[:, 0:32]
// ---------------------------------------------------------------------------
__global__ void k_xs(const float* __restrict__ h_all, const float* __restrict__ hidW,
                     const float* __restrict__ hidb, float* __restrict__ xc){
  int idx = blockIdx.x*blockDim.x + threadIdx.x;   // 4096*32
  int j = idx & 31, n = idx >> 5;
  const float* h = h_all + (size_t)n*64;
  const float* w = hidW + (size_t)j*64;
  float acc = hidb[j];
  for (int k4=0; k4<16; ++k4)
    acc = dot4f(*(const float4*)(h + k4*4), *(const float4*)(w + k4*4), acc);
  xc[(size_t)n*112 + j] = leakyf(acc);
}

// ---------------------------------------------------------------------------
// Social branch via MFMA (validated R5).
// ---------------------------------------------------------------------------
__global__ __launch_bounds__(256,3) void k_soc_mfma(
    const float* __restrict__ h_all, const int* __restrict__ cells,
    const unsigned short* __restrict__ WsocF, const float* __restrict__ socb,
    const float* __restrict__ c31W, const float* __restrict__ c31b,
    float* __restrict__ xc)
{
  __shared__ unsigned short Qb[9*8*64];   // 9 KB  [kk][v][o] bf16
  __shared__ float o1p[4*64*17];          // 17 KB scatter partials (y shifted +2)
  __shared__ float o1[64*12];             // 3 KB  out1 (y 0..10)
  __shared__ float c2p[4*144];            // 2.25 KB conv2 partials
  __shared__ float W2L[64*48];            // 12 KB [o][ky][p]
  __shared__ float socbL[64];
  __shared__ float b2L[16];
  __shared__ int   cellsL[64];            // [a][v]

  const int tid = threadIdx.x;
  const int w  = tid >> 6;
  const int l  = tid & 63;
  const int lr = l & 15, lg = l >> 4;
  const int n0 = blockIdx.x * 8;

  for (int idx=tid; idx<3072; idx+=256){
    int p = idx/192, rem = idx%192, o = rem/3, ky = rem%3;
    W2L[(o*3+ky)*16 + p] = c31W[idx];
  }
  if (tid < 64) socbL[tid] = socb[tid];
  if (tid < 16) b2L[tid]  = c31b[tid];
  if (tid < 64) cellsL[tid] = cells[n0*8 + tid];

  uint4 bs[18];
  #pragma unroll
  for (int f=0; f<18; ++f)
    bs[f] = *(const uint4*)(WsocF + (size_t)(w*18 + f)*512 + l*8);
  __syncthreads();

  #pragma unroll 1
  for (int a=0; a<8; ++a){
    uint4 ax0u = make_uint4(0,0,0,0), ax1u = make_uint4(0,0,0,0);
    if (lr < 8){
      const float* hp = h_all + ((size_t)NAg + (size_t)(n0+a)*8 + lr)*64 + lg*8;
      float4 f0 = *(const float4*)(hp);
      float4 f1 = *(const float4*)(hp + 4);
      float4 f2 = *(const float4*)(hp + 32);
      float4 f3 = *(const float4*)(hp + 36);
      ax0u = pack8bf(f0, f1);
      ax1u = pack8bf(f2, f3);
    }
    bf16x8 A0 = as_bf16x8(ax0u), A1 = as_bf16x8(ax1u);

    f32x4 acc[9];
    #pragma unroll
    for (int kk=0; kk<9; ++kk) acc[kk] = (f32x4){0.f,0.f,0.f,0.f};
    #pragma unroll
    for (int kk=0; kk<9; ++kk){
      acc[kk] = __builtin_amdgcn_mfma_f32_16x16x32_bf16(A0, as_bf16x8(bs[kk*2+0]), acc[kk], 0,0,0);
      acc[kk] = __builtin_amdgcn_mfma_f32_16x16x32_bf16(A1, as_bf16x8(bs[kk*2+1]), acc[kk], 0,0,0);
    }

    __syncthreads();

    if (lg < 2){
      #pragma unroll
      for (int kk=0; kk<9; ++kk)
        #pragma unroll
        for (int j=0; j<4; ++j)
          Qb[(kk*8 + lg*4 + j)*64 + w*16 + lr] = f2bf(acc[kk][j]);
    }
    for (int idx=tid; idx<2816; idx+=256){
      int q = idx/704, r = idx%704;
      int o = r/11, y = r%11;
      o1p[(q*64 + o)*17 + y + 2] = 0.f;
    }
    __syncthreads();

    {
      int o = tid & 63, q = tid >> 6;
      #pragma unroll
      for (int p6=0; p6<6; ++p6){
        int pr = q*6 + p6;
        int v = pr/3, ky = pr%3;
        int cc = cellsL[a*8 + v];
        int gw = cc/13, gh = cc - gw*13;
        float val = bf2f(Qb[((ky*3+gw)*8 + v)*64 + o]);
        o1p[(q*64 + o)*17 + (gh - ky + 2)] += val;
      }
    }
    __syncthreads();

    for (int idx=tid; idx<704; idx+=256){
      int o = idx/11, y = idx%11;
      float s = socbL[o];
      #pragma unroll
      for (int q=0; q<4; ++q) s += o1p[(q*64 + o)*17 + y + 2];
      o1[o*12 + y] = leakyf(s);
    }
    __syncthreads();

    {
      int q = tid >> 6, l2 = tid & 63;
      for (int e=l2; e<144; e+=64){
        int p = e & 15, y2 = e >> 4;
        float accv = 0.f;
        #pragma unroll
        for (int oi=0; oi<16; ++oi){
          int oo = q*16 + oi;
          const float* o1r = o1 + oo*12 + y2;
          const float* w2r = W2L + oo*48 + p;
          accv = fmaf(o1r[0], w2r[0], fmaf(o1r[1], w2r[16], fmaf(o1r[2], w2r[32], accv)));
        }
        c2p[q*144 + e] = accv;
      }
    }
    __syncthreads();

    if (tid < 80){
      int p = tid/5, ww = tid%5;
      float v0, v1;
      {
        int y2 = (ww == 0) ? 0 : 2*ww - 1;
        float s = b2L[p];
        #pragma unroll
        for (int q=0; q<4; ++q) s += c2p[q*144 + y2*16 + p];
        v0 = leakyf(s);
      }
      if (ww == 0) v1 = v0;
      else {
        int y2 = 2*ww;
        float s = b2L[p];
        #pragma unroll
        for (int q=0; q<4; ++q) s += c2p[q*144 + y2*16 + p];
        v1 = leakyf(s);
      }
      xc[(size_t)(n0+a)*112 + 32 + p*5 + ww] = fmaxf(v0, v1);
    }
  }
}

// ---------------------------------------------------------------------------
// Decoder GRU via MFMA + fused output head (validated R3).
// ---------------------------------------------------------------------------
__global__ __launch_bounds__(512,1) void k_dec_mfma(
    const float* __restrict__ xc, const unsigned short* __restrict__ WdecF,
    const unsigned short* __restrict__ WoutF,
    const float* __restrict__ dWih, const float* __restrict__ dbih,
    const float* __restrict__ dbhh, const float* __restrict__ outb,
    float* __restrict__ out)
{
  __shared__ float Gm[384*16];                       // [n][s] f32
  __shared__ __align__(16) unsigned char Hb[16*256]; // h bf16, A-layout, swizzled
  __shared__ float xct[16*XSTR];
  const int tid = threadIdx.x;
  const int g   = tid >> 6;        // wave 0..7
  const int l   = tid & 63;
  const int lr  = l & 15, lg = l >> 4;
  const int n0  = blockIdx.x * 16;
  const int i   = g*16 + lr;       // owned h column (0..127)

  for (int idx=tid; idx<16*112; idx+=512){
    int s = idx/112, k = idx%112;
    xct[s*XSTR + k] = xc[(size_t)(n0+s)*112 + k];
  }
  *(uint2*)(Hb + tid*8) = make_uint2(0,0);
  __syncthreads();

  {
    int s = tid & 15, jq = tid >> 4;                 // jq 0..31
    const float* xr = xct + s*XSTR;
    for (int jj=0; jj<12; ++jj){
      int j = jq*12 + jj;
      float acc = dbih[j];
      const float* wp = dWih + (size_t)j*112;
      for (int k4=0; k4<28; ++k4)
        acc = dot4f(*(const float4*)(wp + k4*4), *(const float4*)(xr + k4*4), acc);
      Gm[j*16 + s] = acc;
    }
  }
  __syncthreads();

  float gi_r[4], gi_z[4], gi_n[4];
  #pragma unroll
  for (int u=0; u<4; ++u){
    int s = lg*4 + u;
    gi_r[u] = Gm[(      i)*16 + s];
    gi_z[u] = Gm[(128 + i)*16 + s];
    gi_n[u] = Gm[(256 + i)*16 + s];
  }
  const float bh_r = dbhh[i], bh_z = dbhh[128+i], bh_n = dbhh[256+i];
  const float obv  = (lr < 5) ? outb[lr] : 0.f;
  __syncthreads();                                   // Gm reused below

  uint4 bgf[12];
  #pragma unroll
  for (int f=0; f<12; ++f)
    bgf[f] = *(const uint4*)(WdecF + (size_t)(g*12 + f)*512 + l*8);
  uint4 bof[4];
  #pragma unroll
  for (int kk=0; kk<4; ++kk)
    bof[kk] = *(const uint4*)(WoutF + (size_t)kk*512 + l*8);

  float hreg[4] = {0.f, 0.f, 0.f, 0.f};
  const int swz = (lr & 7) << 4;

  #pragma unroll 1
  for (int t=0; t<PRED; ++t){
    uint4 ah[4];
    #pragma unroll
    for (int kk=0; kk<4; ++kk)
      ah[kk] = *(const uint4*)(Hb + ((lr*256 + kk*64 + lg*16) ^ swz));

    if (g == 0 && t > 0){
      f32x4 accO = (f32x4){0.f,0.f,0.f,0.f};
      #pragma unroll
      for (int kk=0; kk<4; ++kk)
        accO = __builtin_amdgcn_mfma_f32_16x16x32_bf16(as_bf16x8(ah[kk]), as_bf16x8(bof[kk]), accO, 0,0,0);
      if (lr < 5){
        #pragma unroll
        for (int u=0; u<4; ++u){
          float a = accO[u] + obv;
          float val = (lr < 2) ? a : (lr == 4 ? tanhf_(a) : __expf(a));
          out[((size_t)(t-1)*NAg + n0 + lg*4 + u)*5 + lr] = val;
        }
      }
    }

    f32x4 acc[3];
    #pragma unroll
    for (int nt=0; nt<3; ++nt) acc[nt] = (f32x4){0.f,0.f,0.f,0.f};
    #pragma unroll
    for (int nt=0; nt<3; ++nt)
      #pragma unroll
      for (int kk=0; kk<4; ++kk)
        acc[nt] = __builtin_amdgcn_mfma_f32_16x16x32_bf16(as_bf16x8(ah[kk]), as_bf16x8(bgf[nt*4+kk]), acc[nt], 0,0,0);

    #pragma unroll
    for (int nt=0; nt<3; ++nt)
      *(f32x4*)(Gm + (g*48 + nt*16 + lr)*16 + lg*4) = acc[nt];
    __syncthreads();

    float4 rp = *(const float4*)(Gm + (      i)*16 + lg*4);
    float4 zp = *(const float4*)(Gm + (128 + i)*16 + lg*4);
    float4 hp = *(const float4*)(Gm + (256 + i)*16 + lg*4);
    const float* rpa = &rp.x; const float* zpa = &zp.x; const float* hpa = &hp.x;
    #pragma unroll
    for (int u=0; u<4; ++u){
      float r  = sigf(gi_r[u] + rpa[u] + bh_r);
      float z  = sigf(gi_z[u] + zpa[u] + bh_z);
      float nn = tanhf_(fmaf(r, hpa[u] + bh_n, gi_n[u]));
      float h  = fmaf(z, hreg[u] - nn, nn);
      hreg[u] = h;
      int s = lg*4 + u;
      *(unsigned short*)(Hb + ((s*256 + i*2) ^ ((s & 7) << 4))) = f2bf(h);
    }
    __syncthreads();
  }

  if (g == 0){
    uint4 ah[4];
    #pragma unroll
    for (int kk=0; kk<4; ++kk)
      ah[kk] = *(const uint4*)(Hb + ((lr*256 + kk*64 + lg*16) ^ swz));
    f32x4 accO = (f32x4){0.f,0.f,0.f,0.f};
    #pragma unroll
    for (int kk=0; kk<4; ++kk)
      accO = __builtin_amdgcn_mfma_f32_16x16x32_bf16(as_bf16x8(ah[kk]), as_bf16x8(bof[kk]), accO, 0,0,0);
    if (lr < 5){
      #pragma unroll
      for (int u=0; u<4; ++u){
        float a = accO[u] + obv;
        float val = (lr < 2) ? a : (lr == 4 ? tanhf_(a) : __expf(a));
        out[((size_t)(PRED-1)*NAg + n0 + lg*4 + u)*5 + lr] = val;
      }
    }
  }
}

// ---------------------------------------------------------------------------
extern "C" void kernel_launch(void* const* d_in, const int* in_sizes, int n_in,
                              void* d_out, int out_size, void* d_ws, size_t ws_size,
                              hipStream_t stream)
{
  const float* x      = (const float*)d_in[0];
  const float* ngbrs  = (const float*)d_in[1];
  const float* graphs = (const float*)d_in[2];
  const void*  masks  = d_in[3];
  // d_in[4] = ngbrs_idx (unused by the reference computation)
  const float* dynW   = (const float*)d_in[5];
  const float* dynb   = (const float*)d_in[6];
  const float* eWih   = (const float*)d_in[7];
  const float* eWhh   = (const float*)d_in[8];
  const float* ebih   = (const float*)d_in[9];
  const float* ebhh   = (const float*)d_in[10];
  const float* sW     = (const float*)d_in[11];
  const float* sb     = (const float*)d_in[12];
  const float* hidW   = (const float*)d_in[13];
  const float* hidb   = (const float*)d_in[14];
  const float* socW   = (const float*)d_in[15];
  const float* socb   = (const float*)d_in[16];
  const float* c31W   = (const float*)d_in[17];
  const float* c31b   = (const float*)d_in[18];
  const float* dWih   = (const float*)d_in[19];
  const float* dWhh   = (const float*)d_in[20];
  const float* dbih   = (const float*)d_in[21];
  const float* dbhh   = (const float*)d_in[22];
  const float* outW   = (const float*)d_in[23];
  const float* outb   = (const float*)d_in[24];
  float* out = (float*)d_out;

  char* ws = (char*)d_ws;
  size_t off = 0;
  __hip_bfloat16* E = (__hip_bfloat16*)(ws + off); off += (size_t)T_OBS*SEQ*64*2;   // 75.5 MB
  float* h_all      = (float*)(ws + off);          off += (size_t)SEQ*64*4;          // 9.4 MB
  int*   cells      = (int*)(ws + off);            off += (size_t)NAg*8*4;
  float* xc         = (float*)(ws + off);          off += (size_t)NAg*112*4;
  unsigned short* Wpk = (unsigned short*)(ws + off); off += (size_t)48*512*2;
  unsigned short* WdecF = (unsigned short*)(ws + off); off += (size_t)96*512*2;
  unsigned short* WoutF = (unsigned short*)(ws + off); off += (size_t)4*512*2;
  unsigned short* SWF = (unsigned short*)(ws + off); off += (size_t)16*512*2;
  unsigned short* WsocF = (unsigned short*)(ws + off); off += (size_t)72*512*2;

  k_decode_masks<<<16, 256, 0, stream>>>(masks, cells);
  k_prep<<<192, 256, 0, stream>>>(eWih, eWhh, Wpk, dWhh, WdecF, outW, WoutF, sW, SWF, socW, WsocF);
  k_embed_x<<<16384, 256, 0, stream>>>(x, dynW, dynb, E);
  k_embed_agg_mfma<<<4096, 256, 0, stream>>>(ngbrs, graphs, dynW, dynb, SWF, sb, E);
  k_gru_enc_mfma<<<2304, 256, 0, stream>>>((const unsigned short*)E, Wpk, ebih, ebhh, h_all);
  k_xs<<<512, 256, 0, stream>>>(h_all, hidW, hidb, xc);
  k_soc_mfma<<<512, 256, 0, stream>>>(h_all, cells, WsocF, socb, c31W, c31b, xc);
  k_dec_mfma<<<256, 512, 0, stream>>>(xc, WdecF, WoutF, dWih, dbih, dbhh, outb, out);
}

// Round 9
// 289.546 us; speedup vs baseline: 4.7197x; 1.0315x over previous
//
#include <hip/hip_runtime.h>
#include <hip/hip_bf16.h>

#define T_OBS 16
#define NAg   4096
#define Vn    8
#define NV    32768           // NAg*Vn
#define SEQ   36864           // NAg + NV
#define PRED  25
#define XSTR  116             // padded LDS stride for 112-wide xc tile

typedef __bf16 bf16x8 __attribute__((ext_vector_type(8)));
typedef float  f32x4  __attribute__((ext_vector_type(4)));

__device__ __forceinline__ float leakyf(float v){ return v >= 0.f ? v : 0.1f*v; }
__device__ __forceinline__ float sigf(float x){ return 1.f/(1.f+__expf(-x)); }
__device__ __forceinline__ float tanhf_(float x){
  x = fminf(fmaxf(x, -10.f), 10.f);
  float e = __expf(2.f*x);
  return (e-1.f)/(e+1.f);
}
// branch-free tanh: 2/(1+e^{-2x}) - 1; exp saturation gives exact +-1 tails
__device__ __forceinline__ float tanh2f(float x){
  return fmaf(2.f, 1.f/(1.f+__expf(-2.f*x)), -1.f);
}
__device__ __forceinline__ float bf2f(unsigned short u){
  union{unsigned int i; float f;} v; v.i = ((unsigned int)u)<<16; return v.f;
}
__device__ __forceinline__ unsigned short f2bf(float f){
  __hip_bfloat16 b = __float2bfloat16(f);
  return *reinterpret_cast<unsigned short*>(&b);
}
__device__ __forceinline__ float dot4f(float4 a, float4 b, float acc){
  return fmaf(a.x,b.x, fmaf(a.y,b.y, fmaf(a.z,b.z, fmaf(a.w,b.w, acc))));
}
__device__ __forceinline__ bf16x8 as_bf16x8(uint4 u){
  union { uint4 a; bf16x8 b; } v; v.a = u; return v.b;
}
__device__ __forceinline__ uint4 pack8bf(float4 a, float4 b){
  union{ unsigned short s[8]; uint4 u; } o;
  o.s[0]=f2bf(a.x); o.s[1]=f2bf(a.y); o.s[2]=f2bf(a.z); o.s[3]=f2bf(a.w);
  o.s[4]=f2bf(b.x); o.s[5]=f2bf(b.y); o.s[6]=f2bf(b.z); o.s[7]=f2bf(b.w);
  return o.u;
}

// ---------------------------------------------------------------------------
// Decode bool masks -> per-agent 8 selected cell indices.
// ---------------------------------------------------------------------------
__global__ void k_decode_masks(const void* __restrict__ masks, int* __restrict__ cells){
  int n = blockIdx.x*blockDim.x + threadIdx.x;
  if (n >= NAg) return;
  const unsigned char* m8  = (const unsigned char*)masks;
  const int*           m32 = (const int*)masks;
  int tmp[8]; for (int v=0; v<8; ++v) tmp[v] = 0;
  int cnt = 0;
  for (int cc=0; cc<39; ++cc){                 // u8 interpretation (bool bytes)
    size_t base = ((size_t)n*39 + cc)*64;
    if (m8[base] && m8[base+1] && m8[base+33]){ if (cnt<8) tmp[cnt]=cc; cnt++; }
  }
  if (cnt != 8){                               // fallback: 4-byte elements
    cnt = 0;
    for (int cc=0; cc<39; ++cc){
      size_t base = ((size_t)n*39 + cc)*64;
      if (m32[base] != 0){ if (cnt<8) tmp[cnt]=cc; cnt++; }
    }
  }
  for (int v=0; v<8; ++v) cells[n*8+v] = tmp[v];
}

// ---------------------------------------------------------------------------
// One-shot weight re-layouts.
//  WdecF (CHANGED): wave g owns gate rows {r: g*16.., z: 128+g*16..,
//  n: 256+g*16..}; f = g*12 + gate*4 + kk; n = gate*128 + g*16 + lr.
// ---------------------------------------------------------------------------
__global__ void k_prep(const float* __restrict__ eWih, const float* __restrict__ eWhh,
                       unsigned short* __restrict__ Wpk,
                       const float* __restrict__ dWhh, unsigned short* __restrict__ WdecF,
                       const float* __restrict__ outW, unsigned short* __restrict__ WoutF,
                       const float* __restrict__ sW, unsigned short* __restrict__ SWF,
                       const float* __restrict__ socW, unsigned short* __restrict__ WsocF){
  int idx = blockIdx.x*blockDim.x + threadIdx.x;   // 49152 threads
  if (idx < 24576){                                // encoder: 48 frags * 512
    int f   = idx >> 9;
    int rem = idx & 511;
    int l   = rem >> 3, j = rem & 7;
    int lr  = l & 15, lg = l >> 4;
    float val;
    if (f < 32){
      int nt = f >> 2, kk = f & 3;
      int n  = nt*16 + lr;                         // rows 0..127 = r,z gates
      int k  = kk*32 + lg*8 + j;
      val = (k < 64) ? eWih[(size_t)n*64 + k] : eWhh[(size_t)n*64 + (k-64)];
    } else if (f < 40){
      int q = f - 32;
      int n = (8 + (q>>1))*16 + lr;                // rows 128..191 = n gate
      int k = (q&1)*32 + lg*8 + j;
      val = eWih[(size_t)n*64 + k];
    } else {
      int q = f - 40;
      int n = (8 + (q>>1))*16 + lr;
      int k = (q&1)*32 + lg*8 + j;
      val = eWhh[(size_t)n*64 + k];
    }
    Wpk[f*512 + l*8 + j] = f2bf(val);
  }
  if (idx < 49152){                                // decoder: 96 frags * 512
    int f   = idx >> 9;                            // g*12 + gate*4 + kk
    int rem = idx & 511;
    int l   = rem >> 3, j = rem & 7;
    int lr  = l & 15, lg = l >> 4;
    int g = f/12, loc = f%12, gate = loc>>2, kk = loc&3;
    int n = gate*128 + g*16 + lr;
    int k = kk*32 + lg*8 + j;
    WdecF[idx] = f2bf(dWhh[(size_t)n*128 + k]);
  }
  if (idx < 2048){                                 // out head: 4 frags * 512
    int kk  = idx >> 9;
    int rem = idx & 511;
    int l   = rem >> 3, j = rem & 7;
    int lr  = l & 15, lg = l >> 4;
    int k = kk*32 + lg*8 + j;
    float v = (lr < 5) ? outW[(size_t)lr*128 + k] : 0.f;
    WoutF[idx] = f2bf(v);
  }
  if (idx < 8192){                                 // s_W: 16 frags * 512
    int f   = idx >> 9;                            // nt*2 + kk
    int rem = idx & 511;
    int l   = rem >> 3, j = rem & 7;
    int lr  = l & 15, lg = l >> 4;
    int nt = f >> 1, kk = f & 1;
    int nn = nt*16 + lr;
    int k  = kk*32 + lg*8 + j;
    SWF[idx] = f2bf(sW[(size_t)nn*64 + k]);
  }
  if (idx < 36864){                                // soc conv1: 72 frags * 512
    int f   = idx >> 9;                            // (w*9+kk)*2+ks
    int rem = idx & 511;
    int l   = rem >> 3, j = rem & 7;
    int lr  = l & 15, lg = l >> 4;
    int w = f/18, loc = f%18, kk = loc>>1, ks = loc&1;
    int o = w*16 + lr;
    int c = ks*32 + lg*8 + j;
    WsocF[idx] = f2bf(socW[(size_t)o*576 + c*9 + kk]);
  }
}

// ---------------------------------------------------------------------------
// x_e = leaky(x @ dyn_W.T + dyn_b) -> E[t][0..4095][c] (bf16)
// ---------------------------------------------------------------------------
__global__ void k_embed_x(const float* __restrict__ x, const float* __restrict__ dynW,
                          const float* __restrict__ dynb, __hip_bfloat16* __restrict__ E){
  int idx = blockIdx.x*blockDim.x + threadIdx.x;   // 16*4096*64 exactly
  int c = idx & 63;
  int s = (idx >> 6) & 4095;
  int t = idx >> 18;
  float x0 = x[((size_t)t*NAg + s)*2 + 0];
  float x1 = x[((size_t)t*NAg + s)*2 + 1];
  float v = leakyf(fmaf(x0, dynW[c*2+0], fmaf(x1, dynW[c*2+1], dynb[c])));
  E[((size_t)t*SEQ + s)*64 + c] = __float2bfloat16(v);
}

// ---------------------------------------------------------------------------
// Per agent n (fused, MFMA): ng_e -> H = ng_e@sW.T+sb -> graph einsum -> E.
// (validated R4)
// ---------------------------------------------------------------------------
__global__ __launch_bounds__(256,2) void k_embed_agg_mfma(
    const float* __restrict__ ngbrs, const float* __restrict__ graphs,
    const float* __restrict__ dynW, const float* __restrict__ dynb,
    const unsigned short* __restrict__ SWF, const float* __restrict__ sb,
    __hip_bfloat16* __restrict__ E)
{
  __shared__ __align__(16) unsigned char ngeb[128*128];   // bf16 [row][64] swizzled
  __shared__ __align__(16) unsigned short hm[128*136];    // bf16 [tv][128 pad 136]
  __shared__ float2 pL[128];
  __shared__ float  gL[128];
  __shared__ float2 dwL[64];
  __shared__ float  dbL[64];
  const int tid = threadIdx.x;
  const int n = blockIdx.x;

  if (tid < 128) gL[tid] = graphs[(size_t)n*128 + tid];
  if (tid < 64)  dwL[tid] = *(const float2*)(dynW + tid*2);
  if (tid < 64)  dbL[tid] = dynb[tid];
  if (tid < 128){
    int t = tid >> 3, v = tid & 7;
    pL[tid] = *(const float2*)(ngbrs + ((size_t)t*NV + (size_t)n*8 + v)*2);
  }
  __syncthreads();

  #pragma unroll
  for (int p=0; p<4; ++p){
    int chunk = tid + p*256;          // 1024: row*8 + c8
    int row = chunk >> 3, c8 = chunk & 7;
    float2 xy = pL[row];
    union { unsigned short s[8]; uint4 u; } ou;
    #pragma unroll
    for (int jj=0; jj<8; ++jj){
      int c = c8*8 + jj;
      ou.s[jj] = f2bf(leakyf(fmaf(xy.x, dwL[c].x, fmaf(xy.y, dwL[c].y, dbL[c]))));
    }
    *(uint4*)(ngeb + ((row*128 + c8*16) ^ ((row&7)<<4))) = ou.u;
  }
  __syncthreads();

  const int w4 = tid >> 6, l = tid & 63, lr = l & 15, lg = l >> 4;
  {
    uint4 bsw[16];
    #pragma unroll
    for (int f=0; f<16; ++f) bsw[f] = *(const uint4*)(SWF + f*512 + l*8);
    float sbv[8];
    #pragma unroll
    for (int nt=0; nt<8; ++nt) sbv[nt] = sb[nt*16 + lr];

    f32x4 acc[2][8];
    #pragma unroll
    for (int m=0; m<2; ++m)
      #pragma unroll
      for (int nt=0; nt<8; ++nt)
        acc[m][nt] = (f32x4){sbv[nt], sbv[nt], sbv[nt], sbv[nt]};

    #pragma unroll
    for (int m=0; m<2; ++m){
      int row = (w4*2+m)*16 + lr;
      int rb = row*128, sz = (row&7)<<4;
      uint4 a0 = *(const uint4*)(ngeb + ((rb      + lg*16) ^ sz));
      uint4 a1 = *(const uint4*)(ngeb + ((rb + 64 + lg*16) ^ sz));
      bf16x8 A0 = as_bf16x8(a0), A1 = as_bf16x8(a1);
      #pragma unroll
      for (int nt=0; nt<8; ++nt){
        acc[m][nt] = __builtin_amdgcn_mfma_f32_16x16x32_bf16(A0, as_bf16x8(bsw[nt*2+0]), acc[m][nt], 0,0,0);
        acc[m][nt] = __builtin_amdgcn_mfma_f32_16x16x32_bf16(A1, as_bf16x8(bsw[nt*2+1]), acc[m][nt], 0,0,0);
      }
    }
    #pragma unroll
    for (int m=0; m<2; ++m)
      #pragma unroll
      for (int nt=0; nt<8; ++nt)
        #pragma unroll
        for (int jj=0; jj<4; ++jj)
          hm[((w4*2+m)*16 + lg*4 + jj)*136 + nt*16 + lr] = f2bf(acc[m][nt][jj]);
  }
  __syncthreads();

  #pragma unroll
  for (int p=0; p<4; ++p){
    int task = tid + p*256;           // 1024: t*64 + wv*8 + c8
    int c8 = task & 7, wv = (task>>3)&7, t = task >> 6;
    float a8[8];
    #pragma unroll
    for (int jj=0; jj<8; ++jj) a8[jj] = 0.f;
    #pragma unroll
    for (int k=0; k<2; ++k){
      #pragma unroll
      for (int v=0; v<8; ++v){
        float g = gL[k*64 + v*8 + wv];
        uint4 hv4 = *(const uint4*)(hm + (t*8+v)*136 + k*64 + c8*8);
        const unsigned short* hh = (const unsigned short*)&hv4;
        #pragma unroll
        for (int jj=0; jj<8; ++jj) a8[jj] = fmaf(g, bf2f(hh[jj]), a8[jj]);
      }
    }
    union { unsigned short s[8]; uint4 u; } ou;
    #pragma unroll
    for (int jj=0; jj<8; ++jj) ou.s[jj] = f2bf(a8[jj]);
    *(uint4*)((unsigned short*)E + ((size_t)t*SEQ + NAg + (size_t)n*8 + wv)*64 + c8*8) = ou.u;
  }
}

// ---------------------------------------------------------------------------
// Encoder GRU via MFMA, full-gate-per-wave partition (validated R7).
// ---------------------------------------------------------------------------
__global__ __launch_bounds__(256,4) void k_gru_enc_mfma(
    const unsigned short* __restrict__ E,
    const unsigned short* __restrict__ Wpk,
    const float* __restrict__ bih, const float* __restrict__ bhh,
    float* __restrict__ h_all)
{
  __shared__ __align__(16) unsigned char Hb[2][2048];
  const int tid = threadIdx.x;
  const int w  = tid >> 6;         // wave 0..3
  const int l  = tid & 63;
  const int lr = l & 15;           // A row (seq) / D col
  const int lg = l >> 4;
  const size_t s0 = (size_t)blockIdx.x * 16;
  const int i  = w*16 + lr;        // owned h column

  uint4 bf[12];
  #pragma unroll
  for (int q=0; q<4; ++q) bf[q]   = *(const uint4*)(Wpk + (4*w + q)*512 + l*8);
  #pragma unroll
  for (int q=0; q<4; ++q) bf[4+q] = *(const uint4*)(Wpk + (16 + 4*w + q)*512 + l*8);
  #pragma unroll
  for (int q=0; q<2; ++q) bf[8+q] = *(const uint4*)(Wpk + (32 + 2*w + q)*512 + l*8);
  #pragma unroll
  for (int q=0; q<2; ++q) bf[10+q]= *(const uint4*)(Wpk + (40 + 2*w + q)*512 + l*8);

  const float b_r = bih[i]     + bhh[i];
  const float b_z = bih[64+i]  + bhh[64+i];
  const float bni = bih[128+i];
  const float bnh = bhh[128+i];

  *(uint4*)(&Hb[0][0] + tid*16) = make_uint4(0,0,0,0);
  __syncthreads();

  float hreg[4] = {0.f,0.f,0.f,0.f};

  uint4 ax0, ax1;
  {
    const unsigned short* p = E + (s0 + lr)*64 + lg*8;
    ax0 = *(const uint4*)(p);
    ax1 = *(const uint4*)(p + 32);
  }

  const int swz = (lr & 7) << 4;
  int cur = 0;

  #pragma unroll 1
  for (int t=0; t<T_OBS; ++t){
    int tn = (t < 15) ? t+1 : 15;
    const unsigned short* pn = E + ((size_t)tn*SEQ + s0 + lr)*64 + lg*8;
    uint4 nx0 = *(const uint4*)(pn);
    uint4 nx1 = *(const uint4*)(pn + 32);

    const unsigned char* hc = Hb[cur];
    uint4 ah0 = *(const uint4*)(hc + ((lr*128      + lg*16) ^ swz));
    uint4 ah1 = *(const uint4*)(hc + ((lr*128 + 64 + lg*16) ^ swz));

    bf16x8 Ax0 = as_bf16x8(ax0), Ax1 = as_bf16x8(ax1);
    bf16x8 Ah0 = as_bf16x8(ah0), Ah1 = as_bf16x8(ah1);

    f32x4 aR  = (f32x4){0.f,0.f,0.f,0.f};
    f32x4 aZ  = (f32x4){0.f,0.f,0.f,0.f};
    f32x4 aNI = (f32x4){0.f,0.f,0.f,0.f};
    f32x4 aNH = (f32x4){0.f,0.f,0.f,0.f};

    aR  = __builtin_amdgcn_mfma_f32_16x16x32_bf16(Ax0, as_bf16x8(bf[0]),  aR,  0,0,0);
    aR  = __builtin_amdgcn_mfma_f32_16x16x32_bf16(Ax1, as_bf16x8(bf[1]),  aR,  0,0,0);
    aR  = __builtin_amdgcn_mfma_f32_16x16x32_bf16(Ah0, as_bf16x8(bf[2]),  aR,  0,0,0);
    aR  = __builtin_amdgcn_mfma_f32_16x16x32_bf16(Ah1, as_bf16x8(bf[3]),  aR,  0,0,0);
    aZ  = __builtin_amdgcn_mfma_f32_16x16x32_bf16(Ax0, as_bf16x8(bf[4]),  aZ,  0,0,0);
    aZ  = __builtin_amdgcn_mfma_f32_16x16x32_bf16(Ax1, as_bf16x8(bf[5]),  aZ,  0,0,0);
    aZ  = __builtin_amdgcn_mfma_f32_16x16x32_bf16(Ah0, as_bf16x8(bf[6]),  aZ,  0,0,0);
    aZ  = __builtin_amdgcn_mfma_f32_16x16x32_bf16(Ah1, as_bf16x8(bf[7]),  aZ,  0,0,0);
    aNI = __builtin_amdgcn_mfma_f32_16x16x32_bf16(Ax0, as_bf16x8(bf[8]),  aNI, 0,0,0);
    aNI = __builtin_amdgcn_mfma_f32_16x16x32_bf16(Ax1, as_bf16x8(bf[9]),  aNI, 0,0,0);
    aNH = __builtin_amdgcn_mfma_f32_16x16x32_bf16(Ah0, as_bf16x8(bf[10]), aNH, 0,0,0);
    aNH = __builtin_amdgcn_mfma_f32_16x16x32_bf16(Ah1, as_bf16x8(bf[11]), aNH, 0,0,0);

    unsigned char* hn = Hb[cur^1];
    #pragma unroll
    for (int u=0; u<4; ++u){
      float r  = sigf(aR[u] + b_r);
      float z  = sigf(aZ[u] + b_z);
      float nn = tanh2f(fmaf(r, aNH[u] + bnh, aNI[u] + bni));
      float h  = fmaf(z, hreg[u] - nn, nn);
      hreg[u]  = h;
      int s = lg*4 + u;
      *(unsigned short*)(hn + ((s*128 + i*2) ^ ((s & 7) << 4))) = f2bf(h);
    }
    __syncthreads();
    cur ^= 1;
    ax0 = nx0; ax1 = nx1;
  }

  #pragma unroll
  for (int u=0; u<4; ++u)
    h_all[(s0 + lg*4 + u)*64 + i] = hreg[u];
}

// ---------------------------------------------------------------------------
// x_s = leaky(h_x @ hid_W.T + hid_b) -> xc[:, 0:32]
// ---------------------------------------------------------------------------
__global__ void k_xs(const float* __restrict__ h_all, const float* __restrict__ hidW,
                     const float* __restrict__ hidb, float* __restrict__ xc){
  int idx = blockIdx.x*blockDim.x + threadIdx.x;   // 4096*32
  int j = idx & 31, n = idx >> 5;
  const float* h = h_all + (size_t)n*64;
  const float* w = hidW + (size_t)j*64;
  float acc = hidb[j];
  for (int k4=0; k4<16; ++k4)
    acc = dot4f(*(const float4*)(h + k4*4), *(const float4*)(w + k4*4), acc);
  xc[(size_t)n*112 + j] = leakyf(acc);
}

// ---------------------------------------------------------------------------
// Social branch via MFMA (validated R5).
// ---------------------------------------------------------------------------
__global__ __launch_bounds__(256,3) void k_soc_mfma(
    const float* __restrict__ h_all, const int* __restrict__ cells,
    const unsigned short* __restrict__ WsocF, const float* __restrict__ socb,
    const float* __restrict__ c31W, const float* __restrict__ c31b,
    float* __restrict__ xc)
{
  __shared__ unsigned short Qb[9*8*64];   // 9 KB  [kk][v][o] bf16
  __shared__ float o1p[4*64*17];          // 17 KB scatter partials (y shifted +2)
  __shared__ float o1[64*12];             // 3 KB  out1 (y 0..10)
  __shared__ float c2p[4*144];            // 2.25 KB conv2 partials
  __shared__ float W2L[64*48];            // 12 KB [o][ky][p]
  __shared__ float socbL[64];
  __shared__ float b2L[16];
  __shared__ int   cellsL[64];            // [a][v]

  const int tid = threadIdx.x;
  const int w  = tid >> 6;
  const int l  = tid & 63;
  const int lr = l & 15, lg = l >> 4;
  const int n0 = blockIdx.x * 8;

  for (int idx=tid; idx<3072; idx+=256){
    int p = idx/192, rem = idx%192, o = rem/3, ky = rem%3;
    W2L[(o*3+ky)*16 + p] = c31W[idx];
  }
  if (tid < 64) socbL[tid] = socb[tid];
  if (tid < 16) b2L[tid]  = c31b[tid];
  if (tid < 64) cellsL[tid] = cells[n0*8 + tid];

  uint4 bs[18];
  #pragma unroll
  for (int f=0; f<18; ++f)
    bs[f] = *(const uint4*)(WsocF + (size_t)(w*18 + f)*512 + l*8);
  __syncthreads();

  #pragma unroll 1
  for (int a=0; a<8; ++a){
    uint4 ax0u = make_uint4(0,0,0,0), ax1u = make_uint4(0,0,0,0);
    if (lr < 8){
      const float* hp = h_all + ((size_t)NAg + (size_t)(n0+a)*8 + lr)*64 + lg*8;
      float4 f0 = *(const float4*)(hp);
      float4 f1 = *(const float4*)(hp + 4);
      float4 f2 = *(const float4*)(hp + 32);
      float4 f3 = *(const float4*)(hp + 36);
      ax0u = pack8bf(f0, f1);
      ax1u = pack8bf(f2, f3);
    }
    bf16x8 A0 = as_bf16x8(ax0u), A1 = as_bf16x8(ax1u);

    f32x4 acc[9];
    #pragma unroll
    for (int kk=0; kk<9; ++kk) acc[kk] = (f32x4){0.f,0.f,0.f,0.f};
    #pragma unroll
    for (int kk=0; kk<9; ++kk){
      acc[kk] = __builtin_amdgcn_mfma_f32_16x16x32_bf16(A0, as_bf16x8(bs[kk*2+0]), acc[kk], 0,0,0);
      acc[kk] = __builtin_amdgcn_mfma_f32_16x16x32_bf16(A1, as_bf16x8(bs[kk*2+1]), acc[kk], 0,0,0);
    }

    __syncthreads();

    if (lg < 2){
      #pragma unroll
      for (int kk=0; kk<9; ++kk)
        #pragma unroll
        for (int j=0; j<4; ++j)
          Qb[(kk*8 + lg*4 + j)*64 + w*16 + lr] = f2bf(acc[kk][j]);
    }
    for (int idx=tid; idx<2816; idx+=256){
      int q = idx/704, r = idx%704;
      int o = r/11, y = r%11;
      o1p[(q*64 + o)*17 + y + 2] = 0.f;
    }
    __syncthreads();

    {
      int o = tid & 63, q = tid >> 6;
      #pragma unroll
      for (int p6=0; p6<6; ++p6){
        int pr = q*6 + p6;
        int v = pr/3, ky = pr%3;
        int cc = cellsL[a*8 + v];
        int gw = cc/13, gh = cc - gw*13;
        float val = bf2f(Qb[((ky*3+gw)*8 + v)*64 + o]);
        o1p[(q*64 + o)*17 + (gh - ky + 2)] += val;
      }
    }
    __syncthreads();

    for (int idx=tid; idx<704; idx+=256){
      int o = idx/11, y = idx%11;
      float s = socbL[o];
      #pragma unroll
      for (int q=0; q<4; ++q) s += o1p[(q*64 + o)*17 + y + 2];
      o1[o*12 + y] = leakyf(s);
    }
    __syncthreads();

    {
      int q = tid >> 6, l2 = tid & 63;
      for (int e=l2; e<144; e+=64){
        int p = e & 15, y2 = e >> 4;
        float accv = 0.f;
        #pragma unroll
        for (int oi=0; oi<16; ++oi){
          int oo = q*16 + oi;
          const float* o1r = o1 + oo*12 + y2;
          const float* w2r = W2L + oo*48 + p;
          accv = fmaf(o1r[0], w2r[0], fmaf(o1r[1], w2r[16], fmaf(o1r[2], w2r[32], accv)));
        }
        c2p[q*144 + e] = accv;
      }
    }
    __syncthreads();

    if (tid < 80){
      int p = tid/5, ww = tid%5;
      float v0, v1;
      {
        int y2 = (ww == 0) ? 0 : 2*ww - 1;
        float s = b2L[p];
        #pragma unroll
        for (int q=0; q<4; ++q) s += c2p[q*144 + y2*16 + p];
        v0 = leakyf(s);
      }
      if (ww == 0) v1 = v0;
      else {
        int y2 = 2*ww;
        float s = b2L[p];
        #pragma unroll
        for (int q=0; q<4; ++q) s += c2p[q*144 + y2*16 + p];
        v1 = leakyf(s);
      }
      xc[(size_t)(n0+a)*112 + 32 + p*5 + ww] = fmaxf(v0, v1);
    }
  }
}

// ---------------------------------------------------------------------------
// Decoder GRU via MFMA, full-gate-per-wave partition (R7 pattern) + fused
// output head. Block = 16 seqs, 8 waves. Wave g owns h-columns [g*16,g*16+16)
// for ALL gates (12 B-frags). Epilogue in registers; h via double-buffered
// 2x4KB swizzled bf16 Hb; ONE barrier/step. Gm used once for gi staging.
// ---------------------------------------------------------------------------
__global__ __launch_bounds__(512,1) void k_dec_mfma(
    const float* __restrict__ xc, const unsigned short* __restrict__ WdecF,
    const unsigned short* __restrict__ WoutF,
    const float* __restrict__ dWih, const float* __restrict__ dbih,
    const float* __restrict__ dbhh, const float* __restrict__ outb,
    float* __restrict__ out)
{
  __shared__ float Gm[384*16];                          // gi staging (once)
  __shared__ __align__(16) unsigned char Hb[2][4096];   // h bf16, swizzled, dbuf
  __shared__ float xct[16*XSTR];
  const int tid = threadIdx.x;
  const int g   = tid >> 6;        // wave 0..7
  const int l   = tid & 63;
  const int lr  = l & 15, lg = l >> 4;
  const int n0  = blockIdx.x * 16;
  const int i   = g*16 + lr;       // owned h column (0..127)

  for (int idx=tid; idx<16*112; idx+=512){
    int s = idx/112, k = idx%112;
    xct[s*XSTR + k] = xc[(size_t)(n0+s)*112 + k];
  }
  *(uint4*)(&Hb[0][0] + tid*16) = make_uint4(0,0,0,0);  // zero both buffers (8KB)
  __syncthreads();

  {                                      // gi = xc @ dWih.T + dbih (once)
    int s = tid & 15, jq = tid >> 4;     // jq 0..31
    const float* xr = xct + s*XSTR;
    for (int jj=0; jj<12; ++jj){
      int j = jq*12 + jj;
      float acc = dbih[j];
      const float* wp = dWih + (size_t)j*112;
      for (int k4=0; k4<28; ++k4)
        acc = dot4f(*(const float4*)(wp + k4*4), *(const float4*)(xr + k4*4), acc);
      Gm[j*16 + s] = acc;
    }
  }
  __syncthreads();

  float gi_r[4], gi_z[4], gi_n[4];
  #pragma unroll
  for (int u=0; u<4; ++u){
    int s = lg*4 + u;
    gi_r[u] = Gm[(      i)*16 + s];
    gi_z[u] = Gm[(128 + i)*16 + s];
    gi_n[u] = Gm[(256 + i)*16 + s];
  }
  const float bh_r = dbhh[i], bh_z = dbhh[128+i], bh_n = dbhh[256+i];
  const float obv  = (lr < 5) ? outb[lr] : 0.f;

  // B-fragments: wave g's r/z/n tiles (12) + out head (wave 0 reads 4 more)
  uint4 bgf[12];
  #pragma unroll
  for (int f=0; f<12; ++f)
    bgf[f] = *(const uint4*)(WdecF + (size_t)(g*12 + f)*512 + l*8);
  uint4 bof[4];
  #pragma unroll
  for (int kk=0; kk<4; ++kk)
    bof[kk] = *(const uint4*)(WoutF + (size_t)kk*512 + l*8);

  float hreg[4] = {0.f, 0.f, 0.f, 0.f};
  const int swz = (lr & 7) << 4;
  int cur = 0;
  __syncthreads();

  #pragma unroll 1
  for (int t=0; t<PRED; ++t){
    const unsigned char* hc = Hb[cur];
    uint4 ah[4];
    #pragma unroll
    for (int kk=0; kk<4; ++kk)
      ah[kk] = *(const uint4*)(hc + ((lr*256 + kk*64 + lg*16) ^ swz));

    // fused out head for h_t (emits step t-1), wave 0 only
    if (g == 0 && t > 0){
      f32x4 accO = (f32x4){0.f,0.f,0.f,0.f};
      #pragma unroll
      for (int kk=0; kk<4; ++kk)
        accO = __builtin_amdgcn_mfma_f32_16x16x32_bf16(as_bf16x8(ah[kk]), as_bf16x8(bof[kk]), accO, 0,0,0);
      if (lr < 5){
        #pragma unroll
        for (int u=0; u<4; ++u){
          float a = accO[u] + obv;
          float val = (lr < 2) ? a : (lr == 4 ? tanhf_(a) : __expf(a));
          out[((size_t)(t-1)*NAg + n0 + lg*4 + u)*5 + lr] = val;
        }
      }
    }

    // gate GEMM: 3 gates x 4 K-steps, all for owned columns
    f32x4 aR = (f32x4){0.f,0.f,0.f,0.f};
    f32x4 aZ = (f32x4){0.f,0.f,0.f,0.f};
    f32x4 aN = (f32x4){0.f,0.f,0.f,0.f};
    #pragma unroll
    for (int kk=0; kk<4; ++kk)
      aR = __builtin_amdgcn_mfma_f32_16x16x32_bf16(as_bf16x8(ah[kk]), as_bf16x8(bgf[kk]),    aR, 0,0,0);
    #pragma unroll
    for (int kk=0; kk<4; ++kk)
      aZ = __builtin_amdgcn_mfma_f32_16x16x32_bf16(as_bf16x8(ah[kk]), as_bf16x8(bgf[4+kk]),  aZ, 0,0,0);
    #pragma unroll
    for (int kk=0; kk<4; ++kk)
      aN = __builtin_amdgcn_mfma_f32_16x16x32_bf16(as_bf16x8(ah[kk]), as_bf16x8(bgf[8+kk]),  aN, 0,0,0);

    // elementwise GRU update in registers; write h to other buffer
    unsigned char* hn = Hb[cur^1];
    #pragma unroll
    for (int u=0; u<4; ++u){
      float r  = sigf(gi_r[u] + aR[u] + bh_r);
      float z  = sigf(gi_z[u] + aZ[u] + bh_z);
      float nn = tanh2f(fmaf(r, aN[u] + bh_n, gi_n[u]));
      float h  = fmaf(z, hreg[u] - nn, nn);
      hreg[u] = h;
      int s = lg*4 + u;
      *(unsigned short*)(hn + ((s*256 + i*2) ^ ((s & 7) << 4))) = f2bf(h);
    }
    __syncthreads();
    cur ^= 1;
  }

  // tail: out head for h_PRED (step PRED-1)
  if (g == 0){
    const unsigned char* hc = Hb[cur];
    uint4 ah[4];
    #pragma unroll
    for (int kk=0; kk<4; ++kk)
      ah[kk] = *(const uint4*)(hc + ((lr*256 + kk*64 + lg*16) ^ swz));
    f32x4 accO = (f32x4){0.f,0.f,0.f,0.f};
    #pragma unroll
    for (int kk=0; kk<4; ++kk)
      accO = __builtin_amdgcn_mfma_f32_16x16x32_bf16(as_bf16x8(ah[kk]), as_bf16x8(bof[kk]), accO, 0,0,0);
    if (lr < 5){
      #pragma unroll
      for (int u=0; u<4; ++u){
        float a = accO[u] + obv;
        float val = (lr < 2) ? a : (lr == 4 ? tanhf_(a) : __expf(a));
        out[((size_t)(PRED-1)*NAg + n0 + lg*4 + u)*5 + lr] = val;
      }
    }
  }
}

// ---------------------------------------------------------------------------
extern "C" void kernel_launch(void* const* d_in, const int* in_sizes, int n_in,
                              void* d_out, int out_size, void* d_ws, size_t ws_size,
                              hipStream_t stream)
{
  const float* x      = (const float*)d_in[0];
  const float* ngbrs  = (const float*)d_in[1];
  const float* graphs = (const float*)d_in[2];
  const void*  masks  = d_in[3];
  // d_in[4] = ngbrs_idx (unused by the reference computation)
  const float* dynW   = (const float*)d_in[5];
  const float* dynb   = (const float*)d_in[6];
  const float* eWih   = (const float*)d_in[7];
  const float* eWhh   = (const float*)d_in[8];
  const float* ebih   = (const float*)d_in[9];
  const float* ebhh   = (const float*)d_in[10];
  const float* sW     = (const float*)d_in[11];
  const float* sb     = (const float*)d_in[12];
  const float* hidW   = (const float*)d_in[13];
  const float* hidb   = (const float*)d_in[14];
  const float* socW   = (const float*)d_in[15];
  const float* socb   = (const float*)d_in[16];
  const float* c31W   = (const float*)d_in[17];
  const float* c31b   = (const float*)d_in[18];
  const float* dWih   = (const float*)d_in[19];
  const float* dWhh   = (const float*)d_in[20];
  const float* dbih   = (const float*)d_in[21];
  const float* dbhh   = (const float*)d_in[22];
  const float* outW   = (const float*)d_in[23];
  const float* outb   = (const float*)d_in[24];
  float* out = (float*)d_out;

  char* ws = (char*)d_ws;
  size_t off = 0;
  __hip_bfloat16* E = (__hip_bfloat16*)(ws + off); off += (size_t)T_OBS*SEQ*64*2;   // 75.5 MB
  float* h_all      = (float*)(ws + off);          off += (size_t)SEQ*64*4;          // 9.4 MB
  int*   cells      = (int*)(ws + off);            off += (size_t)NAg*8*4;
  float* xc         = (float*)(ws + off);          off += (size_t)NAg*112*4;
  unsigned short* Wpk = (unsigned short*)(ws + off); off += (size_t)48*512*2;
  unsigned short* WdecF = (unsigned short*)(ws + off); off += (size_t)96*512*2;
  unsigned short* WoutF = (unsigned short*)(ws + off); off += (size_t)4*512*2;
  unsigned short* SWF = (unsigned short*)(ws + off); off += (size_t)16*512*2;
  unsigned short* WsocF = (unsigned short*)(ws + off); off += (size_t)72*512*2;

  k_decode_masks<<<16, 256, 0, stream>>>(masks, cells);
  k_prep<<<192, 256, 0, stream>>>(eWih, eWhh, Wpk, dWhh, WdecF, outW, WoutF, sW, SWF, socW, WsocF);
  k_embed_x<<<16384, 256, 0, stream>>>(x, dynW, dynb, E);
  k_embed_agg_mfma<<<4096, 256, 0, stream>>>(ngbrs, graphs, dynW, dynb, SWF, sb, E);
  k_gru_enc_mfma<<<2304, 256, 0, stream>>>((const unsigned short*)E, Wpk, ebih, ebhh, h_all);
  k_xs<<<512, 256, 0, stream>>>(h_all, hidW, hidb, xc);
  k_soc_mfma<<<512, 256, 0, stream>>>(h_all, cells, WsocF, socb, c31W, c31b, xc);
  k_dec_mfma<<<256, 512, 0, stream>>>(xc, WdecF, WoutF, dWih, dbih, dbhh, outb, out);
}

// Round 10
// 254.298 us; speedup vs baseline: 5.3739x; 1.1386x over previous
//
#include <hip/hip_runtime.h>
#include <hip/hip_bf16.h>

#define T_OBS 16
#define NAg   4096
#define Vn    8
#define NV    32768           // NAg*Vn
#define SEQ   36864           // NAg + NV
#define PRED  25
#define XSTR  116             // padded LDS stride for 112-wide xc tile

typedef __bf16 bf16x8 __attribute__((ext_vector_type(8)));
typedef float  f32x4  __attribute__((ext_vector_type(4)));

__device__ __forceinline__ float leakyf(float v){ return v >= 0.f ? v : 0.1f*v; }
// fast sigmoid/tanh: v_rcp_f32 (~1 ulp) instead of IEEE divide (~10 instrs)
__device__ __forceinline__ float sigf(float x){
  return __builtin_amdgcn_rcpf(1.f + __expf(-x));
}
__device__ __forceinline__ float tanh2f(float x){
  return fmaf(2.f, __builtin_amdgcn_rcpf(1.f + __expf(-2.f*x)), -1.f);
}
__device__ __forceinline__ float tanhf_(float x){
  x = fminf(fmaxf(x, -10.f), 10.f);
  float e = __expf(2.f*x);
  return (e-1.f)*__builtin_amdgcn_rcpf(e+1.f);
}
__device__ __forceinline__ float bf2f(unsigned short u){
  union{unsigned int i; float f;} v; v.i = ((unsigned int)u)<<16; return v.f;
}
__device__ __forceinline__ unsigned short f2bf(float f){
  __hip_bfloat16 b = __float2bfloat16(f);
  return *reinterpret_cast<unsigned short*>(&b);
}
__device__ __forceinline__ float dot4f(float4 a, float4 b, float acc){
  return fmaf(a.x,b.x, fmaf(a.y,b.y, fmaf(a.z,b.z, fmaf(a.w,b.w, acc))));
}
__device__ __forceinline__ bf16x8 as_bf16x8(uint4 u){
  union { uint4 a; bf16x8 b; } v; v.a = u; return v.b;
}
__device__ __forceinline__ uint4 pack8bf(float4 a, float4 b){
  union{ unsigned short s[8]; uint4 u; } o;
  o.s[0]=f2bf(a.x); o.s[1]=f2bf(a.y); o.s[2]=f2bf(a.z); o.s[3]=f2bf(a.w);
  o.s[4]=f2bf(b.x); o.s[5]=f2bf(b.y); o.s[6]=f2bf(b.z); o.s[7]=f2bf(b.w);
  return o.u;
}

// ---------------------------------------------------------------------------
// Decode bool masks -> per-agent 8 selected cell indices.
// ---------------------------------------------------------------------------
__global__ void k_decode_masks(const void* __restrict__ masks, int* __restrict__ cells){
  int n = blockIdx.x*blockDim.x + threadIdx.x;
  if (n >= NAg) return;
  const unsigned char* m8  = (const unsigned char*)masks;
  const int*           m32 = (const int*)masks;
  int tmp[8]; for (int v=0; v<8; ++v) tmp[v] = 0;
  int cnt = 0;
  for (int cc=0; cc<39; ++cc){                 // u8 interpretation (bool bytes)
    size_t base = ((size_t)n*39 + cc)*64;
    if (m8[base] && m8[base+1] && m8[base+33]){ if (cnt<8) tmp[cnt]=cc; cnt++; }
  }
  if (cnt != 8){                               // fallback: 4-byte elements
    cnt = 0;
    for (int cc=0; cc<39; ++cc){
      size_t base = ((size_t)n*39 + cc)*64;
      if (m32[base] != 0){ if (cnt<8) tmp[cnt]=cc; cnt++; }
    }
  }
  for (int v=0; v<8; ++v) cells[n*8+v] = tmp[v];
}

// ---------------------------------------------------------------------------
// One-shot weight re-layouts (unchanged from R8).
// ---------------------------------------------------------------------------
__global__ void k_prep(const float* __restrict__ eWih, const float* __restrict__ eWhh,
                       unsigned short* __restrict__ Wpk,
                       const float* __restrict__ dWhh, unsigned short* __restrict__ WdecF,
                       const float* __restrict__ outW, unsigned short* __restrict__ WoutF,
                       const float* __restrict__ sW, unsigned short* __restrict__ SWF,
                       const float* __restrict__ socW, unsigned short* __restrict__ WsocF){
  int idx = blockIdx.x*blockDim.x + threadIdx.x;   // 49152 threads
  if (idx < 24576){                                // encoder: 48 frags * 512
    int f   = idx >> 9;
    int rem = idx & 511;
    int l   = rem >> 3, j = rem & 7;
    int lr  = l & 15, lg = l >> 4;
    float val;
    if (f < 32){
      int nt = f >> 2, kk = f & 3;
      int n  = nt*16 + lr;                         // rows 0..127 = r,z gates
      int k  = kk*32 + lg*8 + j;
      val = (k < 64) ? eWih[(size_t)n*64 + k] : eWhh[(size_t)n*64 + (k-64)];
    } else if (f < 40){
      int q = f - 32;
      int n = (8 + (q>>1))*16 + lr;                // rows 128..191 = n gate
      int k = (q&1)*32 + lg*8 + j;
      val = eWih[(size_t)n*64 + k];
    } else {
      int q = f - 40;
      int n = (8 + (q>>1))*16 + lr;
      int k = (q&1)*32 + lg*8 + j;
      val = eWhh[(size_t)n*64 + k];
    }
    Wpk[f*512 + l*8 + j] = f2bf(val);
  }
  if (idx < 49152){                                // decoder: 96 frags * 512
    int f   = idx >> 9;                            // g*12 + gate*4 + kk
    int rem = idx & 511;
    int l   = rem >> 3, j = rem & 7;
    int lr  = l & 15, lg = l >> 4;
    int g = f/12, loc = f%12, gate = loc>>2, kk = loc&3;
    int n = gate*128 + g*16 + lr;
    int k = kk*32 + lg*8 + j;
    WdecF[idx] = f2bf(dWhh[(size_t)n*128 + k]);
  }
  if (idx < 2048){                                 // out head: 4 frags * 512
    int kk  = idx >> 9;
    int rem = idx & 511;
    int l   = rem >> 3, j = rem & 7;
    int lr  = l & 15, lg = l >> 4;
    int k = kk*32 + lg*8 + j;
    float v = (lr < 5) ? outW[(size_t)lr*128 + k] : 0.f;
    WoutF[idx] = f2bf(v);
  }
  if (idx < 8192){                                 // s_W: 16 frags * 512
    int f   = idx >> 9;                            // nt*2 + kk
    int rem = idx & 511;
    int l   = rem >> 3, j = rem & 7;
    int lr  = l & 15, lg = l >> 4;
    int nt = f >> 1, kk = f & 1;
    int nn = nt*16 + lr;
    int k  = kk*32 + lg*8 + j;
    SWF[idx] = f2bf(sW[(size_t)nn*64 + k]);
  }
  if (idx < 36864){                                // soc conv1: 72 frags * 512
    int f   = idx >> 9;                            // (w*9+kk)*2+ks
    int rem = idx & 511;
    int l   = rem >> 3, j = rem & 7;
    int lr  = l & 15, lg = l >> 4;
    int w = f/18, loc = f%18, kk = loc>>1, ks = loc&1;
    int o = w*16 + lr;
    int c = ks*32 + lg*8 + j;
    WsocF[idx] = f2bf(socW[(size_t)o*576 + c*9 + kk]);
  }
}

// ---------------------------------------------------------------------------
// x_e = leaky(x @ dyn_W.T + dyn_b) -> E[t][0..4095][c] (bf16)
// ---------------------------------------------------------------------------
__global__ void k_embed_x(const float* __restrict__ x, const float* __restrict__ dynW,
                          const float* __restrict__ dynb, __hip_bfloat16* __restrict__ E){
  int idx = blockIdx.x*blockDim.x + threadIdx.x;   // 16*4096*64 exactly
  int c = idx & 63;
  int s = (idx >> 6) & 4095;
  int t = idx >> 18;
  float x0 = x[((size_t)t*NAg + s)*2 + 0];
  float x1 = x[((size_t)t*NAg + s)*2 + 1];
  float v = leakyf(fmaf(x0, dynW[c*2+0], fmaf(x1, dynW[c*2+1], dynb[c])));
  E[((size_t)t*SEQ + s)*64 + c] = __float2bfloat16(v);
}

// ---------------------------------------------------------------------------
// Per agent n (fused, MFMA): ng_e -> H = ng_e@sW.T+sb -> graph einsum -> E.
// (validated R4)
// ---------------------------------------------------------------------------
__global__ __launch_bounds__(256,2) void k_embed_agg_mfma(
    const float* __restrict__ ngbrs, const float* __restrict__ graphs,
    const float* __restrict__ dynW, const float* __restrict__ dynb,
    const unsigned short* __restrict__ SWF, const float* __restrict__ sb,
    __hip_bfloat16* __restrict__ E)
{
  __shared__ __align__(16) unsigned char ngeb[128*128];   // bf16 [row][64] swizzled
  __shared__ __align__(16) unsigned short hm[128*136];    // bf16 [tv][128 pad 136]
  __shared__ float2 pL[128];
  __shared__ float  gL[128];
  __shared__ float2 dwL[64];
  __shared__ float  dbL[64];
  const int tid = threadIdx.x;
  const int n = blockIdx.x;

  if (tid < 128) gL[tid] = graphs[(size_t)n*128 + tid];
  if (tid < 64)  dwL[tid] = *(const float2*)(dynW + tid*2);
  if (tid < 64)  dbL[tid] = dynb[tid];
  if (tid < 128){
    int t = tid >> 3, v = tid & 7;
    pL[tid] = *(const float2*)(ngbrs + ((size_t)t*NV + (size_t)n*8 + v)*2);
  }
  __syncthreads();

  #pragma unroll
  for (int p=0; p<4; ++p){
    int chunk = tid + p*256;          // 1024: row*8 + c8
    int row = chunk >> 3, c8 = chunk & 7;
    float2 xy = pL[row];
    union { unsigned short s[8]; uint4 u; } ou;
    #pragma unroll
    for (int jj=0; jj<8; ++jj){
      int c = c8*8 + jj;
      ou.s[jj] = f2bf(leakyf(fmaf(xy.x, dwL[c].x, fmaf(xy.y, dwL[c].y, dbL[c]))));
    }
    *(uint4*)(ngeb + ((row*128 + c8*16) ^ ((row&7)<<4))) = ou.u;
  }
  __syncthreads();

  const int w4 = tid >> 6, l = tid & 63, lr = l & 15, lg = l >> 4;
  {
    uint4 bsw[16];
    #pragma unroll
    for (int f=0; f<16; ++f) bsw[f] = *(const uint4*)(SWF + f*512 + l*8);
    float sbv[8];
    #pragma unroll
    for (int nt=0; nt<8; ++nt) sbv[nt] = sb[nt*16 + lr];

    f32x4 acc[2][8];
    #pragma unroll
    for (int m=0; m<2; ++m)
      #pragma unroll
      for (int nt=0; nt<8; ++nt)
        acc[m][nt] = (f32x4){sbv[nt], sbv[nt], sbv[nt], sbv[nt]};

    #pragma unroll
    for (int m=0; m<2; ++m){
      int row = (w4*2+m)*16 + lr;
      int rb = row*128, sz = (row&7)<<4;
      uint4 a0 = *(const uint4*)(ngeb + ((rb      + lg*16) ^ sz));
      uint4 a1 = *(const uint4*)(ngeb + ((rb + 64 + lg*16) ^ sz));
      bf16x8 A0 = as_bf16x8(a0), A1 = as_bf16x8(a1);
      #pragma unroll
      for (int nt=0; nt<8; ++nt){
        acc[m][nt] = __builtin_amdgcn_mfma_f32_16x16x32_bf16(A0, as_bf16x8(bsw[nt*2+0]), acc[m][nt], 0,0,0);
        acc[m][nt] = __builtin_amdgcn_mfma_f32_16x16x32_bf16(A1, as_bf16x8(bsw[nt*2+1]), acc[m][nt], 0,0,0);
      }
    }
    #pragma unroll
    for (int m=0; m<2; ++m)
      #pragma unroll
      for (int nt=0; nt<8; ++nt)
        #pragma unroll
        for (int jj=0; jj<4; ++jj)
          hm[((w4*2+m)*16 + lg*4 + jj)*136 + nt*16 + lr] = f2bf(acc[m][nt][jj]);
  }
  __syncthreads();

  #pragma unroll
  for (int p=0; p<4; ++p){
    int task = tid + p*256;           // 1024: t*64 + wv*8 + c8
    int c8 = task & 7, wv = (task>>3)&7, t = task >> 6;
    float a8[8];
    #pragma unroll
    for (int jj=0; jj<8; ++jj) a8[jj] = 0.f;
    #pragma unroll
    for (int k=0; k<2; ++k){
      #pragma unroll
      for (int v=0; v<8; ++v){
        float g = gL[k*64 + v*8 + wv];
        uint4 hv4 = *(const uint4*)(hm + (t*8+v)*136 + k*64 + c8*8);
        const unsigned short* hh = (const unsigned short*)&hv4;
        #pragma unroll
        for (int jj=0; jj<8; ++jj) a8[jj] = fmaf(g, bf2f(hh[jj]), a8[jj]);
      }
    }
    union { unsigned short s[8]; uint4 u; } ou;
    #pragma unroll
    for (int jj=0; jj<8; ++jj) ou.s[jj] = f2bf(a8[jj]);
    *(uint4*)((unsigned short*)E + ((size_t)t*SEQ + NAg + (size_t)n*8 + wv)*64 + c8*8) = ou.u;
  }
}

// ---------------------------------------------------------------------------
// Encoder GRU via MFMA, full-gate-per-wave partition (validated R7).
// R9: rcp-based gates, hoisted LDS offsets, pointer-increment x prefetch.
// ---------------------------------------------------------------------------
__global__ __launch_bounds__(256,4) void k_gru_enc_mfma(
    const unsigned short* __restrict__ E,
    const unsigned short* __restrict__ Wpk,
    const float* __restrict__ bih, const float* __restrict__ bhh,
    float* __restrict__ h_all)
{
  __shared__ __align__(16) unsigned char Hb[2][2048];
  const int tid = threadIdx.x;
  const int w  = tid >> 6;         // wave 0..3
  const int l  = tid & 63;
  const int lr = l & 15;           // A row (seq) / D col
  const int lg = l >> 4;
  const size_t s0 = (size_t)blockIdx.x * 16;
  const int i  = w*16 + lr;        // owned h column

  uint4 bf[12];
  #pragma unroll
  for (int q=0; q<4; ++q) bf[q]   = *(const uint4*)(Wpk + (4*w + q)*512 + l*8);
  #pragma unroll
  for (int q=0; q<4; ++q) bf[4+q] = *(const uint4*)(Wpk + (16 + 4*w + q)*512 + l*8);
  #pragma unroll
  for (int q=0; q<2; ++q) bf[8+q] = *(const uint4*)(Wpk + (32 + 2*w + q)*512 + l*8);
  #pragma unroll
  for (int q=0; q<2; ++q) bf[10+q]= *(const uint4*)(Wpk + (40 + 2*w + q)*512 + l*8);

  const float b_r = bih[i]     + bhh[i];
  const float b_z = bih[64+i]  + bhh[64+i];
  const float bni = bih[128+i];
  const float bnh = bhh[128+i];

  *(uint4*)(&Hb[0][0] + tid*16) = make_uint4(0,0,0,0);
  __syncthreads();

  float hreg[4] = {0.f,0.f,0.f,0.f};

  // hoisted LDS offsets (loop-invariant)
  const int swz = (lr & 7) << 4;
  const int rd0 = (lr*128      + lg*16) ^ swz;
  const int rd1 = (lr*128 + 64 + lg*16) ^ swz;
  int wro[4];
  #pragma unroll
  for (int u=0; u<4; ++u){
    int s = lg*4 + u;
    wro[u] = (s*128 + i*2) ^ ((s & 7) << 4);
  }

  // x pointer, advanced by one timestep per iteration
  const unsigned short* ep = E + (s0 + lr)*64 + lg*8;
  uint4 ax0 = *(const uint4*)(ep);
  uint4 ax1 = *(const uint4*)(ep + 32);

  int cur = 0;

  #pragma unroll 1
  for (int t=0; t<T_OBS; ++t){
    const unsigned short* pn = ep + ((t < 15) ? (size_t)SEQ*64 : 0);
    uint4 nx0 = *(const uint4*)(pn);
    uint4 nx1 = *(const uint4*)(pn + 32);

    const unsigned char* hc = Hb[cur];
    uint4 ah0 = *(const uint4*)(hc + rd0);
    uint4 ah1 = *(const uint4*)(hc + rd1);

    bf16x8 Ax0 = as_bf16x8(ax0), Ax1 = as_bf16x8(ax1);
    bf16x8 Ah0 = as_bf16x8(ah0), Ah1 = as_bf16x8(ah1);

    f32x4 aR  = (f32x4){0.f,0.f,0.f,0.f};
    f32x4 aZ  = (f32x4){0.f,0.f,0.f,0.f};
    f32x4 aNI = (f32x4){0.f,0.f,0.f,0.f};
    f32x4 aNH = (f32x4){0.f,0.f,0.f,0.f};

    aR  = __builtin_amdgcn_mfma_f32_16x16x32_bf16(Ax0, as_bf16x8(bf[0]),  aR,  0,0,0);
    aR  = __builtin_amdgcn_mfma_f32_16x16x32_bf16(Ax1, as_bf16x8(bf[1]),  aR,  0,0,0);
    aR  = __builtin_amdgcn_mfma_f32_16x16x32_bf16(Ah0, as_bf16x8(bf[2]),  aR,  0,0,0);
    aR  = __builtin_amdgcn_mfma_f32_16x16x32_bf16(Ah1, as_bf16x8(bf[3]),  aR,  0,0,0);
    aZ  = __builtin_amdgcn_mfma_f32_16x16x32_bf16(Ax0, as_bf16x8(bf[4]),  aZ,  0,0,0);
    aZ  = __builtin_amdgcn_mfma_f32_16x16x32_bf16(Ax1, as_bf16x8(bf[5]),  aZ,  0,0,0);
    aZ  = __builtin_amdgcn_mfma_f32_16x16x32_bf16(Ah0, as_bf16x8(bf[6]),  aZ,  0,0,0);
    aZ  = __builtin_amdgcn_mfma_f32_16x16x32_bf16(Ah1, as_bf16x8(bf[7]),  aZ,  0,0,0);
    aNI = __builtin_amdgcn_mfma_f32_16x16x32_bf16(Ax0, as_bf16x8(bf[8]),  aNI, 0,0,0);
    aNI = __builtin_amdgcn_mfma_f32_16x16x32_bf16(Ax1, as_bf16x8(bf[9]),  aNI, 0,0,0);
    aNH = __builtin_amdgcn_mfma_f32_16x16x32_bf16(Ah0, as_bf16x8(bf[10]), aNH, 0,0,0);
    aNH = __builtin_amdgcn_mfma_f32_16x16x32_bf16(Ah1, as_bf16x8(bf[11]), aNH, 0,0,0);

    unsigned char* hn = Hb[cur^1];
    #pragma unroll
    for (int u=0; u<4; ++u){
      float r  = sigf(aR[u] + b_r);
      float z  = sigf(aZ[u] + b_z);
      float nn = tanh2f(fmaf(r, aNH[u] + bnh, aNI[u] + bni));
      float h  = fmaf(z, hreg[u] - nn, nn);
      hreg[u]  = h;
      *(unsigned short*)(hn + wro[u]) = f2bf(h);
    }
    __syncthreads();
    cur ^= 1;
    ax0 = nx0; ax1 = nx1;
    ep = pn;
  }

  #pragma unroll
  for (int u=0; u<4; ++u)
    h_all[(s0 + lg*4 + u)*64 + i] = hreg[u];
}

// ---------------------------------------------------------------------------
// x_s = leaky(h_x @ hid_W.T + hid_b) -> xc[:, 0:32]
// ---------------------------------------------------------------------------
__global__ void k_xs(const float* __restrict__ h_all, const float* __restrict__ hidW,
                     const float* __restrict__ hidb, float* __restrict__ xc){
  int idx = blockIdx.x*blockDim.x + threadIdx.x;   // 4096*32
  int j = idx & 31, n = idx >> 5;
  const float* h = h_all + (size_t)n*64;
  const float* w = hidW + (size_t)j*64;
  float acc = hidb[j];
  for (int k4=0; k4<16; ++k4)
    acc = dot4f(*(const float4*)(h + k4*4), *(const float4*)(w + k4*4), acc);
  xc[(size_t)n*112 + j] = leakyf(acc);
}

// ---------------------------------------------------------------------------
// Social branch via MFMA (validated R5).
// ---------------------------------------------------------------------------
__global__ __launch_bounds__(256,3) void k_soc_mfma(
    const float* __restrict__ h_all, const int* __restrict__ cells,
    const unsigned short* __restrict__ WsocF, const float* __restrict__ socb,
    const float* __restrict__ c31W, const float* __restrict__ c31b,
    float* __restrict__ xc)
{
  __shared__ unsigned short Qb[9*8*64];   // 9 KB  [kk][v][o] bf16
  __shared__ float o1p[4*64*17];          // 17 KB scatter partials (y shifted +2)
  __shared__ float o1[64*12];             // 3 KB  out1 (y 0..10)
  __shared__ float c2p[4*144];            // 2.25 KB conv2 partials
  __shared__ float W2L[64*48];            // 12 KB [o][ky][p]
  __shared__ float socbL[64];
  __shared__ float b2L[16];
  __shared__ int   cellsL[64];            // [a][v]

  const int tid = threadIdx.x;
  const int w  = tid >> 6;
  const int l  = tid & 63;
  const int lr = l & 15, lg = l >> 4;
  const int n0 = blockIdx.x * 8;

  for (int idx=tid; idx<3072; idx+=256){
    int p = idx/192, rem = idx%192, o = rem/3, ky = rem%3;
    W2L[(o*3+ky)*16 + p] = c31W[idx];
  }
  if (tid < 64) socbL[tid] = socb[tid];
  if (tid < 16) b2L[tid]  = c31b[tid];
  if (tid < 64) cellsL[tid] = cells[n0*8 + tid];

  uint4 bs[18];
  #pragma unroll
  for (int f=0; f<18; ++f)
    bs[f] = *(const uint4*)(WsocF + (size_t)(w*18 + f)*512 + l*8);
  __syncthreads();

  #pragma unroll 1
  for (int a=0; a<8; ++a){
    uint4 ax0u = make_uint4(0,0,0,0), ax1u = make_uint4(0,0,0,0);
    if (lr < 8){
      const float* hp = h_all + ((size_t)NAg + (size_t)(n0+a)*8 + lr)*64 + lg*8;
      float4 f0 = *(const float4*)(hp);
      float4 f1 = *(const float4*)(hp + 4);
      float4 f2 = *(const float4*)(hp + 32);
      float4 f3 = *(const float4*)(hp + 36);
      ax0u = pack8bf(f0, f1);
      ax1u = pack8bf(f2, f3);
    }
    bf16x8 A0 = as_bf16x8(ax0u), A1 = as_bf16x8(ax1u);

    f32x4 acc[9];
    #pragma unroll
    for (int kk=0; kk<9; ++kk) acc[kk] = (f32x4){0.f,0.f,0.f,0.f};
    #pragma unroll
    for (int kk=0; kk<9; ++kk){
      acc[kk] = __builtin_amdgcn_mfma_f32_16x16x32_bf16(A0, as_bf16x8(bs[kk*2+0]), acc[kk], 0,0,0);
      acc[kk] = __builtin_amdgcn_mfma_f32_16x16x32_bf16(A1, as_bf16x8(bs[kk*2+1]), acc[kk], 0,0,0);
    }

    __syncthreads();

    if (lg < 2){
      #pragma unroll
      for (int kk=0; kk<9; ++kk)
        #pragma unroll
        for (int j=0; j<4; ++j)
          Qb[(kk*8 + lg*4 + j)*64 + w*16 + lr] = f2bf(acc[kk][j]);
    }
    for (int idx=tid; idx<2816; idx+=256){
      int q = idx/704, r = idx%704;
      int o = r/11, y = r%11;
      o1p[(q*64 + o)*17 + y + 2] = 0.f;
    }
    __syncthreads();

    {
      int o = tid & 63, q = tid >> 6;
      #pragma unroll
      for (int p6=0; p6<6; ++p6){
        int pr = q*6 + p6;
        int v = pr/3, ky = pr%3;
        int cc = cellsL[a*8 + v];
        int gw = cc/13, gh = cc - gw*13;
        float val = bf2f(Qb[((ky*3+gw)*8 + v)*64 + o]);
        o1p[(q*64 + o)*17 + (gh - ky + 2)] += val;
      }
    }
    __syncthreads();

    for (int idx=tid; idx<704; idx+=256){
      int o = idx/11, y = idx%11;
      float s = socbL[o];
      #pragma unroll
      for (int q=0; q<4; ++q) s += o1p[(q*64 + o)*17 + y + 2];
      o1[o*12 + y] = leakyf(s);
    }
    __syncthreads();

    {
      int q = tid >> 6, l2 = tid & 63;
      for (int e=l2; e<144; e+=64){
        int p = e & 15, y2 = e >> 4;
        float accv = 0.f;
        #pragma unroll
        for (int oi=0; oi<16; ++oi){
          int oo = q*16 + oi;
          const float* o1r = o1 + oo*12 + y2;
          const float* w2r = W2L + oo*48 + p;
          accv = fmaf(o1r[0], w2r[0], fmaf(o1r[1], w2r[16], fmaf(o1r[2], w2r[32], accv)));
        }
        c2p[q*144 + e] = accv;
      }
    }
    __syncthreads();

    if (tid < 80){
      int p = tid/5, ww = tid%5;
      float v0, v1;
      {
        int y2 = (ww == 0) ? 0 : 2*ww - 1;
        float s = b2L[p];
        #pragma unroll
        for (int q=0; q<4; ++q) s += c2p[q*144 + y2*16 + p];
        v0 = leakyf(s);
      }
      if (ww == 0) v1 = v0;
      else {
        int y2 = 2*ww;
        float s = b2L[p];
        #pragma unroll
        for (int q=0; q<4; ++q) s += c2p[q*144 + y2*16 + p];
        v1 = leakyf(s);
      }
      xc[(size_t)(n0+a)*112 + 32 + p*5 + ww] = fmaxf(v0, v1);
    }
  }
}

// ---------------------------------------------------------------------------
// Decoder GRU via MFMA, full-gate-per-wave partition + fused output head.
// R9: rcp gates, hoisted LDS offsets, out-head round-robin over waves.
// ---------------------------------------------------------------------------
__global__ __launch_bounds__(512,1) void k_dec_mfma(
    const float* __restrict__ xc, const unsigned short* __restrict__ WdecF,
    const unsigned short* __restrict__ WoutF,
    const float* __restrict__ dWih, const float* __restrict__ dbih,
    const float* __restrict__ dbhh, const float* __restrict__ outb,
    float* __restrict__ out)
{
  __shared__ float Gm[384*16];                          // gi staging (once)
  __shared__ __align__(16) unsigned char Hb[2][4096];   // h bf16, swizzled, dbuf
  __shared__ float xct[16*XSTR];
  const int tid = threadIdx.x;
  const int g   = tid >> 6;        // wave 0..7
  const int l   = tid & 63;
  const int lr  = l & 15, lg = l >> 4;
  const int n0  = blockIdx.x * 16;
  const int i   = g*16 + lr;       // owned h column (0..127)

  for (int idx=tid; idx<16*112; idx+=512){
    int s = idx/112, k = idx%112;
    xct[s*XSTR + k] = xc[(size_t)(n0+s)*112 + k];
  }
  *(uint4*)(&Hb[0][0] + tid*16) = make_uint4(0,0,0,0);  // zero both buffers (8KB)
  __syncthreads();

  {                                      // gi = xc @ dWih.T + dbih (once)
    int s = tid & 15, jq = tid >> 4;     // jq 0..31
    const float* xr = xct + s*XSTR;
    for (int jj=0; jj<12; ++jj){
      int j = jq*12 + jj;
      float acc = dbih[j];
      const float* wp = dWih + (size_t)j*112;
      for (int k4=0; k4<28; ++k4)
        acc = dot4f(*(const float4*)(wp + k4*4), *(const float4*)(xr + k4*4), acc);
      Gm[j*16 + s] = acc;
    }
  }
  __syncthreads();

  float gi_r[4], gi_z[4], gi_n[4];
  #pragma unroll
  for (int u=0; u<4; ++u){
    int s = lg*4 + u;
    gi_r[u] = Gm[(      i)*16 + s];
    gi_z[u] = Gm[(128 + i)*16 + s];
    gi_n[u] = Gm[(256 + i)*16 + s];
  }
  const float bh_r = dbhh[i], bh_z = dbhh[128+i], bh_n = dbhh[256+i];
  const float obv  = (lr < 5) ? outb[lr] : 0.f;

  uint4 bgf[12];
  #pragma unroll
  for (int f=0; f<12; ++f)
    bgf[f] = *(const uint4*)(WdecF + (size_t)(g*12 + f)*512 + l*8);
  uint4 bof[4];
  #pragma unroll
  for (int kk=0; kk<4; ++kk)
    bof[kk] = *(const uint4*)(WoutF + (size_t)kk*512 + l*8);

  float hreg[4] = {0.f, 0.f, 0.f, 0.f};

  // hoisted LDS offsets
  const int swz = (lr & 7) << 4;
  int rdo[4];
  #pragma unroll
  for (int kk=0; kk<4; ++kk) rdo[kk] = (lr*256 + kk*64 + lg*16) ^ swz;
  int wro[4];
  #pragma unroll
  for (int u=0; u<4; ++u){
    int s = lg*4 + u;
    wro[u] = (s*256 + i*2) ^ ((s & 7) << 4);
  }

  int cur = 0;
  __syncthreads();

  #pragma unroll 1
  for (int t=0; t<PRED; ++t){
    const unsigned char* hc = Hb[cur];
    uint4 ah[4];
    #pragma unroll
    for (int kk=0; kk<4; ++kk)
      ah[kk] = *(const uint4*)(hc + rdo[kk]);

    // fused out head for h_t (emits step t-1), round-robin across waves
    if (t > 0 && g == (t & 7)){
      f32x4 accO = (f32x4){0.f,0.f,0.f,0.f};
      #pragma unroll
      for (int kk=0; kk<4; ++kk)
        accO = __builtin_amdgcn_mfma_f32_16x16x32_bf16(as_bf16x8(ah[kk]), as_bf16x8(bof[kk]), accO, 0,0,0);
      if (lr < 5){
        #pragma unroll
        for (int u=0; u<4; ++u){
          float a = accO[u] + obv;
          float val = (lr < 2) ? a : (lr == 4 ? tanhf_(a) : __expf(a));
          out[((size_t)(t-1)*NAg + n0 + lg*4 + u)*5 + lr] = val;
        }
      }
    }

    f32x4 aR = (f32x4){0.f,0.f,0.f,0.f};
    f32x4 aZ = (f32x4){0.f,0.f,0.f,0.f};
    f32x4 aN = (f32x4){0.f,0.f,0.f,0.f};
    #pragma unroll
    for (int kk=0; kk<4; ++kk)
      aR = __builtin_amdgcn_mfma_f32_16x16x32_bf16(as_bf16x8(ah[kk]), as_bf16x8(bgf[kk]),    aR, 0,0,0);
    #pragma unroll
    for (int kk=0; kk<4; ++kk)
      aZ = __builtin_amdgcn_mfma_f32_16x16x32_bf16(as_bf16x8(ah[kk]), as_bf16x8(bgf[4+kk]),  aZ, 0,0,0);
    #pragma unroll
    for (int kk=0; kk<4; ++kk)
      aN = __builtin_amdgcn_mfma_f32_16x16x32_bf16(as_bf16x8(ah[kk]), as_bf16x8(bgf[8+kk]),  aN, 0,0,0);

    unsigned char* hn = Hb[cur^1];
    #pragma unroll
    for (int u=0; u<4; ++u){
      float r  = sigf(gi_r[u] + aR[u] + bh_r);
      float z  = sigf(gi_z[u] + aZ[u] + bh_z);
      float nn = tanh2f(fmaf(r, aN[u] + bh_n, gi_n[u]));
      float h  = fmaf(z, hreg[u] - nn, nn);
      hreg[u] = h;
      *(unsigned short*)(hn + wro[u]) = f2bf(h);
    }
    __syncthreads();
    cur ^= 1;
  }

  // tail: out head for h_PRED (step PRED-1)
  if (g == (PRED & 7)){
    const unsigned char* hc = Hb[cur];
    uint4 ah[4];
    #pragma unroll
    for (int kk=0; kk<4; ++kk)
      ah[kk] = *(const uint4*)(hc + rdo[kk]);
    f32x4 accO = (f32x4){0.f,0.f,0.f,0.f};
    #pragma unroll
    for (int kk=0; kk<4; ++kk)
      accO = __builtin_amdgcn_mfma_f32_16x16x32_bf16(as_bf16x8(ah[kk]), as_bf16x8(bof[kk]), accO, 0,0,0);
    if (lr < 5){
      #pragma unroll
      for (int u=0; u<4; ++u){
        float a = accO[u] + obv;
        float val = (lr < 2) ? a : (lr == 4 ? tanhf_(a) : __expf(a));
        out[((size_t)(PRED-1)*NAg + n0 + lg*4 + u)*5 + lr] = val;
      }
    }
  }
}

// ---------------------------------------------------------------------------
extern "C" void kernel_launch(void* const* d_in, const int* in_sizes, int n_in,
                              void* d_out, int out_size, void* d_ws, size_t ws_size,
                              hipStream_t stream)
{
  const float* x      = (const float*)d_in[0];
  const float* ngbrs  = (const float*)d_in[1];
  const float* graphs = (const float*)d_in[2];
  const void*  masks  = d_in[3];
  // d_in[4] = ngbrs_idx (unused by the reference computation)
  const float* dynW   = (const float*)d_in[5];
  const float* dynb   = (const float*)d_in[6];
  const float* eWih   = (const float*)d_in[7];
  const float* eWhh   = (const float*)d_in[8];
  const float* ebih   = (const float*)d_in[9];
  const float* ebhh   = (const float*)d_in[10];
  const float* sW     = (const float*)d_in[11];
  const float* sb     = (const float*)d_in[12];
  const float* hidW   = (const float*)d_in[13];
  const float* hidb   = (const float*)d_in[14];
  const float* socW   = (const float*)d_in[15];
  const float* socb   = (const float*)d_in[16];
  const float* c31W   = (const float*)d_in[17];
  const float* c31b   = (const float*)d_in[18];
  const float* dWih   = (const float*)d_in[19];
  const float* dWhh   = (const float*)d_in[20];
  const float* dbih   = (const float*)d_in[21];
  const float* dbhh   = (const float*)d_in[22];
  const float* outW   = (const float*)d_in[23];
  const float* outb   = (const float*)d_in[24];
  float* out = (float*)d_out;

  char* ws = (char*)d_ws;
  size_t off = 0;
  __hip_bfloat16* E = (__hip_bfloat16*)(ws + off); off += (size_t)T_OBS*SEQ*64*2;   // 75.5 MB
  float* h_all      = (float*)(ws + off);          off += (size_t)SEQ*64*4;          // 9.4 MB
  int*   cells      = (int*)(ws + off);            off += (size_t)NAg*8*4;
  float* xc         = (float*)(ws + off);          off += (size_t)NAg*112*4;
  unsigned short* Wpk = (unsigned short*)(ws + off); off += (size_t)48*512*2;
  unsigned short* WdecF = (unsigned short*)(ws + off); off += (size_t)96*512*2;
  unsigned short* WoutF = (unsigned short*)(ws + off); off += (size_t)4*512*2;
  unsigned short* SWF = (unsigned short*)(ws + off); off += (size_t)16*512*2;
  unsigned short* WsocF = (unsigned short*)(ws + off); off += (size_t)72*512*2;

  k_decode_masks<<<16, 256, 0, stream>>>(masks, cells);
  k_prep<<<192, 256, 0, stream>>>(eWih, eWhh, Wpk, dWhh, WdecF, outW, WoutF, sW, SWF, socW, WsocF);
  k_embed_x<<<16384, 256, 0, stream>>>(x, dynW, dynb, E);
  k_embed_agg_mfma<<<4096, 256, 0, stream>>>(ngbrs, graphs, dynW, dynb, SWF, sb, E);
  k_gru_enc_mfma<<<2304, 256, 0, stream>>>((const unsigned short*)E, Wpk, ebih, ebhh, h_all);
  k_xs<<<512, 256, 0, stream>>>(h_all, hidW, hidb, xc);
  k_soc_mfma<<<512, 256, 0, stream>>>(h_all, cells, WsocF, socb, c31W, c31b, xc);
  k_dec_mfma<<<256, 512, 0, stream>>>(xc, WdecF, WoutF, dWih, dbih, dbhh, outb, out);
}